// Round 6
// baseline (265.981 us; speedup 1.0000x reference)
//
#include <hip/hip_runtime.h>

#define IN_C 17
#define HID  64
#define OUTC 32

#define CH   8192      // edges per pass-A block
#define TA   512       // pass-A threads
#define NBP  512       // padded bucket count (bucket = dst>>8; N<=131072)
#define BCAP 5632      // pass-B stage capacity (= 512*11; bucket avg ~4096)

__device__ __forceinline__ unsigned short f2bf(float f) {
    unsigned u = __float_as_uint(f);
    u += 0x7fffu + ((u >> 16) & 1u);      // round-nearest-even
    return (unsigned short)(u >> 16);
}
__device__ __forceinline__ float bflo(unsigned u) { return __uint_as_float(u << 16); }
__device__ __forceinline__ float bfhi(unsigned u) { return __uint_as_float(u & 0xffff0000u); }

// ================= pass A: bin edges by dst>>8, coalesced writes =================
__global__ __launch_bounds__(TA) void k_binA(const int* __restrict__ src,
        const int* __restrict__ dst, int E,
        int* __restrict__ outbuf, int* __restrict__ cntmat, int* __restrict__ offmat) {
    __shared__ int cnt[NBP];
    __shared__ int off[NBP];
    __shared__ int stage[CH];
    int t = threadIdx.x;
    long base = (long)blockIdx.x * CH;
    int nE = (int)(E - base); if (nE > CH) nE = CH;
    cnt[t] = 0;
    __syncthreads();
    int bk[16], pk[16], rk[16];
#pragma unroll
    for (int j = 0; j < 16; ++j) {
        int idx = t + j * TA;
        if (idx < nE) {
            long e = base + idx;
            int d = dst[e], s = src[e];
            int b = d >> 8;
            bk[j] = b;
            pk[j] = s | ((d & 255) << 17);
            rk[j] = atomicAdd(&cnt[b], 1);
        } else bk[j] = -1;
    }
    __syncthreads();
    int c = cnt[t];
    off[t] = c;
    __syncthreads();
    int inc = c;
    for (int s = 1; s < NBP; s <<= 1) {
        int add = (t >= s) ? off[t - s] : 0;
        __syncthreads();
        inc += add; off[t] = inc;
        __syncthreads();
    }
    int excl = inc - c;
    __syncthreads();
    off[t] = excl;
    __syncthreads();
#pragma unroll
    for (int j = 0; j < 16; ++j)
        if (bk[j] >= 0) stage[off[bk[j]] + rk[j]] = pk[j];
    __syncthreads();
    for (int i = t; i < nE; i += TA) outbuf[base + i] = stage[i];
    cntmat[blockIdx.x * NBP + t] = c;
    offmat[blockIdx.x * NBP + t] = excl;
}

// ============ bucket totals + exclusive scan -> global bucket bases ============
__global__ __launch_bounds__(NBP) void k_bsum(const int* __restrict__ cntmat,
        int nblkA, int* __restrict__ bbase) {
    __shared__ int sh[NBP];
    int t = threadIdx.x;
    int s = 0;
    for (int i = 0; i < nblkA; ++i) s += cntmat[i * NBP + t];
    sh[t] = s;
    __syncthreads();
    int inc = s;
    for (int st = 1; st < NBP; st <<= 1) {
        int add = (t >= st) ? sh[t - st] : 0;
        __syncthreads();
        inc += add; sh[t] = inc;
        __syncthreads();
    }
    bbase[t] = inc - s;
}

// === pass B: per bucket, gather runs, count degrees, emit CSR + deg + rowstart ===
__global__ __launch_bounds__(TA) void k_binB(const int* __restrict__ outbuf,
        const int* __restrict__ cntmat, const int* __restrict__ offmat,
        const int* __restrict__ bbase, int nblkA, int N,
        int* __restrict__ csr, int* __restrict__ rowstart, int* __restrict__ deg) {
    __shared__ int segc[256], sego[256], segs[256];
    __shared__ int ndeg[256], noff[256];
    __shared__ int stage[BCAP];
    int t = threadIdx.x, b = blockIdx.x;
    if (t < 256) {
        int cc = 0, ss = 0;
        if (t < nblkA) { cc = cntmat[t * NBP + b]; ss = offmat[t * NBP + b]; }
        segc[t] = cc; segs[t] = ss; sego[t] = cc;
        ndeg[t] = 0;
    }
    __syncthreads();
    {
        int c = (t < 256) ? sego[t] : 0;
        int inc = c;
        for (int s = 1; s < 256; s <<= 1) {
            int add = (t < 256 && t >= s) ? sego[t - s] : 0;
            __syncthreads();
            if (t < 256) { inc += add; sego[t] = inc; }
            __syncthreads();
        }
        if (t < 256) sego[t] = inc - c;
    }
    __syncthreads();
    int wave = t >> 6, lane = t & 63;
    for (int i = wave; i < nblkA; i += TA / 64) {
        int c = segc[i], so = sego[i];
        long gs = (long)i * CH + segs[i];
        for (int l = lane; l < c; l += 64) {
            int p = so + l;
            if (p < BCAP) stage[p] = outbuf[gs + l];
        }
    }
    __syncthreads();
    int T = sego[255] + segc[255];
    if (T > BCAP) T = BCAP;
    int mypk[11], myrk[11], ne = 0;
    for (int k = t; k < T; k += TA) {
        int p = stage[k];
        int l = (p >> 17) & 255;
        myrk[ne] = atomicAdd(&ndeg[l], 1);
        mypk[ne] = p;
        ne++;
    }
    __syncthreads();
    {
        int c = (t < 256) ? ndeg[t] : 0;
        if (t < 256) noff[t] = c;
        __syncthreads();
        int inc = c;
        for (int s = 1; s < 256; s <<= 1) {
            int add = (t < 256 && t >= s) ? noff[t - s] : 0;
            __syncthreads();
            if (t < 256) { inc += add; noff[t] = inc; }
            __syncthreads();
        }
        if (t < 256) noff[t] = inc - c;
    }
    __syncthreads();
    int gb = bbase[b];
    int n0 = b << 8;
    if (t < 256 && n0 + t < N) {
        deg[n0 + t] = ndeg[t];
        rowstart[n0 + t] = gb + noff[t];
    }
    for (int j = 0; j < ne; ++j) {
        int p = mypk[j];
        int l = (p >> 17) & 255;
        csr[gb + noff[l] + myrk[j]] = p & 0x1FFFF;
    }
}

// ---------- prep: packed bf16 xs16h[n][8] (ch pairs), xs17h[n]; all x*dinv ----------
__global__ void k_prep(const float* __restrict__ x, const int* __restrict__ deg,
                       unsigned* __restrict__ xs16h, unsigned short* __restrict__ xs17h,
                       int N) {
    long i = (long)blockIdx.x * blockDim.x + threadIdx.x;
    if (i >= (long)N * 8) return;
    int n = (int)(i >> 3);
    int w = (int)(i & 7);
    float dinv = rsqrtf((float)(deg[n] + 1));
    const float* xr = x + (size_t)n * IN_C;
    unsigned lo = f2bf(xr[2 * w] * dinv);
    unsigned hi = f2bf(xr[2 * w + 1] * dinv);
    xs16h[i] = lo | (hi << 16);
    if (w == 0) xs17h[n] = f2bf(xr[16] * dinv);
}

// ---------- layer 1: aggregate bf16 x (17ch) then fused 17->64 matvec + bias + relu ----------
// wave per node: 16 edge groups x 4 quads (quad = 4 bf16 ch via uint2).
__global__ __launch_bounds__(256) void k_gather1(
        const uint2* __restrict__ xs16v, const unsigned short* __restrict__ xs17h,
        const int* __restrict__ csr, const int* __restrict__ rowstart,
        const int* __restrict__ deg, const float* __restrict__ W1,
        const float* __restrict__ b1, float* __restrict__ h1, int N) {
    __shared__ float Ws[IN_C * HID];
    __shared__ float aggx[4][IN_C + 3];
    for (int i = threadIdx.x; i < IN_C * HID; i += 256) Ws[i] = W1[i];
    int ln = threadIdx.x >> 6, lane = threadIdx.x & 63;
    int n = blockIdx.x * 4 + ln;
    int q = lane & 3, g = lane >> 2;
    float ax = 0.f, ay = 0.f, az = 0.f, aw = 0.f, a17 = 0.f;
    if (n < N) {
        int cnt = deg[n], start = rowstart[n], end = start + cnt;
        if (g == 0) {
            uint2 v = xs16v[(size_t)n * 4 + q];
            ax = bflo(v.x); ay = bfhi(v.x); az = bflo(v.y); aw = bfhi(v.y);
            if (q == 0) a17 = bflo((unsigned)xs17h[n]);
        }
        for (int k = start + g; k < end; k += 16) {
            int s = csr[k];
            uint2 v = xs16v[(size_t)s * 4 + q];
            ax += bflo(v.x); ay += bfhi(v.x); az += bflo(v.y); aw += bfhi(v.y);
            if (q == 0) a17 += bflo((unsigned)xs17h[s]);
        }
#pragma unroll
        for (int off = 4; off <= 32; off <<= 1) {
            ax += __shfl_xor(ax, off);
            ay += __shfl_xor(ay, off);
            az += __shfl_xor(az, off);
            aw += __shfl_xor(aw, off);
            a17 += __shfl_xor(a17, off);
        }
        if (g == 0) {
            aggx[ln][q * 4 + 0] = ax;
            aggx[ln][q * 4 + 1] = ay;
            aggx[ln][q * 4 + 2] = az;
            aggx[ln][q * 4 + 3] = aw;
            if (q == 0) aggx[ln][16] = a17;
        }
    }
    __syncthreads();
    if (n < N) {
        float dot = 0.f;
#pragma unroll
        for (int k = 0; k < IN_C; ++k) dot += aggx[ln][k] * Ws[k * HID + lane];
        float dinv = rsqrtf((float)(deg[n] + 1));
        h1[(size_t)n * HID + lane] = fmaxf(dinv * dot + b1[lane], 0.f);
    }
}

// ---------- layer 2 matmul: two packed bf16 halves hs2a (ch0-15), hs2b (ch16-31) ----------
__global__ void k_mm2(const float* __restrict__ h1, const float* __restrict__ W2,
                      const int* __restrict__ deg,
                      unsigned* __restrict__ hs2a, unsigned* __restrict__ hs2b, int N) {
    __shared__ float Ws[HID * OUTC];
    for (int i = threadIdx.x; i < HID * OUTC; i += blockDim.x) Ws[i] = W2[i];
    __syncthreads();
    int tc = threadIdx.x & 15;            // 2 channels per thread
    int ln = threadIdx.x >> 4;            // 16 nodes per 256-thread block
    int n  = blockIdx.x * 16 + ln;
    if (n >= N) return;
    int c0 = tc * 2;
    const float* hr = h1 + (size_t)n * HID;
    float a0 = 0.f, a1 = 0.f;
#pragma unroll
    for (int k = 0; k < HID; ++k) {
        float h = hr[k];
        a0 += h * Ws[k * OUTC + c0];
        a1 += h * Ws[k * OUTC + c0 + 1];
    }
    float dinv = rsqrtf((float)(deg[n] + 1));
    unsigned lo = f2bf(a0 * dinv), hi = f2bf(a1 * dinv);
    unsigned word = lo | (hi << 16);
    unsigned* dstp = (tc < 8) ? hs2a : hs2b;
    dstp[(size_t)n * 8 + (tc & 7)] = word;
}

// ---------- layer 2 gather (one 16-ch bf16 half) + bias + pooled atomics ----------
template<int HALF>
__global__ __launch_bounds__(256) void k_gather2h(
        const uint2* __restrict__ hsv, const int* __restrict__ csr,
        const int* __restrict__ rowstart, const int* __restrict__ deg,
        const float* __restrict__ b2, const int* __restrict__ batch,
        float* pool, float* cntg, int N) {
    __shared__ float cont[4][16];
    __shared__ int bsh[4];
    int ln = threadIdx.x >> 6, lane = threadIdx.x & 63;
    int n = blockIdx.x * 4 + ln;
    int q = lane & 3, g = lane >> 2;
    float ax = 0.f, ay = 0.f, az = 0.f, aw = 0.f;
    if (n < N) {
        int cnt = deg[n], start = rowstart[n], end = start + cnt;
        if (g == 0) {
            uint2 v = hsv[(size_t)n * 4 + q];
            ax = bflo(v.x); ay = bfhi(v.x); az = bflo(v.y); aw = bfhi(v.y);
        }
        for (int k = start + g; k < end; k += 16) {
            int s = csr[k];
            uint2 v = hsv[(size_t)s * 4 + q];
            ax += bflo(v.x); ay += bfhi(v.x); az += bflo(v.y); aw += bfhi(v.y);
        }
#pragma unroll
        for (int off = 4; off <= 32; off <<= 1) {
            ax += __shfl_xor(ax, off);
            ay += __shfl_xor(ay, off);
            az += __shfl_xor(az, off);
            aw += __shfl_xor(aw, off);
        }
        if (g == 0) {
            float dinv = rsqrtf((float)(cnt + 1));
            cont[ln][q * 4 + 0] = dinv * ax + b2[HALF * 16 + q * 4 + 0];
            cont[ln][q * 4 + 1] = dinv * ay + b2[HALF * 16 + q * 4 + 1];
            cont[ln][q * 4 + 2] = dinv * az + b2[HALF * 16 + q * 4 + 2];
            cont[ln][q * 4 + 3] = dinv * aw + b2[HALF * 16 + q * 4 + 3];
        }
        if (lane == 0) bsh[ln] = batch[n];
    } else {
        if (g == 0) {
            cont[ln][q * 4 + 0] = 0.f; cont[ln][q * 4 + 1] = 0.f;
            cont[ln][q * 4 + 2] = 0.f; cont[ln][q * 4 + 3] = 0.f;
        }
        if (lane == 0) bsh[ln] = -1;
    }
    __syncthreads();
    if (threadIdx.x < 16) {
        int c = threadIdx.x;
        float run = 0.f; int cur = -1;
        for (int j = 0; j < 4; ++j) {
            int bj = bsh[j];
            if (bj < 0) continue;
            if (bj == cur) run += cont[j][c];
            else {
                if (cur >= 0) atomicAdd(&pool[(size_t)cur * OUTC + HALF * 16 + c], run);
                cur = bj; run = cont[j][c];
            }
        }
        if (cur >= 0) atomicAdd(&pool[(size_t)cur * OUTC + HALF * 16 + c], run);
        if (HALF == 0 && c == 0) {
            float crun = 0.f; cur = -1;
            for (int j = 0; j < 4; ++j) {
                int bj = bsh[j];
                if (bj < 0) continue;
                if (bj == cur) crun += 1.f;
                else {
                    if (cur >= 0) atomicAdd(&cntg[cur], crun);
                    cur = bj; crun = 1.f;
                }
            }
            if (cur >= 0) atomicAdd(&cntg[cur], crun);
        }
    }
}

// ---------- final: pooled mean -> fc1(relu) -> fc2 ----------
__global__ void k_final(const float* __restrict__ pool, const float* __restrict__ cntg,
                        const float* __restrict__ Wf1, const float* __restrict__ bf1,
                        const float* __restrict__ Wf2, const float* __restrict__ bf2,
                        float* out, int G) {
    __shared__ float p[OUTC], t[OUTC];
    int g = blockIdx.x;
    int c = threadIdx.x;
    float csafe = fmaxf(cntg[g], 1.0f);
    p[c] = pool[g * OUTC + c] / csafe;
    __syncthreads();
    float acc = bf1[c];
#pragma unroll
    for (int k = 0; k < OUTC; ++k) acc += p[k] * Wf1[k * OUTC + c];
    t[c] = fmaxf(acc, 0.f);
    __syncthreads();
    float acc2 = bf2[c];
#pragma unroll
    for (int k = 0; k < OUTC; ++k) acc2 += t[k] * Wf2[k * OUTC + c];
    out[g * OUTC + c] = acc2;
}

extern "C" void kernel_launch(void* const* d_in, const int* in_sizes, int n_in,
                              void* d_out, int out_size, void* d_ws, size_t ws_size,
                              hipStream_t stream) {
    const float* x    = (const float*)d_in[0];
    const int*   ei   = (const int*)  d_in[1];
    const int*   batch= (const int*)  d_in[2];
    const float* W1   = (const float*)d_in[3];
    const float* b1   = (const float*)d_in[4];
    const float* W2   = (const float*)d_in[5];
    const float* b2   = (const float*)d_in[6];
    const float* Wf1  = (const float*)d_in[7];
    const float* bf1  = (const float*)d_in[8];
    const float* Wf2  = (const float*)d_in[9];
    const float* bf2  = (const float*)d_in[10];

    const int N = in_sizes[0] / IN_C;
    const int E = in_sizes[1] / 2;
    const int G = out_size / OUTC;
    const int* src = ei;
    const int* dst = ei + E;

    const int nblkA = (E + CH - 1) / CH;
    const int NB    = (N + 255) >> 8;

    // ---- workspace layout ----
    char* w = (char*)d_ws;
    int*   csr      = (int*)w;   w += (size_t)E * sizeof(int);
    int*   deg      = (int*)w;   w += (size_t)N * sizeof(int);
    int*   rowstart = (int*)w;   w += (size_t)N * sizeof(int);
    unsigned* xs16h = (unsigned*)w; w += (size_t)N * 8 * sizeof(unsigned);
    unsigned short* xs17h = (unsigned short*)w; w += (size_t)N * sizeof(unsigned short);
    unsigned* hs2a  = (unsigned*)w; w += (size_t)N * 8 * sizeof(unsigned);
    unsigned* hs2b  = (unsigned*)w; w += (size_t)N * 8 * sizeof(unsigned);
    float* pool     = (float*)w; w += (size_t)G * OUTC * sizeof(float);
    float* cntg     = (float*)w; w += (size_t)G * sizeof(float);
    // overlap region: pass-A buffers, later reused as h1
    char* ov = w;
    int*   outbuf   = (int*)ov;
    int*   cntmat   = (int*)(ov + (size_t)E * sizeof(int));
    int*   offmat   = (int*)(ov + (size_t)E * sizeof(int) + (size_t)nblkA * NBP * sizeof(int));
    int*   bbase    = (int*)(ov + (size_t)E * sizeof(int) + 2 * (size_t)nblkA * NBP * sizeof(int));
    float* h1       = (float*)ov;              // N*HID floats, alive after pass B

    hipMemsetAsync(pool, 0, (size_t)(G * OUTC + G) * sizeof(float), stream);

    // CSR build (counting sort)
    k_binA<<<nblkA, TA, 0, stream>>>(src, dst, E, outbuf, cntmat, offmat);
    k_bsum<<<1, NBP, 0, stream>>>(cntmat, nblkA, bbase);
    k_binB<<<NB, TA, 0, stream>>>(outbuf, cntmat, offmat, bbase, nblkA, N,
                                  csr, rowstart, deg);

    // layer 1: pack scaled x to bf16, aggregate (L2-resident), fused matvec
    dim3 blk(256);
    k_prep<<<(int)(((long)N * 8 + 255) / 256), blk, 0, stream>>>(x, deg, xs16h, xs17h, N);
    k_gather1<<<(N + 3) / 4, blk, 0, stream>>>((const uint2*)xs16h, xs17h, csr, rowstart,
                                               deg, W1, b1, h1, N);

    // layer 2: matmul to two bf16 halves, two L2-resident gather passes
    k_mm2<<<(N + 15) / 16, blk, 0, stream>>>(h1, W2, deg, hs2a, hs2b, N);
    k_gather2h<0><<<(N + 3) / 4, blk, 0, stream>>>((const uint2*)hs2a, csr, rowstart, deg,
                                                   b2, batch, pool, cntg, N);
    k_gather2h<1><<<(N + 3) / 4, blk, 0, stream>>>((const uint2*)hs2b, csr, rowstart, deg,
                                                   b2, batch, pool, cntg, N);

    // readout
    k_final<<<G, OUTC, 0, stream>>>(pool, cntg, Wf1, bf1, Wf2, bf2, (float*)d_out, G);
}

// Round 7
// 189.947 us; speedup vs baseline: 1.4003x; 1.4003x over previous
//
#include <hip/hip_runtime.h>

#define IN_C 17
#define HID  64
#define OUTC 32

#define CH   8192      // edges per pass-A block
#define TA   512       // pass-A threads
#define NBP  512       // padded bucket count (bucket = dst>>8; N<=131072)
#define BCAP 5632      // pass-B stage capacity (= 512*11; bucket avg ~4096)

__device__ __forceinline__ unsigned short f2bf(float f) {
    unsigned u = __float_as_uint(f);
    u += 0x7fffu + ((u >> 16) & 1u);      // round-nearest-even
    return (unsigned short)(u >> 16);
}
__device__ __forceinline__ float bflo(unsigned u) { return __uint_as_float(u << 16); }
__device__ __forceinline__ float bfhi(unsigned u) { return __uint_as_float(u & 0xffff0000u); }

// ================= pass A: bin edges by dst>>8, coalesced writes =================
__global__ __launch_bounds__(TA) void k_binA(const int* __restrict__ src,
        const int* __restrict__ dst, int E,
        int* __restrict__ outbuf, int* __restrict__ cntmat, int* __restrict__ offmat) {
    __shared__ int cnt[NBP];
    __shared__ int off[NBP];
    __shared__ int stage[CH];
    int t = threadIdx.x;
    long base = (long)blockIdx.x * CH;
    int nE = (int)(E - base); if (nE > CH) nE = CH;
    cnt[t] = 0;
    __syncthreads();
    int bk[16], pk[16], rk[16];
#pragma unroll
    for (int j = 0; j < 16; ++j) {
        int idx = t + j * TA;
        if (idx < nE) {
            long e = base + idx;
            int d = dst[e], s = src[e];
            int b = d >> 8;
            bk[j] = b;
            pk[j] = s | ((d & 255) << 17);
            rk[j] = atomicAdd(&cnt[b], 1);
        } else bk[j] = -1;
    }
    __syncthreads();
    int c = cnt[t];
    off[t] = c;
    __syncthreads();
    int inc = c;
    for (int s = 1; s < NBP; s <<= 1) {
        int add = (t >= s) ? off[t - s] : 0;
        __syncthreads();
        inc += add; off[t] = inc;
        __syncthreads();
    }
    int excl = inc - c;
    __syncthreads();
    off[t] = excl;
    __syncthreads();
#pragma unroll
    for (int j = 0; j < 16; ++j)
        if (bk[j] >= 0) stage[off[bk[j]] + rk[j]] = pk[j];
    __syncthreads();
    for (int i = t; i < nE; i += TA) outbuf[base + i] = stage[i];
    cntmat[blockIdx.x * NBP + t] = c;
    offmat[blockIdx.x * NBP + t] = excl;
}

// ============ bucket totals + exclusive scan -> global bucket bases ============
__global__ __launch_bounds__(NBP) void k_bsum(const int* __restrict__ cntmat,
        int nblkA, int* __restrict__ bbase) {
    __shared__ int sh[NBP];
    int t = threadIdx.x;
    int s = 0;
    for (int i = 0; i < nblkA; ++i) s += cntmat[i * NBP + t];
    sh[t] = s;
    __syncthreads();
    int inc = s;
    for (int st = 1; st < NBP; st <<= 1) {
        int add = (t >= st) ? sh[t - st] : 0;
        __syncthreads();
        inc += add; sh[t] = inc;
        __syncthreads();
    }
    bbase[t] = inc - s;
}

// === pass B: per bucket, gather runs, count degrees, emit CSR + meta(start,deg) ===
__global__ __launch_bounds__(TA) void k_binB(const int* __restrict__ outbuf,
        const int* __restrict__ cntmat, const int* __restrict__ offmat,
        const int* __restrict__ bbase, int nblkA, int N,
        int* __restrict__ csr, int2* __restrict__ meta) {
    __shared__ int segc[256], sego[256], segs[256];
    __shared__ int ndeg[256], noff[256];
    __shared__ int stage[BCAP];
    int t = threadIdx.x, b = blockIdx.x;
    if (t < 256) {
        int cc = 0, ss = 0;
        if (t < nblkA) { cc = cntmat[t * NBP + b]; ss = offmat[t * NBP + b]; }
        segc[t] = cc; segs[t] = ss; sego[t] = cc;
        ndeg[t] = 0;
    }
    __syncthreads();
    {
        int c = (t < 256) ? sego[t] : 0;
        int inc = c;
        for (int s = 1; s < 256; s <<= 1) {
            int add = (t < 256 && t >= s) ? sego[t - s] : 0;
            __syncthreads();
            if (t < 256) { inc += add; sego[t] = inc; }
            __syncthreads();
        }
        if (t < 256) sego[t] = inc - c;
    }
    __syncthreads();
    int wave = t >> 6, lane = t & 63;
    for (int i = wave; i < nblkA; i += TA / 64) {
        int c = segc[i], so = sego[i];
        long gs = (long)i * CH + segs[i];
        for (int l = lane; l < c; l += 64) {
            int p = so + l;
            if (p < BCAP) stage[p] = outbuf[gs + l];
        }
    }
    __syncthreads();
    int T = sego[255] + segc[255];
    if (T > BCAP) T = BCAP;
    int mypk[11], myrk[11], ne = 0;
    for (int k = t; k < T; k += TA) {
        int p = stage[k];
        int l = (p >> 17) & 255;
        myrk[ne] = atomicAdd(&ndeg[l], 1);
        mypk[ne] = p;
        ne++;
    }
    __syncthreads();
    {
        int c = (t < 256) ? ndeg[t] : 0;
        if (t < 256) noff[t] = c;
        __syncthreads();
        int inc = c;
        for (int s = 1; s < 256; s <<= 1) {
            int add = (t < 256 && t >= s) ? noff[t - s] : 0;
            __syncthreads();
            if (t < 256) { inc += add; noff[t] = inc; }
            __syncthreads();
        }
        if (t < 256) noff[t] = inc - c;
    }
    __syncthreads();
    int gb = bbase[b];
    int n0 = b << 8;
    if (t < 256 && n0 + t < N)
        meta[n0 + t] = make_int2(gb + noff[t], ndeg[t]);
    for (int j = 0; j < ne; ++j) {
        int p = mypk[j];
        int l = (p >> 17) & 255;
        csr[gb + noff[l] + myrk[j]] = p & 0x1FFFF;
    }
}

// ---------- prep: packed bf16 xs16h[n][8] (ch pairs), xs17h[n]; all x*dinv ----------
__global__ void k_prep(const float* __restrict__ x, const int2* __restrict__ meta,
                       unsigned* __restrict__ xs16h, unsigned short* __restrict__ xs17h,
                       int N) {
    long i = (long)blockIdx.x * blockDim.x + threadIdx.x;
    if (i >= (long)N * 8) return;
    int n = (int)(i >> 3);
    int w = (int)(i & 7);
    float dinv = rsqrtf((float)(meta[n].y + 1));
    const float* xr = x + (size_t)n * IN_C;
    unsigned lo = f2bf(xr[2 * w] * dinv);
    unsigned hi = f2bf(xr[2 * w + 1] * dinv);
    xs16h[i] = lo | (hi << 16);
    if (w == 0) xs17h[n] = f2bf(xr[16] * dinv);
}

// ---------- layer 1: 2 nodes/wave aggregate + fused 17->64 matvec + bias + relu ----------
// node = 32 lanes: 8 edge groups x 4 quads (quad = 4 bf16 ch via uint2). block = 8 nodes.
__global__ __launch_bounds__(256) void k_gather1(
        const uint2* __restrict__ xs16v, const unsigned short* __restrict__ xs17h,
        const int* __restrict__ csr, const int2* __restrict__ meta,
        const float* __restrict__ W1, const float* __restrict__ b1,
        float* __restrict__ h1, int N) {
    __shared__ float Ws[IN_C * HID];
    __shared__ float aggx[8][IN_C + 3];
    __shared__ float dinv_sh[8];
    for (int i = threadIdx.x; i < IN_C * HID; i += 256) Ws[i] = W1[i];
    int ln = threadIdx.x >> 5;            // node slot 0..7
    int sl = threadIdx.x & 31;            // lane within node
    int n = blockIdx.x * 8 + ln;
    int q = sl & 3, g = sl >> 2;          // quad 0..3, edge group 0..7
    float ax = 0.f, ay = 0.f, az = 0.f, aw = 0.f, a17 = 0.f;
    if (n < N) {
        int2 m = meta[n];
        int start = m.x, cnt = m.y, end = start + cnt;
        if (g == 0) {
            uint2 v = xs16v[(size_t)n * 4 + q];
            ax = bflo(v.x); ay = bfhi(v.x); az = bflo(v.y); aw = bfhi(v.y);
            if (q == 0) a17 = bflo((unsigned)xs17h[n]);
        }
        for (int k = start + g; k < end; k += 8) {
            int s = csr[k];
            uint2 v = xs16v[(size_t)s * 4 + q];
            ax += bflo(v.x); ay += bfhi(v.x); az += bflo(v.y); aw += bfhi(v.y);
            if (q == 0) a17 += bflo((unsigned)xs17h[s]);
        }
#pragma unroll
        for (int off = 4; off <= 16; off <<= 1) {   // stays within the 32-lane half
            ax += __shfl_xor(ax, off);
            ay += __shfl_xor(ay, off);
            az += __shfl_xor(az, off);
            aw += __shfl_xor(aw, off);
            a17 += __shfl_xor(a17, off);
        }
        if (g == 0) {
            aggx[ln][q * 4 + 0] = ax;
            aggx[ln][q * 4 + 1] = ay;
            aggx[ln][q * 4 + 2] = az;
            aggx[ln][q * 4 + 3] = aw;
            if (q == 0) {
                aggx[ln][16] = a17;
                dinv_sh[ln] = rsqrtf((float)(cnt + 1));
            }
        }
    }
    __syncthreads();
    // matvec: 8 nodes x 64 ch = 512 outputs, 2 per thread
    int ch = threadIdx.x & 63;
#pragma unroll
    for (int rep = 0; rep < 2; ++rep) {
        int slot = (threadIdx.x >> 6) + rep * 4;
        int nn = blockIdx.x * 8 + slot;
        if (nn < N) {
            float dot = 0.f;
#pragma unroll
            for (int k = 0; k < IN_C; ++k) dot += aggx[slot][k] * Ws[k * HID + ch];
            h1[(size_t)nn * HID + ch] = fmaxf(dinv_sh[slot] * dot + b1[ch], 0.f);
        }
    }
}

// ---------- layer 2 matmul: packed bf16 hs2[n][16] (ch pairs) ----------
__global__ void k_mm2(const float* __restrict__ h1, const float* __restrict__ W2,
                      const int2* __restrict__ meta, unsigned* __restrict__ hs2, int N) {
    __shared__ float Ws[HID * OUTC];
    for (int i = threadIdx.x; i < HID * OUTC; i += blockDim.x) Ws[i] = W2[i];
    __syncthreads();
    int tc = threadIdx.x & 15;            // 2 channels per thread
    int ln = threadIdx.x >> 4;            // 16 nodes per 256-thread block
    int n  = blockIdx.x * 16 + ln;
    if (n >= N) return;
    int c0 = tc * 2;
    const float* hr = h1 + (size_t)n * HID;
    float a0 = 0.f, a1 = 0.f;
#pragma unroll
    for (int k = 0; k < HID; ++k) {
        float h = hr[k];
        a0 += h * Ws[k * OUTC + c0];
        a1 += h * Ws[k * OUTC + c0 + 1];
    }
    float dinv = rsqrtf((float)(meta[n].y + 1));
    unsigned lo = f2bf(a0 * dinv), hi = f2bf(a1 * dinv);
    hs2[(size_t)n * 16 + tc] = lo | (hi << 16);
}

__device__ __forceinline__ void bf8_add(uint4 v, float* a) {
    a[0] += __uint_as_float(v.x << 16); a[1] += __uint_as_float(v.x & 0xffff0000u);
    a[2] += __uint_as_float(v.y << 16); a[3] += __uint_as_float(v.y & 0xffff0000u);
    a[4] += __uint_as_float(v.z << 16); a[5] += __uint_as_float(v.z & 0xffff0000u);
    a[6] += __uint_as_float(v.w << 16); a[7] += __uint_as_float(v.w & 0xffff0000u);
}

// ---------- layer 2 gather: 2 nodes/wave (8 groups x 4 quads, uint4=8ch/lane) ----------
__global__ __launch_bounds__(256) void k_gather2(
        const uint4* __restrict__ hs2v, const int* __restrict__ csr,
        const int2* __restrict__ meta, const float* __restrict__ b2,
        const int* __restrict__ batch, float* pool, float* cntg, int N) {
    __shared__ float cont[8][OUTC];
    __shared__ int bsh[8];
    int ln = threadIdx.x >> 5;            // node slot 0..7
    int sl = threadIdx.x & 31;
    int n = blockIdx.x * 8 + ln;
    int q = sl & 3, g = sl >> 2;
    float a[8] = {0.f, 0.f, 0.f, 0.f, 0.f, 0.f, 0.f, 0.f};
    if (n < N) {
        int2 m = meta[n];
        int start = m.x, cnt = m.y, end = start + cnt;
        if (g == 0) bf8_add(hs2v[(size_t)n * 4 + q], a);   // self loop
        for (int k = start + g; k < end; k += 8)
            bf8_add(hs2v[(size_t)csr[k] * 4 + q], a);
#pragma unroll
        for (int off = 4; off <= 16; off <<= 1) {
#pragma unroll
            for (int j = 0; j < 8; ++j) a[j] += __shfl_xor(a[j], off);
        }
        if (g == 0) {
            float dinv = rsqrtf((float)(cnt + 1));
#pragma unroll
            for (int j = 0; j < 8; ++j)
                cont[ln][q * 8 + j] = dinv * a[j] + b2[q * 8 + j];
        }
        if (sl == 0) bsh[ln] = batch[n];
    } else {
        if (g == 0) {
#pragma unroll
            for (int j = 0; j < 8; ++j) cont[ln][q * 8 + j] = 0.f;
        }
        if (sl == 0) bsh[ln] = -1;
    }
    __syncthreads();
    if (threadIdx.x < OUTC) {
        int c = threadIdx.x;
        float run = 0.f; int cur = -1;
        for (int j = 0; j < 8; ++j) {
            int bj = bsh[j];
            if (bj < 0) continue;
            if (bj == cur) run += cont[j][c];
            else {
                if (cur >= 0) atomicAdd(&pool[(size_t)cur * OUTC + c], run);
                cur = bj; run = cont[j][c];
            }
        }
        if (cur >= 0) atomicAdd(&pool[(size_t)cur * OUTC + c], run);
        if (c == 0) {
            float crun = 0.f; cur = -1;
            for (int j = 0; j < 8; ++j) {
                int bj = bsh[j];
                if (bj < 0) continue;
                if (bj == cur) crun += 1.f;
                else {
                    if (cur >= 0) atomicAdd(&cntg[cur], crun);
                    cur = bj; crun = 1.f;
                }
            }
            if (cur >= 0) atomicAdd(&cntg[cur], crun);
        }
    }
}

// ---------- final: pooled mean -> fc1(relu) -> fc2 ----------
__global__ void k_final(const float* __restrict__ pool, const float* __restrict__ cntg,
                        const float* __restrict__ Wf1, const float* __restrict__ bf1,
                        const float* __restrict__ Wf2, const float* __restrict__ bf2,
                        float* out, int G) {
    __shared__ float p[OUTC], t[OUTC];
    int g = blockIdx.x;
    int c = threadIdx.x;
    float csafe = fmaxf(cntg[g], 1.0f);
    p[c] = pool[g * OUTC + c] / csafe;
    __syncthreads();
    float acc = bf1[c];
#pragma unroll
    for (int k = 0; k < OUTC; ++k) acc += p[k] * Wf1[k * OUTC + c];
    t[c] = fmaxf(acc, 0.f);
    __syncthreads();
    float acc2 = bf2[c];
#pragma unroll
    for (int k = 0; k < OUTC; ++k) acc2 += t[k] * Wf2[k * OUTC + c];
    out[g * OUTC + c] = acc2;
}

extern "C" void kernel_launch(void* const* d_in, const int* in_sizes, int n_in,
                              void* d_out, int out_size, void* d_ws, size_t ws_size,
                              hipStream_t stream) {
    const float* x    = (const float*)d_in[0];
    const int*   ei   = (const int*)  d_in[1];
    const int*   batch= (const int*)  d_in[2];
    const float* W1   = (const float*)d_in[3];
    const float* b1   = (const float*)d_in[4];
    const float* W2   = (const float*)d_in[5];
    const float* b2   = (const float*)d_in[6];
    const float* Wf1  = (const float*)d_in[7];
    const float* bf1  = (const float*)d_in[8];
    const float* Wf2  = (const float*)d_in[9];
    const float* bf2  = (const float*)d_in[10];

    const int N = in_sizes[0] / IN_C;
    const int E = in_sizes[1] / 2;
    const int G = out_size / OUTC;
    const int* src = ei;
    const int* dst = ei + E;

    const int nblkA = (E + CH - 1) / CH;
    const int NB    = (N + 255) >> 8;

    // ---- workspace layout ----
    char* w = (char*)d_ws;
    int*   csr      = (int*)w;   w += (size_t)E * sizeof(int);
    int2*  meta     = (int2*)w;  w += (size_t)N * sizeof(int2);
    unsigned* xs16h = (unsigned*)w; w += (size_t)N * 8 * sizeof(unsigned);
    unsigned* hs2   = (unsigned*)w; w += (size_t)N * 16 * sizeof(unsigned);
    unsigned short* xs17h = (unsigned short*)w; w += (size_t)N * sizeof(unsigned short);
    w = (char*)(((size_t)w + 15) & ~(size_t)15);
    float* pool     = (float*)w; w += (size_t)G * OUTC * sizeof(float);
    float* cntg     = (float*)w; w += (size_t)G * sizeof(float);
    w = (char*)(((size_t)w + 15) & ~(size_t)15);
    // overlap region: pass-A buffers, later reused as h1
    char* ov = w;
    int*   outbuf   = (int*)ov;
    int*   cntmat   = (int*)(ov + (size_t)E * sizeof(int));
    int*   offmat   = (int*)(ov + (size_t)E * sizeof(int) + (size_t)nblkA * NBP * sizeof(int));
    int*   bbase    = (int*)(ov + (size_t)E * sizeof(int) + 2 * (size_t)nblkA * NBP * sizeof(int));
    float* h1       = (float*)ov;              // N*HID floats, alive after pass B

    hipMemsetAsync(pool, 0, (size_t)(G * OUTC + G) * sizeof(float), stream);

    // CSR build (counting sort)
    k_binA<<<nblkA, TA, 0, stream>>>(src, dst, E, outbuf, cntmat, offmat);
    k_bsum<<<1, NBP, 0, stream>>>(cntmat, nblkA, bbase);
    k_binB<<<NB, TA, 0, stream>>>(outbuf, cntmat, offmat, bbase, nblkA, N, csr, meta);

    // layer 1: pack scaled x to bf16, aggregate (L2-resident), fused matvec
    dim3 blk(256);
    k_prep<<<(int)(((long)N * 8 + 255) / 256), blk, 0, stream>>>(x, meta, xs16h, xs17h, N);
    k_gather1<<<(N + 7) / 8, blk, 0, stream>>>((const uint2*)xs16h, xs17h, csr, meta,
                                               W1, b1, h1, N);

    // layer 2: matmul to packed bf16, single full-width gather pass
    k_mm2<<<(N + 15) / 16, blk, 0, stream>>>(h1, W2, meta, hs2, N);
    k_gather2<<<(N + 7) / 8, blk, 0, stream>>>((const uint4*)hs2, csr, meta,
                                               b2, batch, pool, cntg, N);

    // readout
    k_final<<<G, OUTC, 0, stream>>>(pool, cntg, Wf1, bf1, Wf2, bf2, (float*)d_out, G);
}

// Round 8
// 178.006 us; speedup vs baseline: 1.4942x; 1.0671x over previous
//
#include <hip/hip_runtime.h>

#define IN_C 17
#define HID  64
#define OUTC 32

#define CH   8192      // edges per pass-A block
#define TA   512       // pass-A threads
#define NBP  512       // padded bucket count (bucket = dst>>8; N<=131072)
#define BCAP 5632      // pass-B stage capacity (= 512*11; bucket avg ~4096)

__device__ __forceinline__ unsigned short f2bf(float f) {
    unsigned u = __float_as_uint(f);
    u += 0x7fffu + ((u >> 16) & 1u);      // round-nearest-even
    return (unsigned short)(u >> 16);
}
__device__ __forceinline__ float bflo(unsigned u) { return __uint_as_float(u << 16); }
__device__ __forceinline__ float bfhi(unsigned u) { return __uint_as_float(u & 0xffff0000u); }

// ================= pass A: bin edges by dst>>8, coalesced writes =================
__global__ __launch_bounds__(TA) void k_binA(const int* __restrict__ src,
        const int* __restrict__ dst, int E,
        int* __restrict__ outbuf, int* __restrict__ cntmat, int* __restrict__ offmat) {
    __shared__ int cnt[NBP];
    __shared__ int off[NBP];
    __shared__ int stage[CH];
    int t = threadIdx.x;
    long base = (long)blockIdx.x * CH;
    int nE = (int)(E - base); if (nE > CH) nE = CH;
    cnt[t] = 0;
    __syncthreads();
    int bk[16], pk[16], rk[16];
#pragma unroll
    for (int j = 0; j < 16; ++j) {
        int idx = t + j * TA;
        if (idx < nE) {
            long e = base + idx;
            int d = __builtin_nontemporal_load(&dst[e]);
            int s = __builtin_nontemporal_load(&src[e]);
            int b = d >> 8;
            bk[j] = b;
            pk[j] = s | ((d & 255) << 17);
            rk[j] = atomicAdd(&cnt[b], 1);
        } else bk[j] = -1;
    }
    __syncthreads();
    int c = cnt[t];
    off[t] = c;
    __syncthreads();
    int inc = c;
    for (int s = 1; s < NBP; s <<= 1) {
        int add = (t >= s) ? off[t - s] : 0;
        __syncthreads();
        inc += add; off[t] = inc;
        __syncthreads();
    }
    int excl = inc - c;
    __syncthreads();
    off[t] = excl;
    __syncthreads();
#pragma unroll
    for (int j = 0; j < 16; ++j)
        if (bk[j] >= 0) stage[off[bk[j]] + rk[j]] = pk[j];
    __syncthreads();
    for (int i = t; i < nE; i += TA) outbuf[base + i] = stage[i];
    cntmat[blockIdx.x * NBP + t] = c;
    offmat[blockIdx.x * NBP + t] = excl;
}

// ============ bucket totals + exclusive scan -> global bucket bases ============
__global__ __launch_bounds__(NBP) void k_bsum(const int* __restrict__ cntmat,
        int nblkA, int* __restrict__ bbase) {
    __shared__ int sh[NBP];
    int t = threadIdx.x;
    int s = 0;
    for (int i = 0; i < nblkA; ++i) s += cntmat[i * NBP + t];
    sh[t] = s;
    __syncthreads();
    int inc = s;
    for (int st = 1; st < NBP; st <<= 1) {
        int add = (t >= st) ? sh[t - st] : 0;
        __syncthreads();
        inc += add; sh[t] = inc;
        __syncthreads();
    }
    bbase[t] = inc - s;
}

// === pass B: per bucket, gather runs, emit CSR + meta(start,deg) + bf16 xs (fused prep) ===
__global__ __launch_bounds__(TA) void k_binB(const int* __restrict__ outbuf,
        const int* __restrict__ cntmat, const int* __restrict__ offmat,
        const int* __restrict__ bbase, int nblkA, int N,
        int* __restrict__ csr, int2* __restrict__ meta,
        const float* __restrict__ x, unsigned* __restrict__ xs16h,
        unsigned short* __restrict__ xs17h) {
    __shared__ int segc[256], sego[256], segs[256];
    __shared__ int ndeg[256], noff[256];
    __shared__ int stage[BCAP];
    int t = threadIdx.x, b = blockIdx.x;
    if (t < 256) {
        int cc = 0, ss = 0;
        if (t < nblkA) { cc = cntmat[t * NBP + b]; ss = offmat[t * NBP + b]; }
        segc[t] = cc; segs[t] = ss; sego[t] = cc;
        ndeg[t] = 0;
    }
    __syncthreads();
    {
        int c = (t < 256) ? sego[t] : 0;
        int inc = c;
        for (int s = 1; s < 256; s <<= 1) {
            int add = (t < 256 && t >= s) ? sego[t - s] : 0;
            __syncthreads();
            if (t < 256) { inc += add; sego[t] = inc; }
            __syncthreads();
        }
        if (t < 256) sego[t] = inc - c;
    }
    __syncthreads();
    int wave = t >> 6, lane = t & 63;
    for (int i = wave; i < nblkA; i += TA / 64) {
        int c = segc[i], so = sego[i];
        long gs = (long)i * CH + segs[i];
        for (int l = lane; l < c; l += 64) {
            int p = so + l;
            if (p < BCAP) stage[p] = __builtin_nontemporal_load(&outbuf[gs + l]);
        }
    }
    __syncthreads();
    int T = sego[255] + segc[255];
    if (T > BCAP) T = BCAP;
    int mypk[11], myrk[11], ne = 0;
    for (int k = t; k < T; k += TA) {
        int p = stage[k];
        int l = (p >> 17) & 255;
        myrk[ne] = atomicAdd(&ndeg[l], 1);
        mypk[ne] = p;
        ne++;
    }
    __syncthreads();
    {
        int c = (t < 256) ? ndeg[t] : 0;
        if (t < 256) noff[t] = c;
        __syncthreads();
        int inc = c;
        for (int s = 1; s < 256; s <<= 1) {
            int add = (t < 256 && t >= s) ? noff[t - s] : 0;
            __syncthreads();
            if (t < 256) { inc += add; noff[t] = inc; }
            __syncthreads();
        }
        if (t < 256) noff[t] = inc - c;
    }
    __syncthreads();
    int gb = bbase[b];
    int n0 = b << 8;
    if (t < 256 && n0 + t < N) {
        int n = n0 + t;
        meta[n] = make_int2(gb + noff[t], ndeg[t]);
        // fused prep: xs = bf16(x * dinv)
        float dinv = rsqrtf((float)(ndeg[t] + 1));
        const float* xr = x + (size_t)n * IN_C;
        unsigned* xo = xs16h + (size_t)n * 8;
#pragma unroll
        for (int w2 = 0; w2 < 8; ++w2) {
            unsigned lo = f2bf(xr[2 * w2] * dinv);
            unsigned hi = f2bf(xr[2 * w2 + 1] * dinv);
            xo[w2] = lo | (hi << 16);
        }
        xs17h[n] = f2bf(xr[16] * dinv);
    }
    for (int j = 0; j < ne; ++j) {
        int p = mypk[j];
        int l = (p >> 17) & 255;
        csr[gb + noff[l] + myrk[j]] = p & 0x1FFFF;
    }
}

// ---------- layer 1 (fused): 4 nodes/wave aggregate -> matvec1+relu (LDS) -> matvec2 -> hs2 ----------
// node = 16 lanes: 4 edge groups x 4 quads (quad = 4 bf16 ch via uint2). block = 16 nodes.
__global__ __launch_bounds__(256) void k_gather1(
        const uint2* __restrict__ xs16v, const unsigned short* __restrict__ xs17h,
        const int* __restrict__ csr, const int2* __restrict__ meta,
        const float* __restrict__ W1, const float* __restrict__ b1,
        const float* __restrict__ W2, unsigned* __restrict__ hs2, int N) {
    __shared__ float Ws1[IN_C * HID];
    __shared__ float Ws2[HID * OUTC];
    __shared__ float aggx[16][IN_C + 3];
    __shared__ float dinv_sh[16];
    __shared__ float h1sh[16][HID + 1];
    for (int i = threadIdx.x; i < IN_C * HID; i += 256) Ws1[i] = W1[i];
    for (int i = threadIdx.x; i < HID * OUTC; i += 256) Ws2[i] = W2[i];
    int ln = threadIdx.x >> 4;            // node slot 0..15
    int sl = threadIdx.x & 15;            // lane within node
    int n = blockIdx.x * 16 + ln;
    int q = sl & 3, g = sl >> 2;          // quad 0..3, edge group 0..3
    float ax = 0.f, ay = 0.f, az = 0.f, aw = 0.f, a17 = 0.f;
    if (n < N) {
        int2 m = meta[n];
        int start = m.x, cnt = m.y, end = start + cnt;
        if (g == 0) {
            uint2 v = xs16v[(size_t)n * 4 + q];
            ax = bflo(v.x); ay = bfhi(v.x); az = bflo(v.y); aw = bfhi(v.y);
            if (q == 0) a17 = bflo((unsigned)xs17h[n]);
        }
        for (int k = start + g; k < end; k += 4) {
            int s = __builtin_nontemporal_load(&csr[k]);
            uint2 v = xs16v[(size_t)s * 4 + q];
            ax += bflo(v.x); ay += bfhi(v.x); az += bflo(v.y); aw += bfhi(v.y);
            if (q == 0) a17 += bflo((unsigned)xs17h[s]);
        }
#pragma unroll
        for (int off = 4; off <= 8; off <<= 1) {    // stays within the 16-lane node
            ax += __shfl_xor(ax, off);
            ay += __shfl_xor(ay, off);
            az += __shfl_xor(az, off);
            aw += __shfl_xor(aw, off);
            a17 += __shfl_xor(a17, off);
        }
        if (g == 0) {
            aggx[ln][q * 4 + 0] = ax;
            aggx[ln][q * 4 + 1] = ay;
            aggx[ln][q * 4 + 2] = az;
            aggx[ln][q * 4 + 3] = aw;
            if (q == 0) {
                aggx[ln][16] = a17;
                dinv_sh[ln] = rsqrtf((float)(cnt + 1));
            }
        }
    }
    __syncthreads();
    // matvec1 + bias + relu: 16 nodes x 64 ch, 4 per thread -> h1sh
    int ch = threadIdx.x & 63;
    int s0 = threadIdx.x >> 6;
#pragma unroll
    for (int rep = 0; rep < 4; ++rep) {
        int slot = s0 + rep * 4;
        int nn = blockIdx.x * 16 + slot;
        if (nn < N) {
            float dot = 0.f;
#pragma unroll
            for (int k = 0; k < IN_C; ++k) dot += aggx[slot][k] * Ws1[k * HID + ch];
            h1sh[slot][ch] = fmaxf(dinv_sh[slot] * dot + b1[ch], 0.f);
        }
    }
    __syncthreads();
    // matvec2 (h1 @ W2)*dinv -> packed bf16 hs2, 1 pair per thread
    int slot = threadIdx.x >> 4;
    int tc = threadIdx.x & 15;
    int nn = blockIdx.x * 16 + slot;
    if (nn < N) {
        int c0 = tc * 2;
        float a0 = 0.f, a1 = 0.f;
#pragma unroll
        for (int k = 0; k < HID; ++k) {
            float h = h1sh[slot][k];
            a0 += h * Ws2[k * OUTC + c0];
            a1 += h * Ws2[k * OUTC + c0 + 1];
        }
        float dv = dinv_sh[slot];
        hs2[(size_t)nn * 16 + tc] = (unsigned)f2bf(a0 * dv) | ((unsigned)f2bf(a1 * dv) << 16);
    }
}

__device__ __forceinline__ void bf8_add(uint4 v, float* a) {
    a[0] += __uint_as_float(v.x << 16); a[1] += __uint_as_float(v.x & 0xffff0000u);
    a[2] += __uint_as_float(v.y << 16); a[3] += __uint_as_float(v.y & 0xffff0000u);
    a[4] += __uint_as_float(v.z << 16); a[5] += __uint_as_float(v.z & 0xffff0000u);
    a[6] += __uint_as_float(v.w << 16); a[7] += __uint_as_float(v.w & 0xffff0000u);
}

// ---------- layer 2 gather: 4 nodes/wave (4 groups x 4 quads, uint4=8ch/lane) + pool ----------
__global__ __launch_bounds__(256) void k_gather2(
        const uint4* __restrict__ hs2v, const int* __restrict__ csr,
        const int2* __restrict__ meta, const float* __restrict__ b2,
        const int* __restrict__ batch, float* pool, float* cntg, int N) {
    __shared__ float cont[16][OUTC];
    __shared__ int bsh[16];
    int ln = threadIdx.x >> 4;            // node slot 0..15
    int sl = threadIdx.x & 15;
    int n = blockIdx.x * 16 + ln;
    int q = sl & 3, g = sl >> 2;
    float a[8] = {0.f, 0.f, 0.f, 0.f, 0.f, 0.f, 0.f, 0.f};
    if (n < N) {
        int2 m = meta[n];
        int start = m.x, cnt = m.y, end = start + cnt;
        if (g == 0) bf8_add(hs2v[(size_t)n * 4 + q], a);   // self loop
        for (int k = start + g; k < end; k += 4) {
            int s = __builtin_nontemporal_load(&csr[k]);
            bf8_add(hs2v[(size_t)s * 4 + q], a);
        }
#pragma unroll
        for (int off = 4; off <= 8; off <<= 1) {
#pragma unroll
            for (int j = 0; j < 8; ++j) a[j] += __shfl_xor(a[j], off);
        }
        if (g == 0) {
            float dinv = rsqrtf((float)(cnt + 1));
#pragma unroll
            for (int j = 0; j < 8; ++j)
                cont[ln][q * 8 + j] = dinv * a[j] + b2[q * 8 + j];
        }
        if (sl == 0) bsh[ln] = batch[n];
    } else {
        if (g == 0) {
#pragma unroll
            for (int j = 0; j < 8; ++j) cont[ln][q * 8 + j] = 0.f;
        }
        if (sl == 0) bsh[ln] = -1;
    }
    __syncthreads();
    if (threadIdx.x < OUTC) {
        int c = threadIdx.x;
        float run = 0.f; int cur = -1;
        for (int j = 0; j < 16; ++j) {
            int bj = bsh[j];
            if (bj < 0) continue;
            if (bj == cur) run += cont[j][c];
            else {
                if (cur >= 0) atomicAdd(&pool[(size_t)cur * OUTC + c], run);
                cur = bj; run = cont[j][c];
            }
        }
        if (cur >= 0) atomicAdd(&pool[(size_t)cur * OUTC + c], run);
        if (c == 0) {
            float crun = 0.f; cur = -1;
            for (int j = 0; j < 16; ++j) {
                int bj = bsh[j];
                if (bj < 0) continue;
                if (bj == cur) crun += 1.f;
                else {
                    if (cur >= 0) atomicAdd(&cntg[cur], crun);
                    cur = bj; crun = 1.f;
                }
            }
            if (cur >= 0) atomicAdd(&cntg[cur], crun);
        }
    }
}

// ---------- final: pooled mean -> fc1(relu) -> fc2 ----------
__global__ void k_final(const float* __restrict__ pool, const float* __restrict__ cntg,
                        const float* __restrict__ Wf1, const float* __restrict__ bf1,
                        const float* __restrict__ Wf2, const float* __restrict__ bf2,
                        float* out, int G) {
    __shared__ float p[OUTC], t[OUTC];
    int g = blockIdx.x;
    int c = threadIdx.x;
    float csafe = fmaxf(cntg[g], 1.0f);
    p[c] = pool[g * OUTC + c] / csafe;
    __syncthreads();
    float acc = bf1[c];
#pragma unroll
    for (int k = 0; k < OUTC; ++k) acc += p[k] * Wf1[k * OUTC + c];
    t[c] = fmaxf(acc, 0.f);
    __syncthreads();
    float acc2 = bf2[c];
#pragma unroll
    for (int k = 0; k < OUTC; ++k) acc2 += t[k] * Wf2[k * OUTC + c];
    out[g * OUTC + c] = acc2;
}

extern "C" void kernel_launch(void* const* d_in, const int* in_sizes, int n_in,
                              void* d_out, int out_size, void* d_ws, size_t ws_size,
                              hipStream_t stream) {
    const float* x    = (const float*)d_in[0];
    const int*   ei   = (const int*)  d_in[1];
    const int*   batch= (const int*)  d_in[2];
    const float* W1   = (const float*)d_in[3];
    const float* b1   = (const float*)d_in[4];
    const float* W2   = (const float*)d_in[5];
    const float* b2   = (const float*)d_in[6];
    const float* Wf1  = (const float*)d_in[7];
    const float* bf1  = (const float*)d_in[8];
    const float* Wf2  = (const float*)d_in[9];
    const float* bf2  = (const float*)d_in[10];

    const int N = in_sizes[0] / IN_C;
    const int E = in_sizes[1] / 2;
    const int G = out_size / OUTC;
    const int* src = ei;
    const int* dst = ei + E;

    const int nblkA = (E + CH - 1) / CH;
    const int NB    = (N + 255) >> 8;

    // ---- workspace layout ----
    char* w = (char*)d_ws;
    int*   csr      = (int*)w;   w += (size_t)E * sizeof(int);
    int2*  meta     = (int2*)w;  w += (size_t)N * sizeof(int2);
    unsigned* xs16h = (unsigned*)w; w += (size_t)N * 8 * sizeof(unsigned);
    unsigned* hs2   = (unsigned*)w; w += (size_t)N * 16 * sizeof(unsigned);
    unsigned short* xs17h = (unsigned short*)w; w += (size_t)N * sizeof(unsigned short);
    w = (char*)(((size_t)w + 15) & ~(size_t)15);
    float* pool     = (float*)w; w += (size_t)G * OUTC * sizeof(float);
    float* cntg     = (float*)w; w += (size_t)G * sizeof(float);
    w = (char*)(((size_t)w + 15) & ~(size_t)15);
    int*   outbuf   = (int*)w;   w += (size_t)E * sizeof(int);
    int*   cntmat   = (int*)w;   w += (size_t)nblkA * NBP * sizeof(int);
    int*   offmat   = (int*)w;   w += (size_t)nblkA * NBP * sizeof(int);
    int*   bbase    = (int*)w;   w += NBP * sizeof(int);

    hipMemsetAsync(pool, 0, (size_t)(G * OUTC + G) * sizeof(float), stream);

    // CSR build (counting sort) + fused x prep
    k_binA<<<nblkA, TA, 0, stream>>>(src, dst, E, outbuf, cntmat, offmat);
    k_bsum<<<1, NBP, 0, stream>>>(cntmat, nblkA, bbase);
    k_binB<<<NB, TA, 0, stream>>>(outbuf, cntmat, offmat, bbase, nblkA, N,
                                  csr, meta, x, xs16h, xs17h);

    // layer 1 fused: aggregate x -> matvec1+relu -> matvec2 -> packed bf16 hs2
    dim3 blk(256);
    k_gather1<<<(N + 15) / 16, blk, 0, stream>>>((const uint2*)xs16h, xs17h, csr, meta,
                                                 W1, b1, W2, hs2, N);

    // layer 2: single full-width gather + pool
    k_gather2<<<(N + 15) / 16, blk, 0, stream>>>((const uint4*)hs2, csr, meta,
                                                 b2, batch, pool, cntg, N);

    // readout
    k_final<<<G, OUTC, 0, stream>>>(pool, cntg, Wf1, bf1, Wf2, bf2, (float*)d_out, G);
}

// Round 9
// 170.324 us; speedup vs baseline: 1.5616x; 1.0451x over previous
//
#include <hip/hip_runtime.h>

#define IN_C 17
#define HID  64
#define OUTC 32

#define CH   8192      // edges per pass-A block
#define TA   512       // pass-A threads
#define NBP  512       // padded bucket count (bucket = dst>>8; N<=131072)
#define BCAP 5632      // pass-B stage capacity (= 512*11; bucket avg ~4096)

__device__ __forceinline__ unsigned short f2bf(float f) {
    unsigned u = __float_as_uint(f);
    u += 0x7fffu + ((u >> 16) & 1u);      // round-nearest-even
    return (unsigned short)(u >> 16);
}
__device__ __forceinline__ float bflo(unsigned u) { return __uint_as_float(u << 16); }
__device__ __forceinline__ float bfhi(unsigned u) { return __uint_as_float(u & 0xffff0000u); }

// ================= pass A: bin edges by dst>>8, coalesced writes =================
__global__ __launch_bounds__(TA) void k_binA(const int* __restrict__ src,
        const int* __restrict__ dst, int E,
        int* __restrict__ outbuf, int* __restrict__ cntmat, int* __restrict__ offmat) {
    __shared__ int cnt[NBP];
    __shared__ int off[NBP];
    __shared__ int stage[CH];
    int t = threadIdx.x;
    long base = (long)blockIdx.x * CH;
    int nE = (int)(E - base); if (nE > CH) nE = CH;
    cnt[t] = 0;
    __syncthreads();
    int bk[16], pk[16], rk[16];
#pragma unroll
    for (int j = 0; j < 16; ++j) {
        int idx = t + j * TA;
        if (idx < nE) {
            long e = base + idx;
            int d = __builtin_nontemporal_load(&dst[e]);
            int s = __builtin_nontemporal_load(&src[e]);
            int b = d >> 8;
            bk[j] = b;
            pk[j] = s | ((d & 255) << 17);
            rk[j] = atomicAdd(&cnt[b], 1);
        } else bk[j] = -1;
    }
    __syncthreads();
    int c = cnt[t];
    off[t] = c;
    __syncthreads();
    int inc = c;
    for (int s = 1; s < NBP; s <<= 1) {
        int add = (t >= s) ? off[t - s] : 0;
        __syncthreads();
        inc += add; off[t] = inc;
        __syncthreads();
    }
    int excl = inc - c;
    __syncthreads();
    off[t] = excl;
    __syncthreads();
#pragma unroll
    for (int j = 0; j < 16; ++j)
        if (bk[j] >= 0) stage[off[bk[j]] + rk[j]] = pk[j];
    __syncthreads();
    for (int i = t; i < nE; i += TA) outbuf[base + i] = stage[i];
    cntmat[blockIdx.x * NBP + t] = c;
    offmat[blockIdx.x * NBP + t] = excl;
}

// ============ bucket totals + exclusive scan -> global bucket bases ============
__global__ __launch_bounds__(NBP) void k_bsum(const int* __restrict__ cntmat,
        int nblkA, int* __restrict__ bbase) {
    __shared__ int sh[NBP];
    int t = threadIdx.x;
    int s = 0;
    for (int i = 0; i < nblkA; ++i) s += cntmat[i * NBP + t];
    sh[t] = s;
    __syncthreads();
    int inc = s;
    for (int st = 1; st < NBP; st <<= 1) {
        int add = (t >= st) ? sh[t - st] : 0;
        __syncthreads();
        inc += add; sh[t] = inc;
        __syncthreads();
    }
    bbase[t] = inc - s;
}

// === pass B: per bucket, gather runs, emit CSR + meta(start,deg) + bf16 xs (fused prep) ===
__global__ __launch_bounds__(TA) void k_binB(const int* __restrict__ outbuf,
        const int* __restrict__ cntmat, const int* __restrict__ offmat,
        const int* __restrict__ bbase, int nblkA, int N,
        int* __restrict__ csr, int2* __restrict__ meta,
        const float* __restrict__ x, unsigned* __restrict__ xs16h,
        unsigned short* __restrict__ xs17h) {
    __shared__ int segc[256], sego[256], segs[256];
    __shared__ int ndeg[256], noff[256];
    __shared__ int stage[BCAP];
    int t = threadIdx.x, b = blockIdx.x;
    if (t < 256) {
        int cc = 0, ss = 0;
        if (t < nblkA) { cc = cntmat[t * NBP + b]; ss = offmat[t * NBP + b]; }
        segc[t] = cc; segs[t] = ss; sego[t] = cc;
        ndeg[t] = 0;
    }
    __syncthreads();
    {
        int c = (t < 256) ? sego[t] : 0;
        int inc = c;
        for (int s = 1; s < 256; s <<= 1) {
            int add = (t < 256 && t >= s) ? sego[t - s] : 0;
            __syncthreads();
            if (t < 256) { inc += add; sego[t] = inc; }
            __syncthreads();
        }
        if (t < 256) sego[t] = inc - c;
    }
    __syncthreads();
    int wave = t >> 6, lane = t & 63;
    for (int i = wave; i < nblkA; i += TA / 64) {
        int c = segc[i], so = sego[i];
        long gs = (long)i * CH + segs[i];
        for (int l = lane; l < c; l += 64) {
            int p = so + l;
            if (p < BCAP) stage[p] = __builtin_nontemporal_load(&outbuf[gs + l]);
        }
    }
    __syncthreads();
    int T = sego[255] + segc[255];
    if (T > BCAP) T = BCAP;
    int mypk[11], myrk[11], ne = 0;
    for (int k = t; k < T; k += TA) {
        int p = stage[k];
        int l = (p >> 17) & 255;
        myrk[ne] = atomicAdd(&ndeg[l], 1);
        mypk[ne] = p;
        ne++;
    }
    __syncthreads();
    {
        int c = (t < 256) ? ndeg[t] : 0;
        if (t < 256) noff[t] = c;
        __syncthreads();
        int inc = c;
        for (int s = 1; s < 256; s <<= 1) {
            int add = (t < 256 && t >= s) ? noff[t - s] : 0;
            __syncthreads();
            if (t < 256) { inc += add; noff[t] = inc; }
            __syncthreads();
        }
        if (t < 256) noff[t] = inc - c;
    }
    __syncthreads();
    int gb = bbase[b];
    int n0 = b << 8;
    if (t < 256 && n0 + t < N) {
        int n = n0 + t;
        meta[n] = make_int2(gb + noff[t], ndeg[t]);
        // fused prep: xs = bf16(x * dinv)
        float dinv = rsqrtf((float)(ndeg[t] + 1));
        const float* xr = x + (size_t)n * IN_C;
        unsigned* xo = xs16h + (size_t)n * 8;
#pragma unroll
        for (int w2 = 0; w2 < 8; ++w2) {
            unsigned lo = f2bf(xr[2 * w2] * dinv);
            unsigned hi = f2bf(xr[2 * w2 + 1] * dinv);
            xo[w2] = lo | (hi << 16);
        }
        xs17h[n] = f2bf(xr[16] * dinv);
    }
    for (int j = 0; j < ne; ++j) {
        int p = mypk[j];
        int l = (p >> 17) & 255;
        csr[gb + noff[l] + myrk[j]] = p & 0x1FFFF;
    }
}

// ---------- layer 1 (fused): aggregate -> matvec1 (W1 in regs) -> matvec2 (bf16 W2) ----------
// node = 16 lanes: 4 edge groups x 4 quads. block = 16 nodes.
__global__ __launch_bounds__(256) void k_gather1(
        const uint2* __restrict__ xs16v, const unsigned short* __restrict__ xs17h,
        const int* __restrict__ csr, const int2* __restrict__ meta,
        const float* __restrict__ W1, const float* __restrict__ b1,
        const float* __restrict__ W2, unsigned* __restrict__ hs2, int N) {
    __shared__ __align__(16) float aggx[16][20];      // 17 used, pad to 20 (80B rows)
    __shared__ float dinv_sh[16];
    __shared__ __align__(16) float h1sh[16][68];      // 64 used, pad to 68 (272B rows)
    __shared__ __align__(16) unsigned w2bt[16][68];   // [tc][k] bf16 ch-pair, 64 used

    int tid = threadIdx.x;
    // pack W2 into LDS as bf16 channel pairs (one-time)
    for (int i = tid; i < 16 * 64; i += 256) {
        int tc = i >> 6, k = i & 63;
        w2bt[tc][k] = (unsigned)f2bf(W2[k * OUTC + 2 * tc]) |
                      ((unsigned)f2bf(W2[k * OUTC + 2 * tc + 1]) << 16);
    }
    // W1 row cached in registers: channel = tid & 63 (same for all 4 node-slots)
    int ch = tid & 63;
    float w1r[IN_C];
#pragma unroll
    for (int k = 0; k < IN_C; ++k) w1r[k] = W1[k * HID + ch];
    float b1v = b1[ch];

    int ln = tid >> 4;            // node slot 0..15
    int sl = tid & 15;            // lane within node
    int n = blockIdx.x * 16 + ln;
    int q = sl & 3, g = sl >> 2;  // quad 0..3, edge group 0..3
    float ax = 0.f, ay = 0.f, az = 0.f, aw = 0.f, a17 = 0.f;
    if (n < N) {
        int2 m = meta[n];
        int start = m.x, cnt = m.y, end = start + cnt;
        if (g == 0) {
            uint2 v = xs16v[(size_t)n * 4 + q];
            ax = bflo(v.x); ay = bfhi(v.x); az = bflo(v.y); aw = bfhi(v.y);
            if (q == 0) a17 = bflo((unsigned)xs17h[n]);
        }
        for (int k = start + g; k < end; k += 4) {
            int s = __builtin_nontemporal_load(&csr[k]);
            uint2 v = xs16v[(size_t)s * 4 + q];
            ax += bflo(v.x); ay += bfhi(v.x); az += bflo(v.y); aw += bfhi(v.y);
            if (q == 0) a17 += bflo((unsigned)xs17h[s]);
        }
#pragma unroll
        for (int off = 4; off <= 8; off <<= 1) {    // stays within the 16-lane node
            ax += __shfl_xor(ax, off);
            ay += __shfl_xor(ay, off);
            az += __shfl_xor(az, off);
            aw += __shfl_xor(aw, off);
            a17 += __shfl_xor(a17, off);
        }
        if (g == 0) {
            aggx[ln][q * 4 + 0] = ax;
            aggx[ln][q * 4 + 1] = ay;
            aggx[ln][q * 4 + 2] = az;
            aggx[ln][q * 4 + 3] = aw;
            if (q == 0) {
                aggx[ln][16] = a17;
                dinv_sh[ln] = rsqrtf((float)(cnt + 1));
            }
        }
    }
    __syncthreads();
    // matvec1 + bias + relu: 4 slots per thread, W1 row reused from regs
    int s0 = tid >> 6;
#pragma unroll
    for (int rep = 0; rep < 4; ++rep) {
        int slot = s0 + rep * 4;
        int nn = blockIdx.x * 16 + slot;
        if (nn < N) {
            const float4* ap = (const float4*)aggx[slot];
            float4 A0 = ap[0], A1 = ap[1], A2 = ap[2], A3 = ap[3];
            float a16 = aggx[slot][16];
            float dot = A0.x * w1r[0]  + A0.y * w1r[1]  + A0.z * w1r[2]  + A0.w * w1r[3]
                      + A1.x * w1r[4]  + A1.y * w1r[5]  + A1.z * w1r[6]  + A1.w * w1r[7]
                      + A2.x * w1r[8]  + A2.y * w1r[9]  + A2.z * w1r[10] + A2.w * w1r[11]
                      + A3.x * w1r[12] + A3.y * w1r[13] + A3.z * w1r[14] + A3.w * w1r[15]
                      + a16  * w1r[16];
            h1sh[slot][ch] = fmaxf(dinv_sh[slot] * dot + b1v, 0.f);
        }
    }
    __syncthreads();
    // matvec2 (h1 @ W2)*dinv -> packed bf16 hs2; b128 reads, W2 in bf16 pairs
    int slot = tid >> 4;
    int tc = tid & 15;
    int nn = blockIdx.x * 16 + slot;
    if (nn < N) {
        float a0 = 0.f, a1 = 0.f;
        const float4* hp = (const float4*)h1sh[slot];
        const uint4*  wp = (const uint4*)w2bt[tc];
#pragma unroll
        for (int kg = 0; kg < 16; ++kg) {
            float4 hv = hp[kg];
            uint4  wv = wp[kg];
            a0 += hv.x * bflo(wv.x) + hv.y * bflo(wv.y) + hv.z * bflo(wv.z) + hv.w * bflo(wv.w);
            a1 += hv.x * bfhi(wv.x) + hv.y * bfhi(wv.y) + hv.z * bfhi(wv.z) + hv.w * bfhi(wv.w);
        }
        float dv = dinv_sh[slot];
        hs2[(size_t)nn * 16 + tc] = (unsigned)f2bf(a0 * dv) | ((unsigned)f2bf(a1 * dv) << 16);
    }
}

__device__ __forceinline__ void bf8_add(uint4 v, float* a) {
    a[0] += __uint_as_float(v.x << 16); a[1] += __uint_as_float(v.x & 0xffff0000u);
    a[2] += __uint_as_float(v.y << 16); a[3] += __uint_as_float(v.y & 0xffff0000u);
    a[4] += __uint_as_float(v.z << 16); a[5] += __uint_as_float(v.z & 0xffff0000u);
    a[6] += __uint_as_float(v.w << 16); a[7] += __uint_as_float(v.w & 0xffff0000u);
}

// ---------- layer 2 gather: 4 nodes/wave (4 groups x 4 quads, uint4=8ch/lane) + pool ----------
__global__ __launch_bounds__(256) void k_gather2(
        const uint4* __restrict__ hs2v, const int* __restrict__ csr,
        const int2* __restrict__ meta, const float* __restrict__ b2,
        const int* __restrict__ batch, float* pool, float* cntg, int N) {
    __shared__ float cont[16][OUTC];
    __shared__ int bsh[16];
    int ln = threadIdx.x >> 4;            // node slot 0..15
    int sl = threadIdx.x & 15;
    int n = blockIdx.x * 16 + ln;
    int q = sl & 3, g = sl >> 2;
    float a[8] = {0.f, 0.f, 0.f, 0.f, 0.f, 0.f, 0.f, 0.f};
    if (n < N) {
        int2 m = meta[n];
        int start = m.x, cnt = m.y, end = start + cnt;
        if (g == 0) bf8_add(hs2v[(size_t)n * 4 + q], a);   // self loop
        for (int k = start + g; k < end; k += 4) {
            int s = __builtin_nontemporal_load(&csr[k]);
            bf8_add(hs2v[(size_t)s * 4 + q], a);
        }
#pragma unroll
        for (int off = 4; off <= 8; off <<= 1) {
#pragma unroll
            for (int j = 0; j < 8; ++j) a[j] += __shfl_xor(a[j], off);
        }
        if (g == 0) {
            float dinv = rsqrtf((float)(cnt + 1));
#pragma unroll
            for (int j = 0; j < 8; ++j)
                cont[ln][q * 8 + j] = dinv * a[j] + b2[q * 8 + j];
        }
        if (sl == 0) bsh[ln] = batch[n];
    } else {
        if (g == 0) {
#pragma unroll
            for (int j = 0; j < 8; ++j) cont[ln][q * 8 + j] = 0.f;
        }
        if (sl == 0) bsh[ln] = -1;
    }
    __syncthreads();
    if (threadIdx.x < OUTC) {
        int c = threadIdx.x;
        float run = 0.f; int cur = -1;
        for (int j = 0; j < 16; ++j) {
            int bj = bsh[j];
            if (bj < 0) continue;
            if (bj == cur) run += cont[j][c];
            else {
                if (cur >= 0) atomicAdd(&pool[(size_t)cur * OUTC + c], run);
                cur = bj; run = cont[j][c];
            }
        }
        if (cur >= 0) atomicAdd(&pool[(size_t)cur * OUTC + c], run);
        if (c == 0) {
            float crun = 0.f; cur = -1;
            for (int j = 0; j < 16; ++j) {
                int bj = bsh[j];
                if (bj < 0) continue;
                if (bj == cur) crun += 1.f;
                else {
                    if (cur >= 0) atomicAdd(&cntg[cur], crun);
                    cur = bj; crun = 1.f;
                }
            }
            if (cur >= 0) atomicAdd(&cntg[cur], crun);
        }
    }
}

// ---------- final: pooled mean -> fc1(relu) -> fc2 ----------
__global__ void k_final(const float* __restrict__ pool, const float* __restrict__ cntg,
                        const float* __restrict__ Wf1, const float* __restrict__ bf1,
                        const float* __restrict__ Wf2, const float* __restrict__ bf2,
                        float* out, int G) {
    __shared__ float p[OUTC], t[OUTC];
    int g = blockIdx.x;
    int c = threadIdx.x;
    float csafe = fmaxf(cntg[g], 1.0f);
    p[c] = pool[g * OUTC + c] / csafe;
    __syncthreads();
    float acc = bf1[c];
#pragma unroll
    for (int k = 0; k < OUTC; ++k) acc += p[k] * Wf1[k * OUTC + c];
    t[c] = fmaxf(acc, 0.f);
    __syncthreads();
    float acc2 = bf2[c];
#pragma unroll
    for (int k = 0; k < OUTC; ++k) acc2 += t[k] * Wf2[k * OUTC + c];
    out[g * OUTC + c] = acc2;
}

extern "C" void kernel_launch(void* const* d_in, const int* in_sizes, int n_in,
                              void* d_out, int out_size, void* d_ws, size_t ws_size,
                              hipStream_t stream) {
    const float* x    = (const float*)d_in[0];
    const int*   ei   = (const int*)  d_in[1];
    const int*   batch= (const int*)  d_in[2];
    const float* W1   = (const float*)d_in[3];
    const float* b1   = (const float*)d_in[4];
    const float* W2   = (const float*)d_in[5];
    const float* b2   = (const float*)d_in[6];
    const float* Wf1  = (const float*)d_in[7];
    const float* bf1  = (const float*)d_in[8];
    const float* Wf2  = (const float*)d_in[9];
    const float* bf2  = (const float*)d_in[10];

    const int N = in_sizes[0] / IN_C;
    const int E = in_sizes[1] / 2;
    const int G = out_size / OUTC;
    const int* src = ei;
    const int* dst = ei + E;

    const int nblkA = (E + CH - 1) / CH;
    const int NB    = (N + 255) >> 8;

    // ---- workspace layout ----
    char* w = (char*)d_ws;
    int*   csr      = (int*)w;   w += (size_t)E * sizeof(int);
    int2*  meta     = (int2*)w;  w += (size_t)N * sizeof(int2);
    unsigned* xs16h = (unsigned*)w; w += (size_t)N * 8 * sizeof(unsigned);
    unsigned* hs2   = (unsigned*)w; w += (size_t)N * 16 * sizeof(unsigned);
    unsigned short* xs17h = (unsigned short*)w; w += (size_t)N * sizeof(unsigned short);
    w = (char*)(((size_t)w + 15) & ~(size_t)15);
    float* pool     = (float*)w; w += (size_t)G * OUTC * sizeof(float);
    float* cntg     = (float*)w; w += (size_t)G * sizeof(float);
    w = (char*)(((size_t)w + 15) & ~(size_t)15);
    int*   outbuf   = (int*)w;   w += (size_t)E * sizeof(int);
    int*   cntmat   = (int*)w;   w += (size_t)nblkA * NBP * sizeof(int);
    int*   offmat   = (int*)w;   w += (size_t)nblkA * NBP * sizeof(int);
    int*   bbase    = (int*)w;   w += NBP * sizeof(int);

    hipMemsetAsync(pool, 0, (size_t)(G * OUTC + G) * sizeof(float), stream);

    // CSR build (counting sort) + fused x prep
    k_binA<<<nblkA, TA, 0, stream>>>(src, dst, E, outbuf, cntmat, offmat);
    k_bsum<<<1, NBP, 0, stream>>>(cntmat, nblkA, bbase);
    k_binB<<<NB, TA, 0, stream>>>(outbuf, cntmat, offmat, bbase, nblkA, N,
                                  csr, meta, x, xs16h, xs17h);

    // layer 1 fused: aggregate x -> matvec1+relu -> matvec2 -> packed bf16 hs2
    dim3 blk(256);
    k_gather1<<<(N + 15) / 16, blk, 0, stream>>>((const uint2*)xs16h, xs17h, csr, meta,
                                                 W1, b1, W2, hs2, N);

    // layer 2: single full-width gather + pool
    k_gather2<<<(N + 15) / 16, blk, 0, stream>>>((const uint4*)hs2, csr, meta,
                                                 b2, batch, pool, cntg, N);

    // readout
    k_final<<<G, OUTC, 0, stream>>>(pool, cntg, Wf1, bf1, Wf2, bf2, (float*)d_out, G);
}

// Round 10
// 162.763 us; speedup vs baseline: 1.6342x; 1.0465x over previous
//
#include <hip/hip_runtime.h>

#define IN_C 17
#define HID  64
#define OUTC 32

#define CH   8192      // edges per pass-A block
#define TA   512       // pass-A threads
#define NBP  512       // padded bucket count (bucket = dst>>8; N<=131072)
#define BCAP 5632      // pass-B stage capacity (= 512*11; bucket avg ~4096)

__device__ __forceinline__ unsigned short f2bf(float f) {
    unsigned u = __float_as_uint(f);
    u += 0x7fffu + ((u >> 16) & 1u);      // round-nearest-even
    return (unsigned short)(u >> 16);
}
__device__ __forceinline__ float bflo(unsigned u) { return __uint_as_float(u << 16); }
__device__ __forceinline__ float bfhi(unsigned u) { return __uint_as_float(u & 0xffff0000u); }

// ================= pass A: bin edges by dst>>8, coalesced writes =================
__global__ __launch_bounds__(TA) void k_binA(const int* __restrict__ src,
        const int* __restrict__ dst, int E,
        int* __restrict__ outbuf, int* __restrict__ cntmat, int* __restrict__ offmat) {
    __shared__ int cnt[NBP];
    __shared__ int off[NBP];
    __shared__ int stage[CH];
    int t = threadIdx.x;
    long base = (long)blockIdx.x * CH;
    int nE = (int)(E - base); if (nE > CH) nE = CH;
    cnt[t] = 0;
    __syncthreads();
    int bk[16], pk[16], rk[16];
#pragma unroll
    for (int j = 0; j < 16; ++j) {
        int idx = t + j * TA;
        if (idx < nE) {
            long e = base + idx;
            int d = __builtin_nontemporal_load(&dst[e]);
            int s = __builtin_nontemporal_load(&src[e]);
            int b = d >> 8;
            bk[j] = b;
            pk[j] = s | ((d & 255) << 17);
            rk[j] = atomicAdd(&cnt[b], 1);
        } else bk[j] = -1;
    }
    __syncthreads();
    int c = cnt[t];
    off[t] = c;
    __syncthreads();
    int inc = c;
    for (int s = 1; s < NBP; s <<= 1) {
        int add = (t >= s) ? off[t - s] : 0;
        __syncthreads();
        inc += add; off[t] = inc;
        __syncthreads();
    }
    int excl = inc - c;
    __syncthreads();
    off[t] = excl;
    __syncthreads();
#pragma unroll
    for (int j = 0; j < 16; ++j)
        if (bk[j] >= 0) stage[off[bk[j]] + rk[j]] = pk[j];
    __syncthreads();
    for (int i = t; i < nE; i += TA) outbuf[base + i] = stage[i];
    cntmat[blockIdx.x * NBP + t] = c;
    offmat[blockIdx.x * NBP + t] = excl;
}

// ============ bucket totals + exclusive scan -> global bucket bases ============
__global__ __launch_bounds__(NBP) void k_bsum(const int* __restrict__ cntmat,
        int nblkA, int* __restrict__ bbase) {
    __shared__ int sh[NBP];
    int t = threadIdx.x;
    int s = 0;
    for (int i = 0; i < nblkA; ++i) s += cntmat[i * NBP + t];
    sh[t] = s;
    __syncthreads();
    int inc = s;
    for (int st = 1; st < NBP; st <<= 1) {
        int add = (t >= st) ? sh[t - st] : 0;
        __syncthreads();
        inc += add; sh[t] = inc;
        __syncthreads();
    }
    bbase[t] = inc - s;
}

// === pass B: per bucket, gather runs, emit CSR + meta(start,deg) + bf16 xs (fused prep) ===
__global__ __launch_bounds__(TA) void k_binB(const int* __restrict__ outbuf,
        const int* __restrict__ cntmat, const int* __restrict__ offmat,
        const int* __restrict__ bbase, int nblkA, int N,
        int* __restrict__ csr, int2* __restrict__ meta,
        const float* __restrict__ x, unsigned* __restrict__ xs16h,
        unsigned short* __restrict__ xs17h) {
    __shared__ int segc[256], sego[256], segs[256];
    __shared__ int ndeg[256], noff[256];
    __shared__ int stage[BCAP];
    int t = threadIdx.x, b = blockIdx.x;
    if (t < 256) {
        int cc = 0, ss = 0;
        if (t < nblkA) { cc = cntmat[t * NBP + b]; ss = offmat[t * NBP + b]; }
        segc[t] = cc; segs[t] = ss; sego[t] = cc;
        ndeg[t] = 0;
    }
    __syncthreads();
    {
        int c = (t < 256) ? sego[t] : 0;
        int inc = c;
        for (int s = 1; s < 256; s <<= 1) {
            int add = (t < 256 && t >= s) ? sego[t - s] : 0;
            __syncthreads();
            if (t < 256) { inc += add; sego[t] = inc; }
            __syncthreads();
        }
        if (t < 256) sego[t] = inc - c;
    }
    __syncthreads();
    int wave = t >> 6, lane = t & 63;
    for (int i = wave; i < nblkA; i += TA / 64) {
        int c = segc[i], so = sego[i];
        long gs = (long)i * CH + segs[i];
        for (int l = lane; l < c; l += 64) {
            int p = so + l;
            if (p < BCAP) stage[p] = __builtin_nontemporal_load(&outbuf[gs + l]);
        }
    }
    __syncthreads();
    int T = sego[255] + segc[255];
    if (T > BCAP) T = BCAP;
    int mypk[11], myrk[11], ne = 0;
    for (int k = t; k < T; k += TA) {
        int p = stage[k];
        int l = (p >> 17) & 255;
        myrk[ne] = atomicAdd(&ndeg[l], 1);
        mypk[ne] = p;
        ne++;
    }
    __syncthreads();
    {
        int c = (t < 256) ? ndeg[t] : 0;
        if (t < 256) noff[t] = c;
        __syncthreads();
        int inc = c;
        for (int s = 1; s < 256; s <<= 1) {
            int add = (t < 256 && t >= s) ? noff[t - s] : 0;
            __syncthreads();
            if (t < 256) { inc += add; noff[t] = inc; }
            __syncthreads();
        }
        if (t < 256) noff[t] = inc - c;
    }
    __syncthreads();
    int gb = bbase[b];
    int n0 = b << 8;
    if (t < 256 && n0 + t < N) {
        int n = n0 + t;
        meta[n] = make_int2(gb + noff[t], ndeg[t]);
        // fused prep: xs = bf16(x * dinv)
        float dinv = rsqrtf((float)(ndeg[t] + 1));
        const float* xr = x + (size_t)n * IN_C;
        unsigned* xo = xs16h + (size_t)n * 8;
#pragma unroll
        for (int w2 = 0; w2 < 8; ++w2) {
            unsigned lo = f2bf(xr[2 * w2] * dinv);
            unsigned hi = f2bf(xr[2 * w2 + 1] * dinv);
            xo[w2] = lo | (hi << 16);
        }
        xs17h[n] = f2bf(xr[16] * dinv);
    }
    for (int j = 0; j < ne; ++j) {
        int p = mypk[j];
        int l = (p >> 17) & 255;
        csr[gb + noff[l] + myrk[j]] = p & 0x1FFFF;
    }
}

__device__ __forceinline__ void unp8(uint4 v, float* a) {
    a[0] += bflo(v.x); a[1] += bfhi(v.x);
    a[2] += bflo(v.y); a[3] += bfhi(v.y);
    a[4] += bflo(v.z); a[5] += bfhi(v.z);
    a[6] += bflo(v.w); a[7] += bfhi(v.w);
}

// ---------- layer 1 (fused): 1 lane/edge gather -> fold -> matvec1 -> matvec2 ----------
// node = 16 lanes = 16 edge groups; each lane reads full 32B row. block = 16 nodes.
__global__ __launch_bounds__(256) void k_gather1(
        const uint4* __restrict__ xs16v, const unsigned short* __restrict__ xs17h,
        const int* __restrict__ csr, const int2* __restrict__ meta,
        const float* __restrict__ W1, const float* __restrict__ b1,
        const float* __restrict__ W2, unsigned* __restrict__ hs2, int N) {
    __shared__ __align__(16) float aggx[16][20];      // 17 used
    __shared__ float dinv_sh[16];
    __shared__ __align__(16) float h1sh[16][68];      // 64 used
    __shared__ __align__(16) float w2c0[16][68];      // W2[:,2tc]   f32
    __shared__ __align__(16) float w2c1[16][68];      // W2[:,2tc+1] f32

    int tid = threadIdx.x;
    for (int i = tid; i < 16 * 64; i += 256) {
        int tc = i >> 6, k = i & 63;
        w2c0[tc][k] = W2[k * OUTC + 2 * tc];
        w2c1[tc][k] = W2[k * OUTC + 2 * tc + 1];
    }
    int ch = tid & 63;
    float w1r[IN_C];
#pragma unroll
    for (int k = 0; k < IN_C; ++k) w1r[k] = W1[k * HID + ch];
    float b1v = b1[ch];

    int ln = tid >> 4, sl = tid & 15;
    int n = blockIdx.x * 16 + ln;
    float a[16];
#pragma unroll
    for (int j = 0; j < 16; ++j) a[j] = 0.f;
    float a17 = 0.f;
    if (n < N) {
        int2 m = meta[n];
        int start = m.x, cnt = m.y, end = start + cnt;
        for (int k = start + sl; k < end; k += 16) {
            int s = __builtin_nontemporal_load(&csr[k]);
            uint4 v0 = xs16v[(size_t)s * 2];
            uint4 v1 = xs16v[(size_t)s * 2 + 1];
            unp8(v0, a); unp8(v1, a + 8);
            a17 += bflo((unsigned)xs17h[s]);
        }
        if (sl == 0) {                                   // self loop
            uint4 v0 = xs16v[(size_t)n * 2];
            uint4 v1 = xs16v[(size_t)n * 2 + 1];
            unp8(v0, a); unp8(v1, a + 8);
            a17 += bflo((unsigned)xs17h[n]);
            dinv_sh[ln] = rsqrtf((float)(cnt + 1));
        }
    }
    // halving fold across the 16 node-lanes: lane sl ends with channel sl in a[0]
#pragma unroll
    for (int j = 0; j < 8; ++j) {
        float tt = (sl & 8) ? a[j + 8] : a[j];
        float uu = (sl & 8) ? a[j] : a[j + 8];
        a[j] = tt + __shfl_xor(uu, 8);
    }
#pragma unroll
    for (int j = 0; j < 4; ++j) {
        float tt = (sl & 4) ? a[j + 4] : a[j];
        float uu = (sl & 4) ? a[j] : a[j + 4];
        a[j] = tt + __shfl_xor(uu, 4);
    }
#pragma unroll
    for (int j = 0; j < 2; ++j) {
        float tt = (sl & 2) ? a[j + 2] : a[j];
        float uu = (sl & 2) ? a[j] : a[j + 2];
        a[j] = tt + __shfl_xor(uu, 2);
    }
    {
        float tt = (sl & 1) ? a[1] : a[0];
        float uu = (sl & 1) ? a[0] : a[1];
        a[0] = tt + __shfl_xor(uu, 1);
    }
    a17 += __shfl_xor(a17, 1);
    a17 += __shfl_xor(a17, 2);
    a17 += __shfl_xor(a17, 4);
    a17 += __shfl_xor(a17, 8);
    aggx[ln][sl] = a[0];
    if (sl == 0) aggx[ln][16] = a17;
    __syncthreads();
    // matvec1 + bias + relu: 4 slots per thread, W1 row from regs
    int s0 = tid >> 6;
#pragma unroll
    for (int rep = 0; rep < 4; ++rep) {
        int slot = s0 + rep * 4;
        int nn = blockIdx.x * 16 + slot;
        if (nn < N) {
            const float4* ap = (const float4*)aggx[slot];
            float4 A0 = ap[0], A1 = ap[1], A2 = ap[2], A3 = ap[3];
            float a16 = aggx[slot][16];
            float dot = A0.x * w1r[0]  + A0.y * w1r[1]  + A0.z * w1r[2]  + A0.w * w1r[3]
                      + A1.x * w1r[4]  + A1.y * w1r[5]  + A1.z * w1r[6]  + A1.w * w1r[7]
                      + A2.x * w1r[8]  + A2.y * w1r[9]  + A2.z * w1r[10] + A2.w * w1r[11]
                      + A3.x * w1r[12] + A3.y * w1r[13] + A3.z * w1r[14] + A3.w * w1r[15]
                      + a16  * w1r[16];
            h1sh[slot][ch] = fmaxf(dinv_sh[slot] * dot + b1v, 0.f);
        }
    }
    __syncthreads();
    // matvec2 (h1 @ W2)*dinv -> packed bf16 hs2; all-f32 b128 reads
    int slot = tid >> 4;
    int tc = tid & 15;
    int nn = blockIdx.x * 16 + slot;
    if (nn < N) {
        float a0 = 0.f, a1 = 0.f;
        const float4* hp = (const float4*)h1sh[slot];
        const float4* w0 = (const float4*)w2c0[tc];
        const float4* w1 = (const float4*)w2c1[tc];
#pragma unroll
        for (int kg = 0; kg < 16; ++kg) {
            float4 hv = hp[kg];
            float4 wa = w0[kg];
            float4 wb = w1[kg];
            a0 += hv.x * wa.x + hv.y * wa.y + hv.z * wa.z + hv.w * wa.w;
            a1 += hv.x * wb.x + hv.y * wb.y + hv.z * wb.z + hv.w * wb.w;
        }
        float dv = dinv_sh[slot];
        hs2[(size_t)nn * 16 + tc] = (unsigned)f2bf(a0 * dv) | ((unsigned)f2bf(a1 * dv) << 16);
    }
}

// ---------- layer 2 gather: 1 lane/edge (64B row = 4 uint4) -> fold -> pool ----------
__global__ __launch_bounds__(256) void k_gather2(
        const uint4* __restrict__ hs2v, const int* __restrict__ csr,
        const int2* __restrict__ meta, const float* __restrict__ b2,
        const int* __restrict__ batch, float* pool, float* cntg, int N) {
    __shared__ __align__(16) float cont[16][OUTC];
    __shared__ int bsh[16];
    int ln = threadIdx.x >> 4, sl = threadIdx.x & 15;
    int n = blockIdx.x * 16 + ln;
    float a[32];
#pragma unroll
    for (int j = 0; j < 32; ++j) a[j] = 0.f;
    float dinv = 0.f;
    if (n < N) {
        int2 m = meta[n];
        int start = m.x, cnt = m.y, end = start + cnt;
        dinv = rsqrtf((float)(cnt + 1));
        for (int k = start + sl; k < end; k += 16) {
            int s = __builtin_nontemporal_load(&csr[k]);
            const uint4* rp = hs2v + (size_t)s * 4;
            uint4 v0 = rp[0], v1 = rp[1], v2 = rp[2], v3 = rp[3];
            unp8(v0, a); unp8(v1, a + 8); unp8(v2, a + 16); unp8(v3, a + 24);
        }
        if (sl == 0) {                                   // self loop
            const uint4* rp = hs2v + (size_t)n * 4;
            uint4 v0 = rp[0], v1 = rp[1], v2 = rp[2], v3 = rp[3];
            unp8(v0, a); unp8(v1, a + 8); unp8(v2, a + 16); unp8(v3, a + 24);
        }
    }
    // halving fold: lane sl ends with channels (2sl, 2sl+1) in a[0], a[1]
#pragma unroll
    for (int j = 0; j < 16; ++j) {
        float tt = (sl & 8) ? a[j + 16] : a[j];
        float uu = (sl & 8) ? a[j] : a[j + 16];
        a[j] = tt + __shfl_xor(uu, 8);
    }
#pragma unroll
    for (int j = 0; j < 8; ++j) {
        float tt = (sl & 4) ? a[j + 8] : a[j];
        float uu = (sl & 4) ? a[j] : a[j + 8];
        a[j] = tt + __shfl_xor(uu, 4);
    }
#pragma unroll
    for (int j = 0; j < 4; ++j) {
        float tt = (sl & 2) ? a[j + 4] : a[j];
        float uu = (sl & 2) ? a[j] : a[j + 4];
        a[j] = tt + __shfl_xor(uu, 2);
    }
#pragma unroll
    for (int j = 0; j < 2; ++j) {
        float tt = (sl & 1) ? a[j + 2] : a[j];
        float uu = (sl & 1) ? a[j] : a[j + 2];
        a[j] = tt + __shfl_xor(uu, 1);
    }
    // dinv is per-node uniform; broadcast from lane 0 of the group not needed:
    // every lane computed it from its own meta (same n) — but only if n<N; guard writes.
    if (n < N) {
        float c0 = dinv * a[0] + b2[2 * sl];
        float c1 = dinv * a[1] + b2[2 * sl + 1];
        *(float2*)&cont[ln][2 * sl] = make_float2(c0, c1);
        if (sl == 0) bsh[ln] = batch[n];
    } else {
        *(float2*)&cont[ln][2 * sl] = make_float2(0.f, 0.f);
        if (sl == 0) bsh[ln] = -1;
    }
    __syncthreads();
    if (threadIdx.x < OUTC) {
        int c = threadIdx.x;
        float run = 0.f; int cur = -1;
        for (int j = 0; j < 16; ++j) {
            int bj = bsh[j];
            if (bj < 0) continue;
            if (bj == cur) run += cont[j][c];
            else {
                if (cur >= 0) atomicAdd(&pool[(size_t)cur * OUTC + c], run);
                cur = bj; run = cont[j][c];
            }
        }
        if (cur >= 0) atomicAdd(&pool[(size_t)cur * OUTC + c], run);
        if (c == 0) {
            float crun = 0.f; cur = -1;
            for (int j = 0; j < 16; ++j) {
                int bj = bsh[j];
                if (bj < 0) continue;
                if (bj == cur) crun += 1.f;
                else {
                    if (cur >= 0) atomicAdd(&cntg[cur], crun);
                    cur = bj; crun = 1.f;
                }
            }
            if (cur >= 0) atomicAdd(&cntg[cur], crun);
        }
    }
}

// ---------- final: pooled mean -> fc1(relu) -> fc2 ----------
__global__ void k_final(const float* __restrict__ pool, const float* __restrict__ cntg,
                        const float* __restrict__ Wf1, const float* __restrict__ bf1,
                        const float* __restrict__ Wf2, const float* __restrict__ bf2,
                        float* out, int G) {
    __shared__ float p[OUTC], t[OUTC];
    int g = blockIdx.x;
    int c = threadIdx.x;
    float csafe = fmaxf(cntg[g], 1.0f);
    p[c] = pool[g * OUTC + c] / csafe;
    __syncthreads();
    float acc = bf1[c];
#pragma unroll
    for (int k = 0; k < OUTC; ++k) acc += p[k] * Wf1[k * OUTC + c];
    t[c] = fmaxf(acc, 0.f);
    __syncthreads();
    float acc2 = bf2[c];
#pragma unroll
    for (int k = 0; k < OUTC; ++k) acc2 += t[k] * Wf2[k * OUTC + c];
    out[g * OUTC + c] = acc2;
}

extern "C" void kernel_launch(void* const* d_in, const int* in_sizes, int n_in,
                              void* d_out, int out_size, void* d_ws, size_t ws_size,
                              hipStream_t stream) {
    const float* x    = (const float*)d_in[0];
    const int*   ei   = (const int*)  d_in[1];
    const int*   batch= (const int*)  d_in[2];
    const float* W1   = (const float*)d_in[3];
    const float* b1   = (const float*)d_in[4];
    const float* W2   = (const float*)d_in[5];
    const float* b2   = (const float*)d_in[6];
    const float* Wf1  = (const float*)d_in[7];
    const float* bf1  = (const float*)d_in[8];
    const float* Wf2  = (const float*)d_in[9];
    const float* bf2  = (const float*)d_in[10];

    const int N = in_sizes[0] / IN_C;
    const int E = in_sizes[1] / 2;
    const int G = out_size / OUTC;
    const int* src = ei;
    const int* dst = ei + E;

    const int nblkA = (E + CH - 1) / CH;
    const int NB    = (N + 255) >> 8;

    // ---- workspace layout ----
    char* w = (char*)d_ws;
    int*   csr      = (int*)w;   w += (size_t)E * sizeof(int);
    int2*  meta     = (int2*)w;  w += (size_t)N * sizeof(int2);
    unsigned* xs16h = (unsigned*)w; w += (size_t)N * 8 * sizeof(unsigned);
    unsigned* hs2   = (unsigned*)w; w += (size_t)N * 16 * sizeof(unsigned);
    unsigned short* xs17h = (unsigned short*)w; w += (size_t)N * sizeof(unsigned short);
    w = (char*)(((size_t)w + 15) & ~(size_t)15);
    float* pool     = (float*)w; w += (size_t)G * OUTC * sizeof(float);
    float* cntg     = (float*)w; w += (size_t)G * sizeof(float);
    w = (char*)(((size_t)w + 15) & ~(size_t)15);
    int*   outbuf   = (int*)w;   w += (size_t)E * sizeof(int);
    int*   cntmat   = (int*)w;   w += (size_t)nblkA * NBP * sizeof(int);
    int*   offmat   = (int*)w;   w += (size_t)nblkA * NBP * sizeof(int);
    int*   bbase    = (int*)w;   w += NBP * sizeof(int);

    hipMemsetAsync(pool, 0, (size_t)(G * OUTC + G) * sizeof(float), stream);

    // CSR build (counting sort) + fused x prep
    k_binA<<<nblkA, TA, 0, stream>>>(src, dst, E, outbuf, cntmat, offmat);
    k_bsum<<<1, NBP, 0, stream>>>(cntmat, nblkA, bbase);
    k_binB<<<NB, TA, 0, stream>>>(outbuf, cntmat, offmat, bbase, nblkA, N,
                                  csr, meta, x, xs16h, xs17h);

    // layer 1 fused: aggregate x -> matvec1+relu -> matvec2 -> packed bf16 hs2
    dim3 blk(256);
    k_gather1<<<(N + 15) / 16, blk, 0, stream>>>((const uint4*)xs16h, xs17h, csr, meta,
                                                 W1, b1, W2, hs2, N);

    // layer 2: single full-width gather + pool
    k_gather2<<<(N + 15) / 16, blk, 0, stream>>>((const uint4*)hs2, csr, meta,
                                                 b2, batch, pool, cntg, N);

    // readout
    k_final<<<G, OUTC, 0, stream>>>(pool, cntg, Wf1, bf1, Wf2, bf2, (float*)d_out, G);
}

// Round 11
// 140.382 us; speedup vs baseline: 1.8947x; 1.1594x over previous
//
#include <hip/hip_runtime.h>

#define IN_C 17
#define HID  64
#define OUTC 32

#define CH   8192      // edges per pass-A block
#define TA   512       // pass-A threads
#define NBP  512       // padded bucket count (bucket = dst>>8; N<=131072)
#define BCAP 5632      // pass-B stage capacity
#define SCAP 1024      // per-block CSR stage capacity (gathers)
#define BS_BLKS 8

typedef __attribute__((ext_vector_type(2))) float f2;
__device__ __forceinline__ f2 mkf2(float x, float y) { f2 r; r.x = x; r.y = y; return r; }

__device__ __forceinline__ unsigned short f2bf(float f) {
    unsigned u = __float_as_uint(f);
    u += 0x7fffu + ((u >> 16) & 1u);      // round-nearest-even
    return (unsigned short)(u >> 16);
}
__device__ __forceinline__ float bflo(unsigned u) { return __uint_as_float(u << 16); }
__device__ __forceinline__ float bfhi(unsigned u) { return __uint_as_float(u & 0xffff0000u); }

// ================= pass A: bin edges by dst>>8, coalesced writes =================
__global__ __launch_bounds__(TA) void k_binA(const int* __restrict__ src,
        const int* __restrict__ dst, int E,
        int* __restrict__ outbuf, int* __restrict__ cntmat, int* __restrict__ offmat) {
    __shared__ int cnt[NBP];
    __shared__ int off[NBP];
    __shared__ int stage[CH];
    int t = threadIdx.x;
    long base = (long)blockIdx.x * CH;
    int nE = (int)(E - base); if (nE > CH) nE = CH;
    cnt[t] = 0;
    __syncthreads();
    int bk[16], pk[16], rk[16];
#pragma unroll
    for (int j = 0; j < 16; ++j) {
        int idx = t + j * TA;
        if (idx < nE) {
            long e = base + idx;
            int d = __builtin_nontemporal_load(&dst[e]);
            int s = __builtin_nontemporal_load(&src[e]);
            int b = d >> 8;
            bk[j] = b;
            pk[j] = s | ((d & 255) << 17);
            rk[j] = atomicAdd(&cnt[b], 1);
        } else bk[j] = -1;
    }
    __syncthreads();
    int c = cnt[t];
    off[t] = c;
    __syncthreads();
    int inc = c;
    for (int s = 1; s < NBP; s <<= 1) {
        int add = (t >= s) ? off[t - s] : 0;
        __syncthreads();
        inc += add; off[t] = inc;
        __syncthreads();
    }
    int excl = inc - c;
    __syncthreads();
    off[t] = excl;
    __syncthreads();
#pragma unroll
    for (int j = 0; j < 16; ++j)
        if (bk[j] >= 0) stage[off[bk[j]] + rk[j]] = pk[j];
    __syncthreads();
    for (int i = t; i < nE; i += TA) outbuf[base + i] = stage[i];
    cntmat[blockIdx.x * NBP + t] = c;
    offmat[blockIdx.x * NBP + t] = excl;
}

// ============ bucket totals (parallel partial) + exclusive scan ============
__global__ __launch_bounds__(NBP) void k_bsum1(const int* __restrict__ cntmat,
        int nblkA, int* __restrict__ part) {
    int t = threadIdx.x, b = blockIdx.x;
    int per = (nblkA + BS_BLKS - 1) / BS_BLKS;
    int i0 = b * per, i1 = min(i0 + per, nblkA);
    int s = 0;
    for (int i = i0; i < i1; ++i) s += cntmat[i * NBP + t];
    part[b * NBP + t] = s;
}

__global__ __launch_bounds__(NBP) void k_bsum2(const int* __restrict__ part,
        int* __restrict__ bbase) {
    __shared__ int sh[NBP];
    int t = threadIdx.x;
    int s = 0;
#pragma unroll
    for (int i = 0; i < BS_BLKS; ++i) s += part[i * NBP + t];
    sh[t] = s;
    __syncthreads();
    int inc = s;
    for (int st = 1; st < NBP; st <<= 1) {
        int add = (t >= st) ? sh[t - st] : 0;
        __syncthreads();
        inc += add; sh[t] = inc;
        __syncthreads();
    }
    bbase[t] = inc - s;
}

// === pass B: per bucket, gather runs, emit CSR + meta(start,deg) + bf16 xs (fused prep) ===
__global__ __launch_bounds__(TA) void k_binB(const int* __restrict__ outbuf,
        const int* __restrict__ cntmat, const int* __restrict__ offmat,
        const int* __restrict__ bbase, int nblkA, int N,
        int* __restrict__ csr, int2* __restrict__ meta,
        const float* __restrict__ x, unsigned* __restrict__ xs16h,
        unsigned short* __restrict__ xs17h) {
    __shared__ int segc[256], sego[256], segs[256];
    __shared__ int ndeg[256], noff[256];
    __shared__ int stage[BCAP];
    int t = threadIdx.x, b = blockIdx.x;
    if (t < 256) {
        int cc = 0, ss = 0;
        if (t < nblkA) { cc = cntmat[t * NBP + b]; ss = offmat[t * NBP + b]; }
        segc[t] = cc; segs[t] = ss; sego[t] = cc;
        ndeg[t] = 0;
    }
    __syncthreads();
    {
        int c = (t < 256) ? sego[t] : 0;
        int inc = c;
        for (int s = 1; s < 256; s <<= 1) {
            int add = (t < 256 && t >= s) ? sego[t - s] : 0;
            __syncthreads();
            if (t < 256) { inc += add; sego[t] = inc; }
            __syncthreads();
        }
        if (t < 256) sego[t] = inc - c;
    }
    __syncthreads();
    int wave = t >> 6, lane = t & 63;
    for (int i = wave; i < nblkA; i += TA / 64) {
        int c = segc[i], so = sego[i];
        long gs = (long)i * CH + segs[i];
        for (int l = lane; l < c; l += 64) {
            int p = so + l;
            if (p < BCAP) stage[p] = __builtin_nontemporal_load(&outbuf[gs + l]);
        }
    }
    __syncthreads();
    int T = sego[255] + segc[255];
    if (T > BCAP) T = BCAP;
    int mypk[11], myrk[11], ne = 0;
    for (int k = t; k < T; k += TA) {
        int p = stage[k];
        int l = (p >> 17) & 255;
        myrk[ne] = atomicAdd(&ndeg[l], 1);
        mypk[ne] = p;
        ne++;
    }
    __syncthreads();
    {
        int c = (t < 256) ? ndeg[t] : 0;
        if (t < 256) noff[t] = c;
        __syncthreads();
        int inc = c;
        for (int s = 1; s < 256; s <<= 1) {
            int add = (t < 256 && t >= s) ? noff[t - s] : 0;
            __syncthreads();
            if (t < 256) { inc += add; noff[t] = inc; }
            __syncthreads();
        }
        if (t < 256) noff[t] = inc - c;
    }
    __syncthreads();
    int gb = bbase[b];
    int n0 = b << 8;
    if (t < 256 && n0 + t < N) {
        int n = n0 + t;
        meta[n] = make_int2(gb + noff[t], ndeg[t]);
        float dinv = rsqrtf((float)(ndeg[t] + 1));
        const float* xr = x + (size_t)n * IN_C;
        unsigned* xo = xs16h + (size_t)n * 8;
#pragma unroll
        for (int w2 = 0; w2 < 8; ++w2) {
            unsigned lo = f2bf(xr[2 * w2] * dinv);
            unsigned hi = f2bf(xr[2 * w2 + 1] * dinv);
            xo[w2] = lo | (hi << 16);
        }
        xs17h[n] = f2bf(xr[16] * dinv);
    }
    for (int j = 0; j < ne; ++j) {
        int p = mypk[j];
        int l = (p >> 17) & 255;
        csr[gb + noff[l] + myrk[j]] = p & 0x1FFFF;
    }
}

// ---------- layer 1 (fused): csr LDS-staged, 1 lane/edge, pk accumulate ----------
__global__ __launch_bounds__(256) void k_gather1(
        const uint4* __restrict__ xs16v, const unsigned short* __restrict__ xs17h,
        const int* __restrict__ csr, const int2* __restrict__ meta,
        const float* __restrict__ W1, const float* __restrict__ b1,
        const float* __restrict__ W2, unsigned* __restrict__ hs2, int N) {
    __shared__ __align__(16) float aggx[16][20];
    __shared__ float dinv_sh[16];
    __shared__ __align__(16) float h1sh[16][68];
    __shared__ __align__(16) float w2c0[16][68];
    __shared__ __align__(16) float w2c1[16][68];
    __shared__ int csr_sh[SCAP];

    int tid = threadIdx.x;
    int n0 = blockIdx.x * 16;
    int nlast = min(n0 + 15, N - 1);
    int2 m0 = meta[n0];
    int2 mlv = meta[nlast];
    int s_lo = m0.x;
    int seglen = mlv.x + mlv.y - s_lo;
    int sg = min(seglen, SCAP);
    for (int i = tid; i < sg; i += 256)
        csr_sh[i] = __builtin_nontemporal_load(&csr[s_lo + i]);
    for (int i = tid; i < 16 * 64; i += 256) {
        int tc = i >> 6, k = i & 63;
        w2c0[tc][k] = W2[k * OUTC + 2 * tc];
        w2c1[tc][k] = W2[k * OUTC + 2 * tc + 1];
    }
    int ch = tid & 63;
    float w1r[IN_C];
#pragma unroll
    for (int k = 0; k < IN_C; ++k) w1r[k] = W1[k * HID + ch];
    float b1v = b1[ch];
    __syncthreads();

    int ln = tid >> 4, sl = tid & 15;
    int n = n0 + ln;
    f2 acc[8];
#pragma unroll
    for (int j = 0; j < 8; ++j) acc[j] = mkf2(0.f, 0.f);
    float a17 = 0.f;
    if (n < N) {
        int2 m = meta[n];
        int start = m.x, cnt = m.y, end = start + cnt;
        auto body = [&](int s) {
            uint4 v0 = xs16v[(size_t)s * 2];
            uint4 v1 = xs16v[(size_t)s * 2 + 1];
            acc[0] += mkf2(bflo(v0.x), bfhi(v0.x));
            acc[1] += mkf2(bflo(v0.y), bfhi(v0.y));
            acc[2] += mkf2(bflo(v0.z), bfhi(v0.z));
            acc[3] += mkf2(bflo(v0.w), bfhi(v0.w));
            acc[4] += mkf2(bflo(v1.x), bfhi(v1.x));
            acc[5] += mkf2(bflo(v1.y), bfhi(v1.y));
            acc[6] += mkf2(bflo(v1.z), bfhi(v1.z));
            acc[7] += mkf2(bflo(v1.w), bfhi(v1.w));
            a17 += bflo((unsigned)xs17h[s]);
        };
        if (seglen <= SCAP) {
            for (int k = start + sl; k < end; k += 16) body(csr_sh[k - s_lo]);
        } else {
            for (int k = start + sl; k < end; k += 16)
                body(__builtin_nontemporal_load(&csr[k]));
        }
        if (sl == 0) {                                   // self loop
            body(n);
            dinv_sh[ln] = rsqrtf((float)(cnt + 1));
        }
    }
    float a[16];
#pragma unroll
    for (int j = 0; j < 8; ++j) { a[2 * j] = acc[j].x; a[2 * j + 1] = acc[j].y; }
    // halving fold across the 16 node-lanes: lane sl ends with channel sl in a[0]
#pragma unroll
    for (int j = 0; j < 8; ++j) {
        float tt = (sl & 8) ? a[j + 8] : a[j];
        float uu = (sl & 8) ? a[j] : a[j + 8];
        a[j] = tt + __shfl_xor(uu, 8);
    }
#pragma unroll
    for (int j = 0; j < 4; ++j) {
        float tt = (sl & 4) ? a[j + 4] : a[j];
        float uu = (sl & 4) ? a[j] : a[j + 4];
        a[j] = tt + __shfl_xor(uu, 4);
    }
#pragma unroll
    for (int j = 0; j < 2; ++j) {
        float tt = (sl & 2) ? a[j + 2] : a[j];
        float uu = (sl & 2) ? a[j] : a[j + 2];
        a[j] = tt + __shfl_xor(uu, 2);
    }
    {
        float tt = (sl & 1) ? a[1] : a[0];
        float uu = (sl & 1) ? a[0] : a[1];
        a[0] = tt + __shfl_xor(uu, 1);
    }
    a17 += __shfl_xor(a17, 1);
    a17 += __shfl_xor(a17, 2);
    a17 += __shfl_xor(a17, 4);
    a17 += __shfl_xor(a17, 8);
    aggx[ln][sl] = a[0];
    if (sl == 0) aggx[ln][16] = a17;
    __syncthreads();
    // matvec1 + bias + relu
    int s0 = tid >> 6;
#pragma unroll
    for (int rep = 0; rep < 4; ++rep) {
        int slot = s0 + rep * 4;
        int nn = n0 + slot;
        if (nn < N) {
            const float4* ap = (const float4*)aggx[slot];
            float4 A0 = ap[0], A1 = ap[1], A2 = ap[2], A3 = ap[3];
            float a16 = aggx[slot][16];
            float dot = A0.x * w1r[0]  + A0.y * w1r[1]  + A0.z * w1r[2]  + A0.w * w1r[3]
                      + A1.x * w1r[4]  + A1.y * w1r[5]  + A1.z * w1r[6]  + A1.w * w1r[7]
                      + A2.x * w1r[8]  + A2.y * w1r[9]  + A2.z * w1r[10] + A2.w * w1r[11]
                      + A3.x * w1r[12] + A3.y * w1r[13] + A3.z * w1r[14] + A3.w * w1r[15]
                      + a16  * w1r[16];
            h1sh[slot][ch] = fmaxf(dinv_sh[slot] * dot + b1v, 0.f);
        }
    }
    __syncthreads();
    // matvec2 (h1 @ W2)*dinv -> packed bf16 hs2
    int slot = tid >> 4;
    int tc = tid & 15;
    int nn = n0 + slot;
    if (nn < N) {
        float a0 = 0.f, a1 = 0.f;
        const float4* hp = (const float4*)h1sh[slot];
        const float4* w0 = (const float4*)w2c0[tc];
        const float4* w1 = (const float4*)w2c1[tc];
#pragma unroll
        for (int kg = 0; kg < 16; ++kg) {
            float4 hv = hp[kg];
            float4 wa = w0[kg];
            float4 wb = w1[kg];
            a0 += hv.x * wa.x + hv.y * wa.y + hv.z * wa.z + hv.w * wa.w;
            a1 += hv.x * wb.x + hv.y * wb.y + hv.z * wb.z + hv.w * wb.w;
        }
        float dv = dinv_sh[slot];
        hs2[(size_t)nn * 16 + tc] = (unsigned)f2bf(a0 * dv) | ((unsigned)f2bf(a1 * dv) << 16);
    }
}

// ---------- layer 2 gather: csr LDS-staged, 1 lane/edge, pk accumulate + pool ----------
__global__ __launch_bounds__(256) void k_gather2(
        const uint4* __restrict__ hs2v, const int* __restrict__ csr,
        const int2* __restrict__ meta, const float* __restrict__ b2,
        const int* __restrict__ batch, float* pool, float* cntg, int N) {
    __shared__ __align__(16) float cont[16][OUTC];
    __shared__ int bsh[16];
    __shared__ int csr_sh[SCAP];
    int tid = threadIdx.x;
    int n0 = blockIdx.x * 16;
    int nlast = min(n0 + 15, N - 1);
    int2 m0 = meta[n0];
    int2 mlv = meta[nlast];
    int s_lo = m0.x;
    int seglen = mlv.x + mlv.y - s_lo;
    int sg = min(seglen, SCAP);
    for (int i = tid; i < sg; i += 256)
        csr_sh[i] = __builtin_nontemporal_load(&csr[s_lo + i]);
    __syncthreads();

    int ln = tid >> 4, sl = tid & 15;
    int n = n0 + ln;
    f2 acc[16];
#pragma unroll
    for (int j = 0; j < 16; ++j) acc[j] = mkf2(0.f, 0.f);
    float dinv = 0.f;
    if (n < N) {
        int2 m = meta[n];
        int start = m.x, cnt = m.y, end = start + cnt;
        dinv = rsqrtf((float)(cnt + 1));
        auto body = [&](int s) {
            const uint4* rp = hs2v + (size_t)s * 4;
            uint4 v0 = rp[0], v1 = rp[1], v2 = rp[2], v3 = rp[3];
            acc[0]  += mkf2(bflo(v0.x), bfhi(v0.x));
            acc[1]  += mkf2(bflo(v0.y), bfhi(v0.y));
            acc[2]  += mkf2(bflo(v0.z), bfhi(v0.z));
            acc[3]  += mkf2(bflo(v0.w), bfhi(v0.w));
            acc[4]  += mkf2(bflo(v1.x), bfhi(v1.x));
            acc[5]  += mkf2(bflo(v1.y), bfhi(v1.y));
            acc[6]  += mkf2(bflo(v1.z), bfhi(v1.z));
            acc[7]  += mkf2(bflo(v1.w), bfhi(v1.w));
            acc[8]  += mkf2(bflo(v2.x), bfhi(v2.x));
            acc[9]  += mkf2(bflo(v2.y), bfhi(v2.y));
            acc[10] += mkf2(bflo(v2.z), bfhi(v2.z));
            acc[11] += mkf2(bflo(v2.w), bfhi(v2.w));
            acc[12] += mkf2(bflo(v3.x), bfhi(v3.x));
            acc[13] += mkf2(bflo(v3.y), bfhi(v3.y));
            acc[14] += mkf2(bflo(v3.z), bfhi(v3.z));
            acc[15] += mkf2(bflo(v3.w), bfhi(v3.w));
        };
        if (seglen <= SCAP) {
            for (int k = start + sl; k < end; k += 16) body(csr_sh[k - s_lo]);
        } else {
            for (int k = start + sl; k < end; k += 16)
                body(__builtin_nontemporal_load(&csr[k]));
        }
        if (sl == 0) body(n);                            // self loop
    }
    float a[32];
#pragma unroll
    for (int j = 0; j < 16; ++j) { a[2 * j] = acc[j].x; a[2 * j + 1] = acc[j].y; }
    // halving fold: lane sl ends with channels (2sl, 2sl+1) in a[0], a[1]
#pragma unroll
    for (int j = 0; j < 16; ++j) {
        float tt = (sl & 8) ? a[j + 16] : a[j];
        float uu = (sl & 8) ? a[j] : a[j + 16];
        a[j] = tt + __shfl_xor(uu, 8);
    }
#pragma unroll
    for (int j = 0; j < 8; ++j) {
        float tt = (sl & 4) ? a[j + 8] : a[j];
        float uu = (sl & 4) ? a[j] : a[j + 8];
        a[j] = tt + __shfl_xor(uu, 4);
    }
#pragma unroll
    for (int j = 0; j < 4; ++j) {
        float tt = (sl & 2) ? a[j + 4] : a[j];
        float uu = (sl & 2) ? a[j] : a[j + 4];
        a[j] = tt + __shfl_xor(uu, 2);
    }
#pragma unroll
    for (int j = 0; j < 2; ++j) {
        float tt = (sl & 1) ? a[j + 2] : a[j];
        float uu = (sl & 1) ? a[j] : a[j + 2];
        a[j] = tt + __shfl_xor(uu, 1);
    }
    if (n < N) {
        float c0 = dinv * a[0] + b2[2 * sl];
        float c1 = dinv * a[1] + b2[2 * sl + 1];
        *(float2*)&cont[ln][2 * sl] = make_float2(c0, c1);
        if (sl == 0) bsh[ln] = batch[n];
    } else {
        *(float2*)&cont[ln][2 * sl] = make_float2(0.f, 0.f);
        if (sl == 0) bsh[ln] = -1;
    }
    __syncthreads();
    if (tid < OUTC) {
        int c = tid;
        float run = 0.f; int cur = -1;
        for (int j = 0; j < 16; ++j) {
            int bj = bsh[j];
            if (bj < 0) continue;
            if (bj == cur) run += cont[j][c];
            else {
                if (cur >= 0) atomicAdd(&pool[(size_t)cur * OUTC + c], run);
                cur = bj; run = cont[j][c];
            }
        }
        if (cur >= 0) atomicAdd(&pool[(size_t)cur * OUTC + c], run);
        if (c == 0) {
            float crun = 0.f; cur = -1;
            for (int j = 0; j < 16; ++j) {
                int bj = bsh[j];
                if (bj < 0) continue;
                if (bj == cur) crun += 1.f;
                else {
                    if (cur >= 0) atomicAdd(&cntg[cur], crun);
                    cur = bj; crun = 1.f;
                }
            }
            if (cur >= 0) atomicAdd(&cntg[cur], crun);
        }
    }
}

// ---------- final: pooled mean -> fc1(relu) -> fc2 ----------
__global__ void k_final(const float* __restrict__ pool, const float* __restrict__ cntg,
                        const float* __restrict__ Wf1, const float* __restrict__ bf1,
                        const float* __restrict__ Wf2, const float* __restrict__ bf2,
                        float* out, int G) {
    __shared__ float p[OUTC], t[OUTC];
    int g = blockIdx.x;
    int c = threadIdx.x;
    float csafe = fmaxf(cntg[g], 1.0f);
    p[c] = pool[g * OUTC + c] / csafe;
    __syncthreads();
    float acc = bf1[c];
#pragma unroll
    for (int k = 0; k < OUTC; ++k) acc += p[k] * Wf1[k * OUTC + c];
    t[c] = fmaxf(acc, 0.f);
    __syncthreads();
    float acc2 = bf2[c];
#pragma unroll
    for (int k = 0; k < OUTC; ++k) acc2 += t[k] * Wf2[k * OUTC + c];
    out[g * OUTC + c] = acc2;
}

extern "C" void kernel_launch(void* const* d_in, const int* in_sizes, int n_in,
                              void* d_out, int out_size, void* d_ws, size_t ws_size,
                              hipStream_t stream) {
    const float* x    = (const float*)d_in[0];
    const int*   ei   = (const int*)  d_in[1];
    const int*   batch= (const int*)  d_in[2];
    const float* W1   = (const float*)d_in[3];
    const float* b1   = (const float*)d_in[4];
    const float* W2   = (const float*)d_in[5];
    const float* b2   = (const float*)d_in[6];
    const float* Wf1  = (const float*)d_in[7];
    const float* bf1  = (const float*)d_in[8];
    const float* Wf2  = (const float*)d_in[9];
    const float* bf2  = (const float*)d_in[10];

    const int N = in_sizes[0] / IN_C;
    const int E = in_sizes[1] / 2;
    const int G = out_size / OUTC;
    const int* src = ei;
    const int* dst = ei + E;

    const int nblkA = (E + CH - 1) / CH;
    const int NB    = (N + 255) >> 8;

    // ---- workspace layout ----
    char* w = (char*)d_ws;
    int*   csr      = (int*)w;   w += (size_t)E * sizeof(int);
    int2*  meta     = (int2*)w;  w += (size_t)N * sizeof(int2);
    unsigned* xs16h = (unsigned*)w; w += (size_t)N * 8 * sizeof(unsigned);
    unsigned* hs2   = (unsigned*)w; w += (size_t)N * 16 * sizeof(unsigned);
    unsigned short* xs17h = (unsigned short*)w; w += (size_t)N * sizeof(unsigned short);
    w = (char*)(((size_t)w + 15) & ~(size_t)15);
    float* pool     = (float*)w; w += (size_t)G * OUTC * sizeof(float);
    float* cntg     = (float*)w; w += (size_t)G * sizeof(float);
    w = (char*)(((size_t)w + 15) & ~(size_t)15);
    int*   outbuf   = (int*)w;   w += (size_t)E * sizeof(int);
    int*   cntmat   = (int*)w;   w += (size_t)nblkA * NBP * sizeof(int);
    int*   offmat   = (int*)w;   w += (size_t)nblkA * NBP * sizeof(int);
    int*   bbase    = (int*)w;   w += NBP * sizeof(int);
    int*   part     = (int*)w;   w += BS_BLKS * NBP * sizeof(int);

    hipMemsetAsync(pool, 0, (size_t)(G * OUTC + G) * sizeof(float), stream);

    // CSR build (counting sort) + fused x prep
    k_binA<<<nblkA, TA, 0, stream>>>(src, dst, E, outbuf, cntmat, offmat);
    k_bsum1<<<BS_BLKS, NBP, 0, stream>>>(cntmat, nblkA, part);
    k_bsum2<<<1, NBP, 0, stream>>>(part, bbase);
    k_binB<<<NB, TA, 0, stream>>>(outbuf, cntmat, offmat, bbase, nblkA, N,
                                  csr, meta, x, xs16h, xs17h);

    // layer 1 fused: aggregate x -> matvec1+relu -> matvec2 -> packed bf16 hs2
    dim3 blk(256);
    k_gather1<<<(N + 15) / 16, blk, 0, stream>>>((const uint4*)xs16h, xs17h, csr, meta,
                                                 W1, b1, W2, hs2, N);

    // layer 2: single full-width gather + pool
    k_gather2<<<(N + 15) / 16, blk, 0, stream>>>((const uint4*)hs2, csr, meta,
                                                 b2, batch, pool, cntg, N);

    // readout
    k_final<<<G, OUTC, 0, stream>>>(pool, cntg, Wf1, bf1, Wf2, bf2, (float*)d_out, G);
}

// Round 12
// 135.241 us; speedup vs baseline: 1.9667x; 1.0380x over previous
//
#include <hip/hip_runtime.h>

#define IN_C 17
#define HID  64
#define OUTC 32

#define CH   8192      // edges per pass-A block
#define TA   512       // pass-A threads
#define NBP  512       // padded bucket count (bucket = dst>>8; N<=131072)
#define BCAP 5632      // pass-B stage capacity
#define SCAP 1024      // per-block CSR stage capacity (gathers)
#define BS_BLKS 8

typedef __attribute__((ext_vector_type(2))) float f2;
typedef __attribute__((ext_vector_type(8))) short bf16x8;
typedef __attribute__((ext_vector_type(4))) float f32x4;
__device__ __forceinline__ f2 mkf2(float x, float y) { f2 r; r.x = x; r.y = y; return r; }

__device__ __forceinline__ unsigned short f2bf(float f) {
    unsigned u = __float_as_uint(f);
    u += 0x7fffu + ((u >> 16) & 1u);      // round-nearest-even
    return (unsigned short)(u >> 16);
}
__device__ __forceinline__ float bflo(unsigned u) { return __uint_as_float(u << 16); }
__device__ __forceinline__ float bfhi(unsigned u) { return __uint_as_float(u & 0xffff0000u); }

// ================= pass A: bin edges by dst>>8, coalesced writes =================
__global__ __launch_bounds__(TA) void k_binA(const int* __restrict__ src,
        const int* __restrict__ dst, int E,
        int* __restrict__ outbuf, int* __restrict__ cntmat, int* __restrict__ offmat) {
    __shared__ int cnt[NBP];
    __shared__ int off[NBP];
    __shared__ int stage[CH];
    int t = threadIdx.x;
    long base = (long)blockIdx.x * CH;
    int nE = (int)(E - base); if (nE > CH) nE = CH;
    cnt[t] = 0;
    __syncthreads();
    int bk[16], pk[16], rk[16];
#pragma unroll
    for (int j = 0; j < 16; ++j) {
        int idx = t + j * TA;
        if (idx < nE) {
            long e = base + idx;
            int d = __builtin_nontemporal_load(&dst[e]);
            int s = __builtin_nontemporal_load(&src[e]);
            int b = d >> 8;
            bk[j] = b;
            pk[j] = s | ((d & 255) << 17);
            rk[j] = atomicAdd(&cnt[b], 1);
        } else bk[j] = -1;
    }
    __syncthreads();
    int c = cnt[t];
    off[t] = c;
    __syncthreads();
    int inc = c;
    for (int s = 1; s < NBP; s <<= 1) {
        int add = (t >= s) ? off[t - s] : 0;
        __syncthreads();
        inc += add; off[t] = inc;
        __syncthreads();
    }
    int excl = inc - c;
    __syncthreads();
    off[t] = excl;
    __syncthreads();
#pragma unroll
    for (int j = 0; j < 16; ++j)
        if (bk[j] >= 0) stage[off[bk[j]] + rk[j]] = pk[j];
    __syncthreads();
    for (int i = t; i < nE; i += TA) outbuf[base + i] = stage[i];
    cntmat[blockIdx.x * NBP + t] = c;
    offmat[blockIdx.x * NBP + t] = excl;
}

// ============ bucket totals (parallel partial) + exclusive scan + W2 frag pack ============
__global__ __launch_bounds__(NBP) void k_bsum1(const int* __restrict__ cntmat,
        int nblkA, int* __restrict__ part) {
    int t = threadIdx.x, b = blockIdx.x;
    int per = (nblkA + BS_BLKS - 1) / BS_BLKS;
    int i0 = b * per, i1 = min(i0 + per, nblkA);
    int s = 0;
    for (int i = i0; i < i1; ++i) s += cntmat[i * NBP + t];
    part[b * NBP + t] = s;
}

__global__ __launch_bounds__(NBP) void k_bsum2(const int* __restrict__ part,
        int* __restrict__ bbase, const float* __restrict__ W2,
        uint4* __restrict__ w2frag) {
    __shared__ int sh[NBP];
    int t = threadIdx.x;
    int s = 0;
#pragma unroll
    for (int i = 0; i < BS_BLKS; ++i) s += part[i * NBP + t];
    sh[t] = s;
    __syncthreads();
    int inc = s;
    for (int st = 1; st < NBP; st <<= 1) {
        int add = (t >= st) ? sh[t - st] : 0;
        __syncthreads();
        inc += add; sh[t] = inc;
        __syncthreads();
    }
    bbase[t] = inc - s;
    // pack W2 into MFMA B-fragment layout: frag f = kt*2+nt; lane l holds
    // B[k = kt*32 + (l>>4)*8 + j][c = nt*16 + (l&15)], j=0..7
    if (t < 256) {
        int f = t >> 6, l = t & 63;
        int kt = f >> 1, nt = f & 1;
        int kbase = kt * 32 + (l >> 4) * 8;
        int c = nt * 16 + (l & 15);
        unsigned short v[8];
#pragma unroll
        for (int j = 0; j < 8; ++j) v[j] = f2bf(W2[(kbase + j) * OUTC + c]);
        uint4 o;
        o.x = (unsigned)v[0] | ((unsigned)v[1] << 16);
        o.y = (unsigned)v[2] | ((unsigned)v[3] << 16);
        o.z = (unsigned)v[4] | ((unsigned)v[5] << 16);
        o.w = (unsigned)v[6] | ((unsigned)v[7] << 16);
        w2frag[f * 64 + l] = o;
    }
}

// === pass B: per bucket, gather runs, emit CSR + meta(start,deg) + bf16 xs (fused prep) ===
__global__ __launch_bounds__(TA) void k_binB(const int* __restrict__ outbuf,
        const int* __restrict__ cntmat, const int* __restrict__ offmat,
        const int* __restrict__ bbase, int nblkA, int N,
        int* __restrict__ csr, int2* __restrict__ meta,
        const float* __restrict__ x, unsigned* __restrict__ xs16h,
        unsigned short* __restrict__ xs17h) {
    __shared__ int segc[256], sego[256], segs[256];
    __shared__ int ndeg[256], noff[256];
    __shared__ int stage[BCAP];
    int t = threadIdx.x, b = blockIdx.x;
    if (t < 256) {
        int cc = 0, ss = 0;
        if (t < nblkA) { cc = cntmat[t * NBP + b]; ss = offmat[t * NBP + b]; }
        segc[t] = cc; segs[t] = ss; sego[t] = cc;
        ndeg[t] = 0;
    }
    __syncthreads();
    {
        int c = (t < 256) ? sego[t] : 0;
        int inc = c;
        for (int s = 1; s < 256; s <<= 1) {
            int add = (t < 256 && t >= s) ? sego[t - s] : 0;
            __syncthreads();
            if (t < 256) { inc += add; sego[t] = inc; }
            __syncthreads();
        }
        if (t < 256) sego[t] = inc - c;
    }
    __syncthreads();
    int wave = t >> 6, lane = t & 63;
    for (int i = wave; i < nblkA; i += TA / 64) {
        int c = segc[i], so = sego[i];
        long gs = (long)i * CH + segs[i];
        for (int l = lane; l < c; l += 64) {
            int p = so + l;
            if (p < BCAP) stage[p] = __builtin_nontemporal_load(&outbuf[gs + l]);
        }
    }
    __syncthreads();
    int T = sego[255] + segc[255];
    if (T > BCAP) T = BCAP;
    int mypk[11], myrk[11], ne = 0;
    for (int k = t; k < T; k += TA) {
        int p = stage[k];
        int l = (p >> 17) & 255;
        myrk[ne] = atomicAdd(&ndeg[l], 1);
        mypk[ne] = p;
        ne++;
    }
    __syncthreads();
    {
        int c = (t < 256) ? ndeg[t] : 0;
        if (t < 256) noff[t] = c;
        __syncthreads();
        int inc = c;
        for (int s = 1; s < 256; s <<= 1) {
            int add = (t < 256 && t >= s) ? noff[t - s] : 0;
            __syncthreads();
            if (t < 256) { inc += add; noff[t] = inc; }
            __syncthreads();
        }
        if (t < 256) noff[t] = inc - c;
    }
    __syncthreads();
    int gb = bbase[b];
    int n0 = b << 8;
    if (t < 256 && n0 + t < N) {
        int n = n0 + t;
        meta[n] = make_int2(gb + noff[t], ndeg[t]);
        float dinv = rsqrtf((float)(ndeg[t] + 1));
        const float* xr = x + (size_t)n * IN_C;
        unsigned* xo = xs16h + (size_t)n * 8;
#pragma unroll
        for (int w2 = 0; w2 < 8; ++w2) {
            unsigned lo = f2bf(xr[2 * w2] * dinv);
            unsigned hi = f2bf(xr[2 * w2 + 1] * dinv);
            xo[w2] = lo | (hi << 16);
        }
        xs17h[n] = f2bf(xr[16] * dinv);
    }
    for (int j = 0; j < ne; ++j) {
        int p = mypk[j];
        int l = (p >> 17) & 255;
        csr[gb + noff[l] + myrk[j]] = p & 0x1FFFF;
    }
}

// ---------- layer 1: csr LDS-staged gather -> fold -> matvec1 -> bf16 h1b (dinv folded) ----------
__global__ __launch_bounds__(256) void k_gather1(
        const uint4* __restrict__ xs16v, const unsigned short* __restrict__ xs17h,
        const int* __restrict__ csr, const int2* __restrict__ meta,
        const float* __restrict__ W1, const float* __restrict__ b1,
        unsigned short* __restrict__ h1b, int N) {
    __shared__ __align__(16) float aggx[16][20];
    __shared__ float dinv_sh[16];
    __shared__ int csr_sh[SCAP];

    int tid = threadIdx.x;
    int n0 = blockIdx.x * 16;
    int nlast = min(n0 + 15, N - 1);
    int2 m0 = meta[n0];
    int2 mlv = meta[nlast];
    int s_lo = m0.x;
    int seglen = mlv.x + mlv.y - s_lo;
    int sg = min(seglen, SCAP);
    for (int i = tid; i < sg; i += 256)
        csr_sh[i] = __builtin_nontemporal_load(&csr[s_lo + i]);
    int ch = tid & 63;
    float w1r[IN_C];
#pragma unroll
    for (int k = 0; k < IN_C; ++k) w1r[k] = W1[k * HID + ch];
    float b1v = b1[ch];
    __syncthreads();

    int ln = tid >> 4, sl = tid & 15;
    int n = n0 + ln;
    f2 acc[8];
#pragma unroll
    for (int j = 0; j < 8; ++j) acc[j] = mkf2(0.f, 0.f);
    float a17 = 0.f;
    if (n < N) {
        int2 m = meta[n];
        int start = m.x, cnt = m.y, end = start + cnt;
        auto body = [&](int s) {
            uint4 v0 = xs16v[(size_t)s * 2];
            uint4 v1 = xs16v[(size_t)s * 2 + 1];
            acc[0] += mkf2(bflo(v0.x), bfhi(v0.x));
            acc[1] += mkf2(bflo(v0.y), bfhi(v0.y));
            acc[2] += mkf2(bflo(v0.z), bfhi(v0.z));
            acc[3] += mkf2(bflo(v0.w), bfhi(v0.w));
            acc[4] += mkf2(bflo(v1.x), bfhi(v1.x));
            acc[5] += mkf2(bflo(v1.y), bfhi(v1.y));
            acc[6] += mkf2(bflo(v1.z), bfhi(v1.z));
            acc[7] += mkf2(bflo(v1.w), bfhi(v1.w));
            a17 += bflo((unsigned)xs17h[s]);
        };
        if (seglen <= SCAP) {
            for (int k = start + sl; k < end; k += 16) body(csr_sh[k - s_lo]);
        } else {
            for (int k = start + sl; k < end; k += 16)
                body(__builtin_nontemporal_load(&csr[k]));
        }
        if (sl == 0) {                                   // self loop
            body(n);
            dinv_sh[ln] = rsqrtf((float)(cnt + 1));
        }
    }
    float a[16];
#pragma unroll
    for (int j = 0; j < 8; ++j) { a[2 * j] = acc[j].x; a[2 * j + 1] = acc[j].y; }
#pragma unroll
    for (int j = 0; j < 8; ++j) {
        float tt = (sl & 8) ? a[j + 8] : a[j];
        float uu = (sl & 8) ? a[j] : a[j + 8];
        a[j] = tt + __shfl_xor(uu, 8);
    }
#pragma unroll
    for (int j = 0; j < 4; ++j) {
        float tt = (sl & 4) ? a[j + 4] : a[j];
        float uu = (sl & 4) ? a[j] : a[j + 4];
        a[j] = tt + __shfl_xor(uu, 4);
    }
#pragma unroll
    for (int j = 0; j < 2; ++j) {
        float tt = (sl & 2) ? a[j + 2] : a[j];
        float uu = (sl & 2) ? a[j] : a[j + 2];
        a[j] = tt + __shfl_xor(uu, 2);
    }
    {
        float tt = (sl & 1) ? a[1] : a[0];
        float uu = (sl & 1) ? a[0] : a[1];
        a[0] = tt + __shfl_xor(uu, 1);
    }
    a17 += __shfl_xor(a17, 1);
    a17 += __shfl_xor(a17, 2);
    a17 += __shfl_xor(a17, 4);
    a17 += __shfl_xor(a17, 8);
    aggx[ln][sl] = a[0];
    if (sl == 0) aggx[ln][16] = a17;
    __syncthreads();
    // matvec1 + bias + relu, dinv folded into stored h1b (bf16)
    int s0 = tid >> 6;
#pragma unroll
    for (int rep = 0; rep < 4; ++rep) {
        int slot = s0 + rep * 4;
        int nn = n0 + slot;
        if (nn < N) {
            const float4* ap = (const float4*)aggx[slot];
            float4 A0 = ap[0], A1 = ap[1], A2 = ap[2], A3 = ap[3];
            float a16 = aggx[slot][16];
            float dot = A0.x * w1r[0]  + A0.y * w1r[1]  + A0.z * w1r[2]  + A0.w * w1r[3]
                      + A1.x * w1r[4]  + A1.y * w1r[5]  + A1.z * w1r[6]  + A1.w * w1r[7]
                      + A2.x * w1r[8]  + A2.y * w1r[9]  + A2.z * w1r[10] + A2.w * w1r[11]
                      + A3.x * w1r[12] + A3.y * w1r[13] + A3.z * w1r[14] + A3.w * w1r[15]
                      + a16  * w1r[16];
            float dv = dinv_sh[slot];
            float r = fmaxf(dv * dot + b1v, 0.f);
            h1b[(size_t)nn * HID + ch] = f2bf(dv * r);
        }
    }
}

// ---------- mm2 via MFMA: hs2 = h1b @ W2, word w = (ch w, ch w+16) ----------
__global__ __launch_bounds__(256) void k_mm2f(
        const unsigned short* __restrict__ h1b, const uint4* __restrict__ w2frag,
        unsigned* __restrict__ hs2, int N) {
    int tid = threadIdx.x;
    int wv = tid >> 6, l = tid & 63;
    int n0w = blockIdx.x * 64 + wv * 16;
    int row = l & 15, kq = l >> 4;
    const bf16x8* a0p = (const bf16x8*)(h1b + (size_t)(n0w + row) * HID + kq * 8);
    const bf16x8* a1p = (const bf16x8*)(h1b + (size_t)(n0w + row) * HID + 32 + kq * 8);
    bf16x8 a0 = *a0p;
    bf16x8 a1 = *a1p;
    bf16x8 b00 = *(const bf16x8*)&w2frag[0 * 64 + l];   // kt0, nt0
    bf16x8 b01 = *(const bf16x8*)&w2frag[1 * 64 + l];   // kt0, nt1
    bf16x8 b10 = *(const bf16x8*)&w2frag[2 * 64 + l];   // kt1, nt0
    bf16x8 b11 = *(const bf16x8*)&w2frag[3 * 64 + l];   // kt1, nt1
    f32x4 d0 = {0.f, 0.f, 0.f, 0.f}, d1 = {0.f, 0.f, 0.f, 0.f};
    d0 = __builtin_amdgcn_mfma_f32_16x16x32_bf16(a0, b00, d0, 0, 0, 0);
    d0 = __builtin_amdgcn_mfma_f32_16x16x32_bf16(a1, b10, d0, 0, 0, 0);
    d1 = __builtin_amdgcn_mfma_f32_16x16x32_bf16(a0, b01, d1, 0, 0, 0);
    d1 = __builtin_amdgcn_mfma_f32_16x16x32_bf16(a1, b11, d1, 0, 0, 0);
    int wcol = l & 15;
    int rbase = (l >> 4) * 4;
#pragma unroll
    for (int r = 0; r < 4; ++r) {
        int node = n0w + rbase + r;
        if (node < N)
            hs2[(size_t)node * 16 + wcol] =
                (unsigned)f2bf(d0[r]) | ((unsigned)f2bf(d1[r]) << 16);
    }
}

// ---------- layer 2 gather: csr LDS-staged, 1 lane/edge + pool ----------
__global__ __launch_bounds__(256) void k_gather2(
        const uint4* __restrict__ hs2v, const int* __restrict__ csr,
        const int2* __restrict__ meta, const float* __restrict__ b2,
        const int* __restrict__ batch, float* pool, float* cntg, int N) {
    __shared__ __align__(16) float cont[16][OUTC];
    __shared__ int bsh[16];
    __shared__ int csr_sh[SCAP];
    int tid = threadIdx.x;
    int n0 = blockIdx.x * 16;
    int nlast = min(n0 + 15, N - 1);
    int2 m0 = meta[n0];
    int2 mlv = meta[nlast];
    int s_lo = m0.x;
    int seglen = mlv.x + mlv.y - s_lo;
    int sg = min(seglen, SCAP);
    for (int i = tid; i < sg; i += 256)
        csr_sh[i] = __builtin_nontemporal_load(&csr[s_lo + i]);
    __syncthreads();

    int ln = tid >> 4, sl = tid & 15;
    int n = n0 + ln;
    f2 acc[16];
#pragma unroll
    for (int j = 0; j < 16; ++j) acc[j] = mkf2(0.f, 0.f);
    float dinv = 0.f;
    if (n < N) {
        int2 m = meta[n];
        int start = m.x, cnt = m.y, end = start + cnt;
        dinv = rsqrtf((float)(cnt + 1));
        auto body = [&](int s) {
            const uint4* rp = hs2v + (size_t)s * 4;
            uint4 v0 = rp[0], v1 = rp[1], v2 = rp[2], v3 = rp[3];
            acc[0]  += mkf2(bflo(v0.x), bfhi(v0.x));
            acc[1]  += mkf2(bflo(v0.y), bfhi(v0.y));
            acc[2]  += mkf2(bflo(v0.z), bfhi(v0.z));
            acc[3]  += mkf2(bflo(v0.w), bfhi(v0.w));
            acc[4]  += mkf2(bflo(v1.x), bfhi(v1.x));
            acc[5]  += mkf2(bflo(v1.y), bfhi(v1.y));
            acc[6]  += mkf2(bflo(v1.z), bfhi(v1.z));
            acc[7]  += mkf2(bflo(v1.w), bfhi(v1.w));
            acc[8]  += mkf2(bflo(v2.x), bfhi(v2.x));
            acc[9]  += mkf2(bflo(v2.y), bfhi(v2.y));
            acc[10] += mkf2(bflo(v2.z), bfhi(v2.z));
            acc[11] += mkf2(bflo(v2.w), bfhi(v2.w));
            acc[12] += mkf2(bflo(v3.x), bfhi(v3.x));
            acc[13] += mkf2(bflo(v3.y), bfhi(v3.y));
            acc[14] += mkf2(bflo(v3.z), bfhi(v3.z));
            acc[15] += mkf2(bflo(v3.w), bfhi(v3.w));
        };
        if (seglen <= SCAP) {
            for (int k = start + sl; k < end; k += 16) body(csr_sh[k - s_lo]);
        } else {
            for (int k = start + sl; k < end; k += 16)
                body(__builtin_nontemporal_load(&csr[k]));
        }
        if (sl == 0) body(n);                            // self loop
    }
    float a[32];
#pragma unroll
    for (int j = 0; j < 16; ++j) { a[2 * j] = acc[j].x; a[2 * j + 1] = acc[j].y; }
    // fold: lane sl ends with orig elements (2sl, 2sl+1) = (ch sl, ch sl+16)
#pragma unroll
    for (int j = 0; j < 16; ++j) {
        float tt = (sl & 8) ? a[j + 16] : a[j];
        float uu = (sl & 8) ? a[j] : a[j + 16];
        a[j] = tt + __shfl_xor(uu, 8);
    }
#pragma unroll
    for (int j = 0; j < 8; ++j) {
        float tt = (sl & 4) ? a[j + 8] : a[j];
        float uu = (sl & 4) ? a[j] : a[j + 8];
        a[j] = tt + __shfl_xor(uu, 4);
    }
#pragma unroll
    for (int j = 0; j < 4; ++j) {
        float tt = (sl & 2) ? a[j + 4] : a[j];
        float uu = (sl & 2) ? a[j] : a[j + 4];
        a[j] = tt + __shfl_xor(uu, 2);
    }
#pragma unroll
    for (int j = 0; j < 2; ++j) {
        float tt = (sl & 1) ? a[j + 2] : a[j];
        float uu = (sl & 1) ? a[j] : a[j + 2];
        a[j] = tt + __shfl_xor(uu, 1);
    }
    if (n < N) {
        cont[ln][sl]      = dinv * a[0] + b2[sl];
        cont[ln][sl + 16] = dinv * a[1] + b2[sl + 16];
        if (sl == 0) bsh[ln] = batch[n];
    } else {
        cont[ln][sl] = 0.f;
        cont[ln][sl + 16] = 0.f;
        if (sl == 0) bsh[ln] = -1;
    }
    __syncthreads();
    if (tid < OUTC) {
        int c = tid;
        float run = 0.f; int cur = -1;
        for (int j = 0; j < 16; ++j) {
            int bj = bsh[j];
            if (bj < 0) continue;
            if (bj == cur) run += cont[j][c];
            else {
                if (cur >= 0) atomicAdd(&pool[(size_t)cur * OUTC + c], run);
                cur = bj; run = cont[j][c];
            }
        }
        if (cur >= 0) atomicAdd(&pool[(size_t)cur * OUTC + c], run);
        if (c == 0) {
            float crun = 0.f; cur = -1;
            for (int j = 0; j < 16; ++j) {
                int bj = bsh[j];
                if (bj < 0) continue;
                if (bj == cur) crun += 1.f;
                else {
                    if (cur >= 0) atomicAdd(&cntg[cur], crun);
                    cur = bj; crun = 1.f;
                }
            }
            if (cur >= 0) atomicAdd(&cntg[cur], crun);
        }
    }
}

// ---------- final: pooled mean -> fc1(relu) -> fc2 ----------
__global__ void k_final(const float* __restrict__ pool, const float* __restrict__ cntg,
                        const float* __restrict__ Wf1, const float* __restrict__ bf1,
                        const float* __restrict__ Wf2, const float* __restrict__ bf2,
                        float* out, int G) {
    __shared__ float p[OUTC], t[OUTC];
    int g = blockIdx.x;
    int c = threadIdx.x;
    float csafe = fmaxf(cntg[g], 1.0f);
    p[c] = pool[g * OUTC + c] / csafe;
    __syncthreads();
    float acc = bf1[c];
#pragma unroll
    for (int k = 0; k < OUTC; ++k) acc += p[k] * Wf1[k * OUTC + c];
    t[c] = fmaxf(acc, 0.f);
    __syncthreads();
    float acc2 = bf2[c];
#pragma unroll
    for (int k = 0; k < OUTC; ++k) acc2 += t[k] * Wf2[k * OUTC + c];
    out[g * OUTC + c] = acc2;
}

extern "C" void kernel_launch(void* const* d_in, const int* in_sizes, int n_in,
                              void* d_out, int out_size, void* d_ws, size_t ws_size,
                              hipStream_t stream) {
    const float* x    = (const float*)d_in[0];
    const int*   ei   = (const int*)  d_in[1];
    const int*   batch= (const int*)  d_in[2];
    const float* W1   = (const float*)d_in[3];
    const float* b1   = (const float*)d_in[4];
    const float* W2   = (const float*)d_in[5];
    const float* b2   = (const float*)d_in[6];
    const float* Wf1  = (const float*)d_in[7];
    const float* bf1  = (const float*)d_in[8];
    const float* Wf2  = (const float*)d_in[9];
    const float* bf2  = (const float*)d_in[10];

    const int N = in_sizes[0] / IN_C;
    const int E = in_sizes[1] / 2;
    const int G = out_size / OUTC;
    const int* src = ei;
    const int* dst = ei + E;

    const int nblkA = (E + CH - 1) / CH;
    const int NB    = (N + 255) >> 8;

    // ---- workspace layout ----
    char* w = (char*)d_ws;
    int*   csr      = (int*)w;   w += (size_t)E * sizeof(int);
    int2*  meta     = (int2*)w;  w += (size_t)N * sizeof(int2);
    unsigned* xs16h = (unsigned*)w; w += (size_t)N * 8 * sizeof(unsigned);
    unsigned* hs2   = (unsigned*)w; w += (size_t)N * 16 * sizeof(unsigned);
    unsigned short* xs17h = (unsigned short*)w; w += (size_t)N * sizeof(unsigned short);
    w = (char*)(((size_t)w + 15) & ~(size_t)15);
    float* pool     = (float*)w; w += (size_t)G * OUTC * sizeof(float);
    float* cntg     = (float*)w; w += (size_t)G * sizeof(float);
    w = (char*)(((size_t)w + 15) & ~(size_t)15);
    int*   outbuf   = (int*)w;   w += (size_t)E * sizeof(int);
    int*   cntmat   = (int*)w;   w += (size_t)nblkA * NBP * sizeof(int);
    int*   offmat   = (int*)w;   w += (size_t)nblkA * NBP * sizeof(int);
    int*   bbase    = (int*)w;   w += NBP * sizeof(int);
    int*   part     = (int*)w;   w += BS_BLKS * NBP * sizeof(int);
    w = (char*)(((size_t)w + 15) & ~(size_t)15);
    unsigned short* h1b = (unsigned short*)w; w += (size_t)(N + 64) * HID * sizeof(unsigned short);
    uint4* w2frag   = (uint4*)w; w += 4 * 64 * sizeof(uint4);

    hipMemsetAsync(pool, 0, (size_t)(G * OUTC + G) * sizeof(float), stream);

    // CSR build (counting sort) + fused x prep + W2 fragment pack
    k_binA<<<nblkA, TA, 0, stream>>>(src, dst, E, outbuf, cntmat, offmat);
    k_bsum1<<<BS_BLKS, NBP, 0, stream>>>(cntmat, nblkA, part);
    k_bsum2<<<1, NBP, 0, stream>>>(part, bbase, W2, w2frag);
    k_binB<<<NB, TA, 0, stream>>>(outbuf, cntmat, offmat, bbase, nblkA, N,
                                  csr, meta, x, xs16h, xs17h);

    // layer 1: gather + matvec1 -> bf16 h1b (dinv pre-applied)
    dim3 blk(256);
    k_gather1<<<(N + 15) / 16, blk, 0, stream>>>((const uint4*)xs16h, xs17h, csr, meta,
                                                 W1, b1, h1b, N);

    // layer 2 projection via MFMA
    k_mm2f<<<(N + 63) / 64, blk, 0, stream>>>(h1b, w2frag, hs2, N);

    // layer 2 gather + pool
    k_gather2<<<(N + 15) / 16, blk, 0, stream>>>((const uint4*)hs2, csr, meta,
                                                 b2, batch, pool, cntg, N);

    // readout
    k_final<<<G, OUTC, 0, stream>>>(pool, cntg, Wf1, bf1, Wf2, bf2, (float*)d_out, G);
}

// Round 13
// 130.745 us; speedup vs baseline: 2.0343x; 1.0344x over previous
//
#include <hip/hip_runtime.h>

#define IN_C 17
#define HID  64
#define OUTC 32

#define CH   8192      // edges per pass-A block
#define TA   512       // pass-A threads
#define NBP  512       // padded bucket count (bucket = dst>>8; N<=131072)
#define BCAP 5632      // pass-B stage capacity
#define SCAP 1024      // per-block CSR stage capacity (gathers)
#define BS_BLKS 8

typedef __attribute__((ext_vector_type(2))) float f2;
typedef __attribute__((ext_vector_type(8))) short bf16x8;
typedef __attribute__((ext_vector_type(4))) float f32x4;
__device__ __forceinline__ f2 mkf2(float x, float y) { f2 r; r.x = x; r.y = y; return r; }

__device__ __forceinline__ unsigned short f2bf(float f) {
    unsigned u = __float_as_uint(f);
    u += 0x7fffu + ((u >> 16) & 1u);      // round-nearest-even
    return (unsigned short)(u >> 16);
}
__device__ __forceinline__ float bflo(unsigned u) { return __uint_as_float(u << 16); }
__device__ __forceinline__ float bfhi(unsigned u) { return __uint_as_float(u & 0xffff0000u); }

// ================= pass A: bin edges by dst>>8, coalesced writes =================
__global__ __launch_bounds__(TA) void k_binA(const int* __restrict__ src,
        const int* __restrict__ dst, int E,
        int* __restrict__ outbuf, int* __restrict__ cntmat, int* __restrict__ offmat) {
    __shared__ int cnt[NBP];
    __shared__ int off[NBP];
    __shared__ int stage[CH];
    int t = threadIdx.x;
    long base = (long)blockIdx.x * CH;
    int nE = (int)(E - base); if (nE > CH) nE = CH;
    cnt[t] = 0;
    __syncthreads();
    int bk[16], pk[16], rk[16];
#pragma unroll
    for (int j = 0; j < 16; ++j) {
        int idx = t + j * TA;
        if (idx < nE) {
            long e = base + idx;
            int d = __builtin_nontemporal_load(&dst[e]);
            int s = __builtin_nontemporal_load(&src[e]);
            int b = d >> 8;
            bk[j] = b;
            pk[j] = s | ((d & 255) << 17);
            rk[j] = atomicAdd(&cnt[b], 1);
        } else bk[j] = -1;
    }
    __syncthreads();
    int c = cnt[t];
    off[t] = c;
    __syncthreads();
    int inc = c;
    for (int s = 1; s < NBP; s <<= 1) {
        int add = (t >= s) ? off[t - s] : 0;
        __syncthreads();
        inc += add; off[t] = inc;
        __syncthreads();
    }
    int excl = inc - c;
    __syncthreads();
    off[t] = excl;
    __syncthreads();
#pragma unroll
    for (int j = 0; j < 16; ++j)
        if (bk[j] >= 0) stage[off[bk[j]] + rk[j]] = pk[j];
    __syncthreads();
    for (int i = t; i < nE; i += TA) outbuf[base + i] = stage[i];
    cntmat[blockIdx.x * NBP + t] = c;
    offmat[blockIdx.x * NBP + t] = excl;
}

// ============ bucket totals (parallel partial) + pool zero-init ============
__global__ __launch_bounds__(NBP) void k_bsum1(const int* __restrict__ cntmat,
        int nblkA, int* __restrict__ part, float* __restrict__ pool, int poolN) {
    int t = threadIdx.x, b = blockIdx.x;
    int per = (nblkA + BS_BLKS - 1) / BS_BLKS;
    int i0 = b * per, i1 = min(i0 + per, nblkA);
    int s = 0;
    for (int i = i0; i < i1; ++i) s += cntmat[i * NBP + t];
    part[b * NBP + t] = s;
    // zero the pool+cntg region (replaces pathological hipMemsetAsync fill)
    for (int i = b * NBP + t; i < poolN; i += BS_BLKS * NBP) pool[i] = 0.f;
}

__global__ __launch_bounds__(NBP) void k_bsum2(const int* __restrict__ part,
        int* __restrict__ bbase, const float* __restrict__ W2,
        uint4* __restrict__ w2frag) {
    __shared__ int sh[NBP];
    int t = threadIdx.x;
    int s = 0;
#pragma unroll
    for (int i = 0; i < BS_BLKS; ++i) s += part[i * NBP + t];
    sh[t] = s;
    __syncthreads();
    int inc = s;
    for (int st = 1; st < NBP; st <<= 1) {
        int add = (t >= st) ? sh[t - st] : 0;
        __syncthreads();
        inc += add; sh[t] = inc;
        __syncthreads();
    }
    bbase[t] = inc - s;
    // pack W2 into MFMA B-fragment layout: frag f = kt*2+nt; lane l holds
    // B[k = kt*32 + (l>>4)*8 + j][c = nt*16 + (l&15)], j=0..7
    if (t < 256) {
        int f = t >> 6, l = t & 63;
        int kt = f >> 1, nt = f & 1;
        int kbase = kt * 32 + (l >> 4) * 8;
        int c = nt * 16 + (l & 15);
        unsigned short v[8];
#pragma unroll
        for (int j = 0; j < 8; ++j) v[j] = f2bf(W2[(kbase + j) * OUTC + c]);
        uint4 o;
        o.x = (unsigned)v[0] | ((unsigned)v[1] << 16);
        o.y = (unsigned)v[2] | ((unsigned)v[3] << 16);
        o.z = (unsigned)v[4] | ((unsigned)v[5] << 16);
        o.w = (unsigned)v[6] | ((unsigned)v[7] << 16);
        w2frag[f * 64 + l] = o;
    }
}

// === pass B: per bucket, gather runs, emit CSR + meta(start,deg) + bf16 xs (fused prep) ===
__global__ __launch_bounds__(TA) void k_binB(const int* __restrict__ outbuf,
        const int* __restrict__ cntmat, const int* __restrict__ offmat,
        const int* __restrict__ bbase, int nblkA, int N,
        int* __restrict__ csr, int2* __restrict__ meta,
        const float* __restrict__ x, unsigned* __restrict__ xs16h,
        unsigned short* __restrict__ xs17h) {
    __shared__ int segc[256], sego[256], segs[256];
    __shared__ int ndeg[256], noff[256];
    __shared__ int stage[BCAP];
    int t = threadIdx.x, b = blockIdx.x;
    if (t < 256) {
        int cc = 0, ss = 0;
        if (t < nblkA) { cc = cntmat[t * NBP + b]; ss = offmat[t * NBP + b]; }
        segc[t] = cc; segs[t] = ss; sego[t] = cc;
        ndeg[t] = 0;
    }
    __syncthreads();
    {
        int c = (t < 256) ? sego[t] : 0;
        int inc = c;
        for (int s = 1; s < 256; s <<= 1) {
            int add = (t < 256 && t >= s) ? sego[t - s] : 0;
            __syncthreads();
            if (t < 256) { inc += add; sego[t] = inc; }
            __syncthreads();
        }
        if (t < 256) sego[t] = inc - c;
    }
    __syncthreads();
    int wave = t >> 6, lane = t & 63;
    for (int i = wave; i < nblkA; i += TA / 64) {
        int c = segc[i], so = sego[i];
        long gs = (long)i * CH + segs[i];
        for (int l = lane; l < c; l += 64) {
            int p = so + l;
            if (p < BCAP) stage[p] = __builtin_nontemporal_load(&outbuf[gs + l]);
        }
    }
    __syncthreads();
    int T = sego[255] + segc[255];
    if (T > BCAP) T = BCAP;
    int mypk[11], myrk[11], ne = 0;
    for (int k = t; k < T; k += TA) {
        int p = stage[k];
        int l = (p >> 17) & 255;
        myrk[ne] = atomicAdd(&ndeg[l], 1);
        mypk[ne] = p;
        ne++;
    }
    __syncthreads();
    {
        int c = (t < 256) ? ndeg[t] : 0;
        if (t < 256) noff[t] = c;
        __syncthreads();
        int inc = c;
        for (int s = 1; s < 256; s <<= 1) {
            int add = (t < 256 && t >= s) ? noff[t - s] : 0;
            __syncthreads();
            if (t < 256) { inc += add; noff[t] = inc; }
            __syncthreads();
        }
        if (t < 256) noff[t] = inc - c;
    }
    __syncthreads();
    int gb = bbase[b];
    int n0 = b << 8;
    if (t < 256 && n0 + t < N) {
        int n = n0 + t;
        meta[n] = make_int2(gb + noff[t], ndeg[t]);
        float dinv = rsqrtf((float)(ndeg[t] + 1));
        const float* xr = x + (size_t)n * IN_C;
        unsigned* xo = xs16h + (size_t)n * 8;
#pragma unroll
        for (int w2 = 0; w2 < 8; ++w2) {
            unsigned lo = f2bf(xr[2 * w2] * dinv);
            unsigned hi = f2bf(xr[2 * w2 + 1] * dinv);
            xo[w2] = lo | (hi << 16);
        }
        xs17h[n] = f2bf(xr[16] * dinv);
    }
    for (int j = 0; j < ne; ++j) {
        int p = mypk[j];
        int l = (p >> 17) & 255;
        csr[gb + noff[l] + myrk[j]] = p & 0x1FFFF;
    }
}

// ---------- layer 1: csr LDS-staged gather -> fold -> matvec1 -> bf16 h1b (dinv folded) ----------
__global__ __launch_bounds__(256) void k_gather1(
        const uint4* __restrict__ xs16v, const unsigned short* __restrict__ xs17h,
        const int* __restrict__ csr, const int2* __restrict__ meta,
        const float* __restrict__ W1, const float* __restrict__ b1,
        unsigned short* __restrict__ h1b, int N) {
    __shared__ __align__(16) float aggx[16][20];
    __shared__ float dinv_sh[16];
    __shared__ int csr_sh[SCAP];

    int tid = threadIdx.x;
    int n0 = blockIdx.x * 16;
    int nlast = min(n0 + 15, N - 1);
    int2 m0 = meta[n0];
    int2 mlv = meta[nlast];
    int s_lo = m0.x;
    int seglen = mlv.x + mlv.y - s_lo;
    int sg = min(seglen, SCAP);
    for (int i = tid; i < sg; i += 256)
        csr_sh[i] = __builtin_nontemporal_load(&csr[s_lo + i]);
    int ch = tid & 63;
    float w1r[IN_C];
#pragma unroll
    for (int k = 0; k < IN_C; ++k) w1r[k] = W1[k * HID + ch];
    float b1v = b1[ch];
    __syncthreads();

    int ln = tid >> 4, sl = tid & 15;
    int n = n0 + ln;
    f2 acc[8];
#pragma unroll
    for (int j = 0; j < 8; ++j) acc[j] = mkf2(0.f, 0.f);
    float a17 = 0.f;
    if (n < N) {
        int2 m = meta[n];
        int start = m.x, cnt = m.y, end = start + cnt;
        auto body = [&](int s) {
            uint4 v0 = xs16v[(size_t)s * 2];
            uint4 v1 = xs16v[(size_t)s * 2 + 1];
            acc[0] += mkf2(bflo(v0.x), bfhi(v0.x));
            acc[1] += mkf2(bflo(v0.y), bfhi(v0.y));
            acc[2] += mkf2(bflo(v0.z), bfhi(v0.z));
            acc[3] += mkf2(bflo(v0.w), bfhi(v0.w));
            acc[4] += mkf2(bflo(v1.x), bfhi(v1.x));
            acc[5] += mkf2(bflo(v1.y), bfhi(v1.y));
            acc[6] += mkf2(bflo(v1.z), bfhi(v1.z));
            acc[7] += mkf2(bflo(v1.w), bfhi(v1.w));
            a17 += bflo((unsigned)xs17h[s]);
        };
        if (seglen <= SCAP) {
            for (int k = start + sl; k < end; k += 16) body(csr_sh[k - s_lo]);
        } else {
            for (int k = start + sl; k < end; k += 16)
                body(__builtin_nontemporal_load(&csr[k]));
        }
        if (sl == 0) {                                   // self loop
            body(n);
            dinv_sh[ln] = rsqrtf((float)(cnt + 1));
        }
    }
    float a[16];
#pragma unroll
    for (int j = 0; j < 8; ++j) { a[2 * j] = acc[j].x; a[2 * j + 1] = acc[j].y; }
#pragma unroll
    for (int j = 0; j < 8; ++j) {
        float tt = (sl & 8) ? a[j + 8] : a[j];
        float uu = (sl & 8) ? a[j] : a[j + 8];
        a[j] = tt + __shfl_xor(uu, 8);
    }
#pragma unroll
    for (int j = 0; j < 4; ++j) {
        float tt = (sl & 4) ? a[j + 4] : a[j];
        float uu = (sl & 4) ? a[j] : a[j + 4];
        a[j] = tt + __shfl_xor(uu, 4);
    }
#pragma unroll
    for (int j = 0; j < 2; ++j) {
        float tt = (sl & 2) ? a[j + 2] : a[j];
        float uu = (sl & 2) ? a[j] : a[j + 2];
        a[j] = tt + __shfl_xor(uu, 2);
    }
    {
        float tt = (sl & 1) ? a[1] : a[0];
        float uu = (sl & 1) ? a[0] : a[1];
        a[0] = tt + __shfl_xor(uu, 1);
    }
    a17 += __shfl_xor(a17, 1);
    a17 += __shfl_xor(a17, 2);
    a17 += __shfl_xor(a17, 4);
    a17 += __shfl_xor(a17, 8);
    aggx[ln][sl] = a[0];
    if (sl == 0) aggx[ln][16] = a17;
    __syncthreads();
    // matvec1 + bias + relu, dinv folded into stored h1b (bf16)
    int s0 = tid >> 6;
#pragma unroll
    for (int rep = 0; rep < 4; ++rep) {
        int slot = s0 + rep * 4;
        int nn = n0 + slot;
        if (nn < N) {
            const float4* ap = (const float4*)aggx[slot];
            float4 A0 = ap[0], A1 = ap[1], A2 = ap[2], A3 = ap[3];
            float a16 = aggx[slot][16];
            float dot = A0.x * w1r[0]  + A0.y * w1r[1]  + A0.z * w1r[2]  + A0.w * w1r[3]
                      + A1.x * w1r[4]  + A1.y * w1r[5]  + A1.z * w1r[6]  + A1.w * w1r[7]
                      + A2.x * w1r[8]  + A2.y * w1r[9]  + A2.z * w1r[10] + A2.w * w1r[11]
                      + A3.x * w1r[12] + A3.y * w1r[13] + A3.z * w1r[14] + A3.w * w1r[15]
                      + a16  * w1r[16];
            float dv = dinv_sh[slot];
            float r = fmaxf(dv * dot + b1v, 0.f);
            h1b[(size_t)nn * HID + ch] = f2bf(dv * r);
        }
    }
}

// ---------- mm2 via MFMA: hs2 = h1b @ W2, word w = (ch w, ch w+16) ----------
__global__ __launch_bounds__(256) void k_mm2f(
        const unsigned short* __restrict__ h1b, const uint4* __restrict__ w2frag,
        unsigned* __restrict__ hs2, int N) {
    int tid = threadIdx.x;
    int wv = tid >> 6, l = tid & 63;
    int n0w = blockIdx.x * 64 + wv * 16;
    int row = l & 15, kq = l >> 4;
    const bf16x8* a0p = (const bf16x8*)(h1b + (size_t)(n0w + row) * HID + kq * 8);
    const bf16x8* a1p = (const bf16x8*)(h1b + (size_t)(n0w + row) * HID + 32 + kq * 8);
    bf16x8 a0 = *a0p;
    bf16x8 a1 = *a1p;
    bf16x8 b00 = *(const bf16x8*)&w2frag[0 * 64 + l];   // kt0, nt0
    bf16x8 b01 = *(const bf16x8*)&w2frag[1 * 64 + l];   // kt0, nt1
    bf16x8 b10 = *(const bf16x8*)&w2frag[2 * 64 + l];   // kt1, nt0
    bf16x8 b11 = *(const bf16x8*)&w2frag[3 * 64 + l];   // kt1, nt1
    f32x4 d0 = {0.f, 0.f, 0.f, 0.f}, d1 = {0.f, 0.f, 0.f, 0.f};
    d0 = __builtin_amdgcn_mfma_f32_16x16x32_bf16(a0, b00, d0, 0, 0, 0);
    d0 = __builtin_amdgcn_mfma_f32_16x16x32_bf16(a1, b10, d0, 0, 0, 0);
    d1 = __builtin_amdgcn_mfma_f32_16x16x32_bf16(a0, b01, d1, 0, 0, 0);
    d1 = __builtin_amdgcn_mfma_f32_16x16x32_bf16(a1, b11, d1, 0, 0, 0);
    int wcol = l & 15;
    int rbase = (l >> 4) * 4;
#pragma unroll
    for (int r = 0; r < 4; ++r) {
        int node = n0w + rbase + r;
        if (node < N)
            hs2[(size_t)node * 16 + wcol] =
                (unsigned)f2bf(d0[r]) | ((unsigned)f2bf(d1[r]) << 16);
    }
}

// ---------- layer 2 gather: csr LDS-staged, 1 lane/edge + pool ----------
__global__ __launch_bounds__(256) void k_gather2(
        const uint4* __restrict__ hs2v, const int* __restrict__ csr,
        const int2* __restrict__ meta, const float* __restrict__ b2,
        const int* __restrict__ batch, float* pool, float* cntg, int N) {
    __shared__ __align__(16) float cont[16][OUTC];
    __shared__ int bsh[16];
    __shared__ int csr_sh[SCAP];
    int tid = threadIdx.x;
    int n0 = blockIdx.x * 16;
    int nlast = min(n0 + 15, N - 1);
    int2 m0 = meta[n0];
    int2 mlv = meta[nlast];
    int s_lo = m0.x;
    int seglen = mlv.x + mlv.y - s_lo;
    int sg = min(seglen, SCAP);
    for (int i = tid; i < sg; i += 256)
        csr_sh[i] = __builtin_nontemporal_load(&csr[s_lo + i]);
    __syncthreads();

    int ln = tid >> 4, sl = tid & 15;
    int n = n0 + ln;
    f2 acc[16];
#pragma unroll
    for (int j = 0; j < 16; ++j) acc[j] = mkf2(0.f, 0.f);
    float dinv = 0.f;
    if (n < N) {
        int2 m = meta[n];
        int start = m.x, cnt = m.y, end = start + cnt;
        dinv = rsqrtf((float)(cnt + 1));
        auto body = [&](int s) {
            const uint4* rp = hs2v + (size_t)s * 4;
            uint4 v0 = rp[0], v1 = rp[1], v2 = rp[2], v3 = rp[3];
            acc[0]  += mkf2(bflo(v0.x), bfhi(v0.x));
            acc[1]  += mkf2(bflo(v0.y), bfhi(v0.y));
            acc[2]  += mkf2(bflo(v0.z), bfhi(v0.z));
            acc[3]  += mkf2(bflo(v0.w), bfhi(v0.w));
            acc[4]  += mkf2(bflo(v1.x), bfhi(v1.x));
            acc[5]  += mkf2(bflo(v1.y), bfhi(v1.y));
            acc[6]  += mkf2(bflo(v1.z), bfhi(v1.z));
            acc[7]  += mkf2(bflo(v1.w), bfhi(v1.w));
            acc[8]  += mkf2(bflo(v2.x), bfhi(v2.x));
            acc[9]  += mkf2(bflo(v2.y), bfhi(v2.y));
            acc[10] += mkf2(bflo(v2.z), bfhi(v2.z));
            acc[11] += mkf2(bflo(v2.w), bfhi(v2.w));
            acc[12] += mkf2(bflo(v3.x), bfhi(v3.x));
            acc[13] += mkf2(bflo(v3.y), bfhi(v3.y));
            acc[14] += mkf2(bflo(v3.z), bfhi(v3.z));
            acc[15] += mkf2(bflo(v3.w), bfhi(v3.w));
        };
        if (seglen <= SCAP) {
            for (int k = start + sl; k < end; k += 16) body(csr_sh[k - s_lo]);
        } else {
            for (int k = start + sl; k < end; k += 16)
                body(__builtin_nontemporal_load(&csr[k]));
        }
        if (sl == 0) body(n);                            // self loop
    }
    float a[32];
#pragma unroll
    for (int j = 0; j < 16; ++j) { a[2 * j] = acc[j].x; a[2 * j + 1] = acc[j].y; }
    // fold: lane sl ends with orig elements (2sl, 2sl+1) = (ch sl, ch sl+16)
#pragma unroll
    for (int j = 0; j < 16; ++j) {
        float tt = (sl & 8) ? a[j + 16] : a[j];
        float uu = (sl & 8) ? a[j] : a[j + 16];
        a[j] = tt + __shfl_xor(uu, 8);
    }
#pragma unroll
    for (int j = 0; j < 8; ++j) {
        float tt = (sl & 4) ? a[j + 8] : a[j];
        float uu = (sl & 4) ? a[j] : a[j + 8];
        a[j] = tt + __shfl_xor(uu, 4);
    }
#pragma unroll
    for (int j = 0; j < 4; ++j) {
        float tt = (sl & 2) ? a[j + 4] : a[j];
        float uu = (sl & 2) ? a[j] : a[j + 4];
        a[j] = tt + __shfl_xor(uu, 2);
    }
#pragma unroll
    for (int j = 0; j < 2; ++j) {
        float tt = (sl & 1) ? a[j + 2] : a[j];
        float uu = (sl & 1) ? a[j] : a[j + 2];
        a[j] = tt + __shfl_xor(uu, 1);
    }
    if (n < N) {
        cont[ln][sl]      = dinv * a[0] + b2[sl];
        cont[ln][sl + 16] = dinv * a[1] + b2[sl + 16];
        if (sl == 0) bsh[ln] = batch[n];
    } else {
        cont[ln][sl] = 0.f;
        cont[ln][sl + 16] = 0.f;
        if (sl == 0) bsh[ln] = -1;
    }
    __syncthreads();
    if (tid < OUTC) {
        int c = tid;
        float run = 0.f; int cur = -1;
        for (int j = 0; j < 16; ++j) {
            int bj = bsh[j];
            if (bj < 0) continue;
            if (bj == cur) run += cont[j][c];
            else {
                if (cur >= 0) atomicAdd(&pool[(size_t)cur * OUTC + c], run);
                cur = bj; run = cont[j][c];
            }
        }
        if (cur >= 0) atomicAdd(&pool[(size_t)cur * OUTC + c], run);
        if (c == 0) {
            float crun = 0.f; cur = -1;
            for (int j = 0; j < 16; ++j) {
                int bj = bsh[j];
                if (bj < 0) continue;
                if (bj == cur) crun += 1.f;
                else {
                    if (cur >= 0) atomicAdd(&cntg[cur], crun);
                    cur = bj; crun = 1.f;
                }
            }
            if (cur >= 0) atomicAdd(&cntg[cur], crun);
        }
    }
}

// ---------- final: pooled mean -> fc1(relu) -> fc2 ----------
__global__ void k_final(const float* __restrict__ pool, const float* __restrict__ cntg,
                        const float* __restrict__ Wf1, const float* __restrict__ bf1,
                        const float* __restrict__ Wf2, const float* __restrict__ bf2,
                        float* out, int G) {
    __shared__ float p[OUTC], t[OUTC];
    int g = blockIdx.x;
    int c = threadIdx.x;
    float csafe = fmaxf(cntg[g], 1.0f);
    p[c] = pool[g * OUTC + c] / csafe;
    __syncthreads();
    float acc = bf1[c];
#pragma unroll
    for (int k = 0; k < OUTC; ++k) acc += p[k] * Wf1[k * OUTC + c];
    t[c] = fmaxf(acc, 0.f);
    __syncthreads();
    float acc2 = bf2[c];
#pragma unroll
    for (int k = 0; k < OUTC; ++k) acc2 += t[k] * Wf2[k * OUTC + c];
    out[g * OUTC + c] = acc2;
}

extern "C" void kernel_launch(void* const* d_in, const int* in_sizes, int n_in,
                              void* d_out, int out_size, void* d_ws, size_t ws_size,
                              hipStream_t stream) {
    const float* x    = (const float*)d_in[0];
    const int*   ei   = (const int*)  d_in[1];
    const int*   batch= (const int*)  d_in[2];
    const float* W1   = (const float*)d_in[3];
    const float* b1   = (const float*)d_in[4];
    const float* W2   = (const float*)d_in[5];
    const float* b2   = (const float*)d_in[6];
    const float* Wf1  = (const float*)d_in[7];
    const float* bf1  = (const float*)d_in[8];
    const float* Wf2  = (const float*)d_in[9];
    const float* bf2  = (const float*)d_in[10];

    const int N = in_sizes[0] / IN_C;
    const int E = in_sizes[1] / 2;
    const int G = out_size / OUTC;
    const int* src = ei;
    const int* dst = ei + E;

    const int nblkA = (E + CH - 1) / CH;
    const int NB    = (N + 255) >> 8;

    // ---- workspace layout ----
    char* w = (char*)d_ws;
    int*   csr      = (int*)w;   w += (size_t)E * sizeof(int);
    int2*  meta     = (int2*)w;  w += (size_t)N * sizeof(int2);
    unsigned* xs16h = (unsigned*)w; w += (size_t)N * 8 * sizeof(unsigned);
    unsigned* hs2   = (unsigned*)w; w += (size_t)N * 16 * sizeof(unsigned);
    unsigned short* xs17h = (unsigned short*)w; w += (size_t)N * sizeof(unsigned short);
    w = (char*)(((size_t)w + 15) & ~(size_t)15);
    float* pool     = (float*)w; w += (size_t)G * OUTC * sizeof(float);
    float* cntg     = (float*)w; w += (size_t)G * sizeof(float);
    w = (char*)(((size_t)w + 15) & ~(size_t)15);
    int*   outbuf   = (int*)w;   w += (size_t)E * sizeof(int);
    int*   cntmat   = (int*)w;   w += (size_t)nblkA * NBP * sizeof(int);
    int*   offmat   = (int*)w;   w += (size_t)nblkA * NBP * sizeof(int);
    int*   bbase    = (int*)w;   w += NBP * sizeof(int);
    int*   part     = (int*)w;   w += BS_BLKS * NBP * sizeof(int);
    w = (char*)(((size_t)w + 15) & ~(size_t)15);
    unsigned short* h1b = (unsigned short*)w; w += (size_t)(N + 64) * HID * sizeof(unsigned short);
    uint4* w2frag   = (uint4*)w; w += 4 * 64 * sizeof(uint4);

    const int poolN = G * OUTC + G;   // pool + cntg are contiguous floats

    // CSR build (counting sort) + fused x prep + W2 fragment pack + pool zero
    k_binA<<<nblkA, TA, 0, stream>>>(src, dst, E, outbuf, cntmat, offmat);
    k_bsum1<<<BS_BLKS, NBP, 0, stream>>>(cntmat, nblkA, part, pool, poolN);
    k_bsum2<<<1, NBP, 0, stream>>>(part, bbase, W2, w2frag);
    k_binB<<<NB, TA, 0, stream>>>(outbuf, cntmat, offmat, bbase, nblkA, N,
                                  csr, meta, x, xs16h, xs17h);

    // layer 1: gather + matvec1 -> bf16 h1b (dinv pre-applied)
    dim3 blk(256);
    k_gather1<<<(N + 15) / 16, blk, 0, stream>>>((const uint4*)xs16h, xs17h, csr, meta,
                                                 W1, b1, h1b, N);

    // layer 2 projection via MFMA
    k_mm2f<<<(N + 63) / 64, blk, 0, stream>>>(h1b, w2frag, hs2, N);

    // layer 2 gather + pool
    k_gather2<<<(N + 15) / 16, blk, 0, stream>>>((const uint4*)hs2, csr, meta,
                                                 b2, batch, pool, cntg, N);

    // readout
    k_final<<<G, OUTC, 0, stream>>>(pool, cntg, Wf1, bf1, Wf2, bf2, (float*)d_out, G);
}

// Round 14
// 125.346 us; speedup vs baseline: 2.1220x; 1.0431x over previous
//
#include <hip/hip_runtime.h>

#define IN_C 17
#define HID  64
#define OUTC 32

#define CH   8192      // edges per pass-A block
#define TA   512       // pass-A threads
#define NBP  512       // padded bucket count (bucket = dst>>8; N<=131072)
#define BCAP 5632      // pass-B stage capacity
#define SCAP 1024      // per-block CSR stage capacity (gathers)
#define BS_BLKS 8

typedef __attribute__((ext_vector_type(2))) float f2;
typedef __attribute__((ext_vector_type(8))) short bf16x8;
typedef __attribute__((ext_vector_type(4))) float f32x4;
__device__ __forceinline__ f2 mkf2(float x, float y) { f2 r; r.x = x; r.y = y; return r; }

__device__ __forceinline__ unsigned short f2bf(float f) {
    unsigned u = __float_as_uint(f);
    u += 0x7fffu + ((u >> 16) & 1u);      // round-nearest-even
    return (unsigned short)(u >> 16);
}
__device__ __forceinline__ float bflo(unsigned u) { return __uint_as_float(u << 16); }
__device__ __forceinline__ float bfhi(unsigned u) { return __uint_as_float(u & 0xffff0000u); }

// ================= pass A: bin edges by dst>>8, coalesced writes =================
__global__ __launch_bounds__(TA) void k_binA(const int* __restrict__ src,
        const int* __restrict__ dst, int E,
        int* __restrict__ outbuf, int* __restrict__ cntmat, int* __restrict__ offmat) {
    __shared__ int cnt[NBP];
    __shared__ int off[NBP];
    __shared__ int stage[CH];
    int t = threadIdx.x;
    long base = (long)blockIdx.x * CH;
    int nE = (int)(E - base); if (nE > CH) nE = CH;
    cnt[t] = 0;
    __syncthreads();
    int bk[16], pk[16], rk[16];
#pragma unroll
    for (int j = 0; j < 16; ++j) {
        int idx = t + j * TA;
        if (idx < nE) {
            long e = base + idx;
            int d = __builtin_nontemporal_load(&dst[e]);
            int s = __builtin_nontemporal_load(&src[e]);
            int b = d >> 8;
            bk[j] = b;
            pk[j] = s | ((d & 255) << 17);
            rk[j] = atomicAdd(&cnt[b], 1);
        } else bk[j] = -1;
    }
    __syncthreads();
    int c = cnt[t];
    off[t] = c;
    __syncthreads();
    int inc = c;
    for (int s = 1; s < NBP; s <<= 1) {
        int add = (t >= s) ? off[t - s] : 0;
        __syncthreads();
        inc += add; off[t] = inc;
        __syncthreads();
    }
    int excl = inc - c;
    __syncthreads();
    off[t] = excl;
    __syncthreads();
#pragma unroll
    for (int j = 0; j < 16; ++j)
        if (bk[j] >= 0) stage[off[bk[j]] + rk[j]] = pk[j];
    __syncthreads();
    for (int i = t; i < nE; i += TA) outbuf[base + i] = stage[i];
    cntmat[blockIdx.x * NBP + t] = c;
    offmat[blockIdx.x * NBP + t] = excl;
}

// ============ bucket totals (parallel partial) + pool zero-init ============
__global__ __launch_bounds__(NBP) void k_bsum1(const int* __restrict__ cntmat,
        int nblkA, int* __restrict__ part, float* __restrict__ pool, int poolN) {
    int t = threadIdx.x, b = blockIdx.x;
    int per = (nblkA + BS_BLKS - 1) / BS_BLKS;
    int i0 = b * per, i1 = min(i0 + per, nblkA);
    int s = 0;
    for (int i = i0; i < i1; ++i) s += cntmat[i * NBP + t];
    part[b * NBP + t] = s;
    // zero the pool+cntg region (replaces pathological hipMemsetAsync fill)
    for (int i = b * NBP + t; i < poolN; i += BS_BLKS * NBP) pool[i] = 0.f;
}

__global__ __launch_bounds__(NBP) void k_bsum2(const int* __restrict__ part,
        int* __restrict__ bbase, const float* __restrict__ W2,
        uint4* __restrict__ w2frag) {
    __shared__ int sh[NBP];
    int t = threadIdx.x;
    int s = 0;
#pragma unroll
    for (int i = 0; i < BS_BLKS; ++i) s += part[i * NBP + t];
    sh[t] = s;
    __syncthreads();
    int inc = s;
    for (int st = 1; st < NBP; st <<= 1) {
        int add = (t >= st) ? sh[t - st] : 0;
        __syncthreads();
        inc += add; sh[t] = inc;
        __syncthreads();
    }
    bbase[t] = inc - s;
    // pack W2 into MFMA B-fragment layout: frag f = kt*2+nt; lane l holds
    // B[k = kt*32 + (l>>4)*8 + j][c = nt*16 + (l&15)], j=0..7
    if (t < 256) {
        int f = t >> 6, l = t & 63;
        int kt = f >> 1, nt = f & 1;
        int kbase = kt * 32 + (l >> 4) * 8;
        int c = nt * 16 + (l & 15);
        unsigned short v[8];
#pragma unroll
        for (int j = 0; j < 8; ++j) v[j] = f2bf(W2[(kbase + j) * OUTC + c]);
        uint4 o;
        o.x = (unsigned)v[0] | ((unsigned)v[1] << 16);
        o.y = (unsigned)v[2] | ((unsigned)v[3] << 16);
        o.z = (unsigned)v[4] | ((unsigned)v[5] << 16);
        o.w = (unsigned)v[6] | ((unsigned)v[7] << 16);
        w2frag[f * 64 + l] = o;
    }
}

// === pass B: per bucket, gather runs, emit CSR + meta(start,deg) + bf16 xs (fused prep) ===
__global__ __launch_bounds__(TA) void k_binB(const int* __restrict__ outbuf,
        const int* __restrict__ cntmat, const int* __restrict__ offmat,
        const int* __restrict__ bbase, int nblkA, int N,
        int* __restrict__ csr, int2* __restrict__ meta,
        const float* __restrict__ x, unsigned* __restrict__ xs16h,
        unsigned short* __restrict__ xs17h) {
    __shared__ int segc[256], sego[256], segs[256];
    __shared__ int ndeg[256], noff[256];
    __shared__ int stage[BCAP];
    int t = threadIdx.x, b = blockIdx.x;
    if (t < 256) {
        int cc = 0, ss = 0;
        if (t < nblkA) { cc = cntmat[t * NBP + b]; ss = offmat[t * NBP + b]; }
        segc[t] = cc; segs[t] = ss; sego[t] = cc;
        ndeg[t] = 0;
    }
    __syncthreads();
    {
        int c = (t < 256) ? sego[t] : 0;
        int inc = c;
        for (int s = 1; s < 256; s <<= 1) {
            int add = (t < 256 && t >= s) ? sego[t - s] : 0;
            __syncthreads();
            if (t < 256) { inc += add; sego[t] = inc; }
            __syncthreads();
        }
        if (t < 256) sego[t] = inc - c;
    }
    __syncthreads();
    int wave = t >> 6, lane = t & 63;
    for (int i = wave; i < nblkA; i += TA / 64) {
        int c = segc[i], so = sego[i];
        long gs = (long)i * CH + segs[i];
        for (int l = lane; l < c; l += 64) {
            int p = so + l;
            if (p < BCAP) stage[p] = __builtin_nontemporal_load(&outbuf[gs + l]);
        }
    }
    __syncthreads();
    int T = sego[255] + segc[255];
    if (T > BCAP) T = BCAP;
    int mypk[11], myrk[11], ne = 0;
    for (int k = t; k < T; k += TA) {
        int p = stage[k];
        int l = (p >> 17) & 255;
        myrk[ne] = atomicAdd(&ndeg[l], 1);
        mypk[ne] = p;
        ne++;
    }
    __syncthreads();
    {
        int c = (t < 256) ? ndeg[t] : 0;
        if (t < 256) noff[t] = c;
        __syncthreads();
        int inc = c;
        for (int s = 1; s < 256; s <<= 1) {
            int add = (t < 256 && t >= s) ? noff[t - s] : 0;
            __syncthreads();
            if (t < 256) { inc += add; noff[t] = inc; }
            __syncthreads();
        }
        if (t < 256) noff[t] = inc - c;
    }
    __syncthreads();
    int gb = bbase[b];
    int n0 = b << 8;
    if (t < 256 && n0 + t < N) {
        int n = n0 + t;
        meta[n] = make_int2(gb + noff[t], ndeg[t]);
        float dinv = rsqrtf((float)(ndeg[t] + 1));
        const float* xr = x + (size_t)n * IN_C;
        unsigned* xo = xs16h + (size_t)n * 8;
#pragma unroll
        for (int w2 = 0; w2 < 8; ++w2) {
            unsigned lo = f2bf(xr[2 * w2] * dinv);
            unsigned hi = f2bf(xr[2 * w2 + 1] * dinv);
            xo[w2] = lo | (hi << 16);
        }
        xs17h[n] = f2bf(xr[16] * dinv);
    }
    for (int j = 0; j < ne; ++j) {
        int p = mypk[j];
        int l = (p >> 17) & 255;
        csr[gb + noff[l] + myrk[j]] = p & 0x1FFFF;
    }
}

// ---------- layer 1: gather -> fold -> matvec1 -> in-block MFMA mm2 -> bf16 hs2 ----------
__global__ __launch_bounds__(256) void k_gather1(
        const uint4* __restrict__ xs16v, const unsigned short* __restrict__ xs17h,
        const int* __restrict__ csr, const int2* __restrict__ meta,
        const float* __restrict__ W1, const float* __restrict__ b1,
        const uint4* __restrict__ w2frag, unsigned short* __restrict__ hs2u, int N) {
    __shared__ __align__(16) float aggx[16][20];
    __shared__ float dinv_sh[16];
    __shared__ __align__(16) float h1sh[16][68];   // holds dinv*relu(h1), f32
    __shared__ int csr_sh[SCAP];

    int tid = threadIdx.x;
    int n0 = blockIdx.x * 16;
    int nlast = min(n0 + 15, N - 1);
    int2 m0 = meta[n0];
    int2 mlv = meta[nlast];
    int s_lo = m0.x;
    int seglen = mlv.x + mlv.y - s_lo;
    int sg = min(seglen, SCAP);
    for (int i = tid; i < sg; i += 256)
        csr_sh[i] = __builtin_nontemporal_load(&csr[s_lo + i]);
    int ch = tid & 63;
    float w1r[IN_C];
#pragma unroll
    for (int k = 0; k < IN_C; ++k) w1r[k] = W1[k * HID + ch];
    float b1v = b1[ch];
    __syncthreads();

    int ln = tid >> 4, sl = tid & 15;
    int n = n0 + ln;
    f2 acc[8];
#pragma unroll
    for (int j = 0; j < 8; ++j) acc[j] = mkf2(0.f, 0.f);
    float a17 = 0.f;
    if (n < N) {
        int2 m = meta[n];
        int start = m.x, cnt = m.y, end = start + cnt;
        auto body = [&](int s) {
            uint4 v0 = xs16v[(size_t)s * 2];
            uint4 v1 = xs16v[(size_t)s * 2 + 1];
            acc[0] += mkf2(bflo(v0.x), bfhi(v0.x));
            acc[1] += mkf2(bflo(v0.y), bfhi(v0.y));
            acc[2] += mkf2(bflo(v0.z), bfhi(v0.z));
            acc[3] += mkf2(bflo(v0.w), bfhi(v0.w));
            acc[4] += mkf2(bflo(v1.x), bfhi(v1.x));
            acc[5] += mkf2(bflo(v1.y), bfhi(v1.y));
            acc[6] += mkf2(bflo(v1.z), bfhi(v1.z));
            acc[7] += mkf2(bflo(v1.w), bfhi(v1.w));
            a17 += bflo((unsigned)xs17h[s]);
        };
        if (seglen <= SCAP) {
            for (int k = start + sl; k < end; k += 16) body(csr_sh[k - s_lo]);
        } else {
            for (int k = start + sl; k < end; k += 16)
                body(__builtin_nontemporal_load(&csr[k]));
        }
        if (sl == 0) {                                   // self loop
            body(n);
            dinv_sh[ln] = rsqrtf((float)(cnt + 1));
        }
    }
    float a[16];
#pragma unroll
    for (int j = 0; j < 8; ++j) { a[2 * j] = acc[j].x; a[2 * j + 1] = acc[j].y; }
#pragma unroll
    for (int j = 0; j < 8; ++j) {
        float tt = (sl & 8) ? a[j + 8] : a[j];
        float uu = (sl & 8) ? a[j] : a[j + 8];
        a[j] = tt + __shfl_xor(uu, 8);
    }
#pragma unroll
    for (int j = 0; j < 4; ++j) {
        float tt = (sl & 4) ? a[j + 4] : a[j];
        float uu = (sl & 4) ? a[j] : a[j + 4];
        a[j] = tt + __shfl_xor(uu, 4);
    }
#pragma unroll
    for (int j = 0; j < 2; ++j) {
        float tt = (sl & 2) ? a[j + 2] : a[j];
        float uu = (sl & 2) ? a[j] : a[j + 2];
        a[j] = tt + __shfl_xor(uu, 2);
    }
    {
        float tt = (sl & 1) ? a[1] : a[0];
        float uu = (sl & 1) ? a[0] : a[1];
        a[0] = tt + __shfl_xor(uu, 1);
    }
    a17 += __shfl_xor(a17, 1);
    a17 += __shfl_xor(a17, 2);
    a17 += __shfl_xor(a17, 4);
    a17 += __shfl_xor(a17, 8);
    aggx[ln][sl] = a[0];
    if (sl == 0) aggx[ln][16] = a17;
    __syncthreads();
    // matvec1 + bias + relu; h1sh = dinv * relu(...)  (f32)
    int s0 = tid >> 6;
#pragma unroll
    for (int rep = 0; rep < 4; ++rep) {
        int slot = s0 + rep * 4;
        int nn = n0 + slot;
        if (nn < N) {
            const float4* ap = (const float4*)aggx[slot];
            float4 A0 = ap[0], A1 = ap[1], A2 = ap[2], A3 = ap[3];
            float a16 = aggx[slot][16];
            float dot = A0.x * w1r[0]  + A0.y * w1r[1]  + A0.z * w1r[2]  + A0.w * w1r[3]
                      + A1.x * w1r[4]  + A1.y * w1r[5]  + A1.z * w1r[6]  + A1.w * w1r[7]
                      + A2.x * w1r[8]  + A2.y * w1r[9]  + A2.z * w1r[10] + A2.w * w1r[11]
                      + A3.x * w1r[12] + A3.y * w1r[13] + A3.z * w1r[14] + A3.w * w1r[15]
                      + a16  * w1r[16];
            float dv = dinv_sh[slot];
            h1sh[slot][ch] = dv * fmaxf(dv * dot + b1v, 0.f);
        }
    }
    __syncthreads();
    // mm2 via MFMA on this block's 16 nodes: wave wv computes N-tile wv (cols wv*16..+15)
    int wv = tid >> 6, l = tid & 63;
    if (wv < 2) {
        int row = l & 15, kq = l >> 4;
        const float4* hp = (const float4*)&h1sh[row][kq * 8];
        float4 f0v = hp[0], f1v = hp[1];
        const float4* hq = (const float4*)&h1sh[row][32 + kq * 8];
        float4 g0v = hq[0], g1v = hq[1];
        bf16x8 a0, a1;
        a0[0] = (short)f2bf(f0v.x); a0[1] = (short)f2bf(f0v.y);
        a0[2] = (short)f2bf(f0v.z); a0[3] = (short)f2bf(f0v.w);
        a0[4] = (short)f2bf(f1v.x); a0[5] = (short)f2bf(f1v.y);
        a0[6] = (short)f2bf(f1v.z); a0[7] = (short)f2bf(f1v.w);
        a1[0] = (short)f2bf(g0v.x); a1[1] = (short)f2bf(g0v.y);
        a1[2] = (short)f2bf(g0v.z); a1[3] = (short)f2bf(g0v.w);
        a1[4] = (short)f2bf(g1v.x); a1[5] = (short)f2bf(g1v.y);
        a1[6] = (short)f2bf(g1v.z); a1[7] = (short)f2bf(g1v.w);
        bf16x8 bA = *(const bf16x8*)&w2frag[(0 + wv) * 64 + l];   // kt0, nt=wv
        bf16x8 bB = *(const bf16x8*)&w2frag[(2 + wv) * 64 + l];   // kt1, nt=wv
        f32x4 d = {0.f, 0.f, 0.f, 0.f};
        d = __builtin_amdgcn_mfma_f32_16x16x32_bf16(a0, bA, d, 0, 0, 0);
        d = __builtin_amdgcn_mfma_f32_16x16x32_bf16(a1, bB, d, 0, 0, 0);
        int rbase = (l >> 4) * 4;
#pragma unroll
        for (int r = 0; r < 4; ++r) {
            int node = n0 + rbase + r;
            if (node < N)
                hs2u[(size_t)node * 32 + wv * 16 + (l & 15)] = f2bf(d[r]);
        }
    }
}

// ---------- layer 2 gather: csr LDS-staged, 1 lane/edge + pool ----------
__global__ __launch_bounds__(256) void k_gather2(
        const uint4* __restrict__ hs2v, const int* __restrict__ csr,
        const int2* __restrict__ meta, const float* __restrict__ b2,
        const int* __restrict__ batch, float* pool, float* cntg, int N) {
    __shared__ __align__(16) float cont[16][OUTC];
    __shared__ int bsh[16];
    __shared__ int csr_sh[SCAP];
    int tid = threadIdx.x;
    int n0 = blockIdx.x * 16;
    int nlast = min(n0 + 15, N - 1);
    int2 m0 = meta[n0];
    int2 mlv = meta[nlast];
    int s_lo = m0.x;
    int seglen = mlv.x + mlv.y - s_lo;
    int sg = min(seglen, SCAP);
    for (int i = tid; i < sg; i += 256)
        csr_sh[i] = __builtin_nontemporal_load(&csr[s_lo + i]);
    __syncthreads();

    int ln = tid >> 4, sl = tid & 15;
    int n = n0 + ln;
    f2 acc[16];
#pragma unroll
    for (int j = 0; j < 16; ++j) acc[j] = mkf2(0.f, 0.f);
    float dinv = 0.f;
    if (n < N) {
        int2 m = meta[n];
        int start = m.x, cnt = m.y, end = start + cnt;
        dinv = rsqrtf((float)(cnt + 1));
        auto body = [&](int s) {
            const uint4* rp = hs2v + (size_t)s * 4;
            uint4 v0 = rp[0], v1 = rp[1], v2 = rp[2], v3 = rp[3];
            acc[0]  += mkf2(bflo(v0.x), bfhi(v0.x));
            acc[1]  += mkf2(bflo(v0.y), bfhi(v0.y));
            acc[2]  += mkf2(bflo(v0.z), bfhi(v0.z));
            acc[3]  += mkf2(bflo(v0.w), bfhi(v0.w));
            acc[4]  += mkf2(bflo(v1.x), bfhi(v1.x));
            acc[5]  += mkf2(bflo(v1.y), bfhi(v1.y));
            acc[6]  += mkf2(bflo(v1.z), bfhi(v1.z));
            acc[7]  += mkf2(bflo(v1.w), bfhi(v1.w));
            acc[8]  += mkf2(bflo(v2.x), bfhi(v2.x));
            acc[9]  += mkf2(bflo(v2.y), bfhi(v2.y));
            acc[10] += mkf2(bflo(v2.z), bfhi(v2.z));
            acc[11] += mkf2(bflo(v2.w), bfhi(v2.w));
            acc[12] += mkf2(bflo(v3.x), bfhi(v3.x));
            acc[13] += mkf2(bflo(v3.y), bfhi(v3.y));
            acc[14] += mkf2(bflo(v3.z), bfhi(v3.z));
            acc[15] += mkf2(bflo(v3.w), bfhi(v3.w));
        };
        if (seglen <= SCAP) {
            for (int k = start + sl; k < end; k += 16) body(csr_sh[k - s_lo]);
        } else {
            for (int k = start + sl; k < end; k += 16)
                body(__builtin_nontemporal_load(&csr[k]));
        }
        if (sl == 0) body(n);                            // self loop
    }
    float a[32];
#pragma unroll
    for (int j = 0; j < 16; ++j) { a[2 * j] = acc[j].x; a[2 * j + 1] = acc[j].y; }
    // halving fold: lane sl ends with channels (2sl, 2sl+1) in a[0], a[1]
#pragma unroll
    for (int j = 0; j < 16; ++j) {
        float tt = (sl & 8) ? a[j + 16] : a[j];
        float uu = (sl & 8) ? a[j] : a[j + 16];
        a[j] = tt + __shfl_xor(uu, 8);
    }
#pragma unroll
    for (int j = 0; j < 8; ++j) {
        float tt = (sl & 4) ? a[j + 8] : a[j];
        float uu = (sl & 4) ? a[j] : a[j + 8];
        a[j] = tt + __shfl_xor(uu, 4);
    }
#pragma unroll
    for (int j = 0; j < 4; ++j) {
        float tt = (sl & 2) ? a[j + 4] : a[j];
        float uu = (sl & 2) ? a[j] : a[j + 4];
        a[j] = tt + __shfl_xor(uu, 2);
    }
#pragma unroll
    for (int j = 0; j < 2; ++j) {
        float tt = (sl & 1) ? a[j + 2] : a[j];
        float uu = (sl & 1) ? a[j] : a[j + 2];
        a[j] = tt + __shfl_xor(uu, 1);
    }
    if (n < N) {
        float c0 = dinv * a[0] + b2[2 * sl];
        float c1 = dinv * a[1] + b2[2 * sl + 1];
        *(float2*)&cont[ln][2 * sl] = make_float2(c0, c1);
        if (sl == 0) bsh[ln] = batch[n];
    } else {
        *(float2*)&cont[ln][2 * sl] = make_float2(0.f, 0.f);
        if (sl == 0) bsh[ln] = -1;
    }
    __syncthreads();
    if (tid < OUTC) {
        int c = tid;
        float run = 0.f; int cur = -1;
        for (int j = 0; j < 16; ++j) {
            int bj = bsh[j];
            if (bj < 0) continue;
            if (bj == cur) run += cont[j][c];
            else {
                if (cur >= 0) atomicAdd(&pool[(size_t)cur * OUTC + c], run);
                cur = bj; run = cont[j][c];
            }
        }
        if (cur >= 0) atomicAdd(&pool[(size_t)cur * OUTC + c], run);
        if (c == 0) {
            float crun = 0.f; cur = -1;
            for (int j = 0; j < 16; ++j) {
                int bj = bsh[j];
                if (bj < 0) continue;
                if (bj == cur) crun += 1.f;
                else {
                    if (cur >= 0) atomicAdd(&cntg[cur], crun);
                    cur = bj; crun = 1.f;
                }
            }
            if (cur >= 0) atomicAdd(&cntg[cur], crun);
        }
    }
}

// ---------- final: pooled mean -> fc1(relu) -> fc2 ----------
__global__ void k_final(const float* __restrict__ pool, const float* __restrict__ cntg,
                        const float* __restrict__ Wf1, const float* __restrict__ bf1,
                        const float* __restrict__ Wf2, const float* __restrict__ bf2,
                        float* out, int G) {
    __shared__ float p[OUTC], t[OUTC];
    int g = blockIdx.x;
    int c = threadIdx.x;
    float csafe = fmaxf(cntg[g], 1.0f);
    p[c] = pool[g * OUTC + c] / csafe;
    __syncthreads();
    float acc = bf1[c];
#pragma unroll
    for (int k = 0; k < OUTC; ++k) acc += p[k] * Wf1[k * OUTC + c];
    t[c] = fmaxf(acc, 0.f);
    __syncthreads();
    float acc2 = bf2[c];
#pragma unroll
    for (int k = 0; k < OUTC; ++k) acc2 += t[k] * Wf2[k * OUTC + c];
    out[g * OUTC + c] = acc2;
}

extern "C" void kernel_launch(void* const* d_in, const int* in_sizes, int n_in,
                              void* d_out, int out_size, void* d_ws, size_t ws_size,
                              hipStream_t stream) {
    const float* x    = (const float*)d_in[0];
    const int*   ei   = (const int*)  d_in[1];
    const int*   batch= (const int*)  d_in[2];
    const float* W1   = (const float*)d_in[3];
    const float* b1   = (const float*)d_in[4];
    const float* W2   = (const float*)d_in[5];
    const float* b2   = (const float*)d_in[6];
    const float* Wf1  = (const float*)d_in[7];
    const float* bf1  = (const float*)d_in[8];
    const float* Wf2  = (const float*)d_in[9];
    const float* bf2  = (const float*)d_in[10];

    const int N = in_sizes[0] / IN_C;
    const int E = in_sizes[1] / 2;
    const int G = out_size / OUTC;
    const int* src = ei;
    const int* dst = ei + E;

    const int nblkA = (E + CH - 1) / CH;
    const int NB    = (N + 255) >> 8;

    // ---- workspace layout ----
    char* w = (char*)d_ws;
    int*   csr      = (int*)w;   w += (size_t)E * sizeof(int);
    int2*  meta     = (int2*)w;  w += (size_t)N * sizeof(int2);
    unsigned* xs16h = (unsigned*)w; w += (size_t)N * 8 * sizeof(unsigned);
    unsigned* hs2   = (unsigned*)w; w += (size_t)N * 16 * sizeof(unsigned);
    unsigned short* xs17h = (unsigned short*)w; w += (size_t)N * sizeof(unsigned short);
    w = (char*)(((size_t)w + 15) & ~(size_t)15);
    float* pool     = (float*)w; w += (size_t)G * OUTC * sizeof(float);
    float* cntg     = (float*)w; w += (size_t)G * sizeof(float);
    w = (char*)(((size_t)w + 15) & ~(size_t)15);
    int*   outbuf   = (int*)w;   w += (size_t)E * sizeof(int);
    int*   cntmat   = (int*)w;   w += (size_t)nblkA * NBP * sizeof(int);
    int*   offmat   = (int*)w;   w += (size_t)nblkA * NBP * sizeof(int);
    int*   bbase    = (int*)w;   w += NBP * sizeof(int);
    int*   part     = (int*)w;   w += BS_BLKS * NBP * sizeof(int);
    w = (char*)(((size_t)w + 15) & ~(size_t)15);
    uint4* w2frag   = (uint4*)w; w += 4 * 64 * sizeof(uint4);

    const int poolN = G * OUTC + G;   // pool + cntg are contiguous floats

    // CSR build (counting sort) + fused x prep + W2 fragment pack + pool zero
    k_binA<<<nblkA, TA, 0, stream>>>(src, dst, E, outbuf, cntmat, offmat);
    k_bsum1<<<BS_BLKS, NBP, 0, stream>>>(cntmat, nblkA, part, pool, poolN);
    k_bsum2<<<1, NBP, 0, stream>>>(part, bbase, W2, w2frag);
    k_binB<<<NB, TA, 0, stream>>>(outbuf, cntmat, offmat, bbase, nblkA, N,
                                  csr, meta, x, xs16h, xs17h);

    // layer 1: gather + matvec1 + in-block MFMA mm2 -> bf16 hs2 (natural ch order)
    dim3 blk(256);
    k_gather1<<<(N + 15) / 16, blk, 0, stream>>>((const uint4*)xs16h, xs17h, csr, meta,
                                                 W1, b1, w2frag,
                                                 (unsigned short*)hs2, N);

    // layer 2 gather + pool
    k_gather2<<<(N + 15) / 16, blk, 0, stream>>>((const uint4*)hs2, csr, meta,
                                                 b2, batch, pool, cntg, N);

    // readout
    k_final<<<G, OUTC, 0, stream>>>(pool, cntg, Wf1, bf1, Wf2, bf2, (float*)d_out, G);
}

// Round 15
// 122.105 us; speedup vs baseline: 2.1783x; 1.0265x over previous
//
#include <hip/hip_runtime.h>

#define IN_C 17
#define HID  64
#define OUTC 32

#define CH   8192      // edges per pass-A block
#define TA   512       // pass-A threads
#define NBP  512       // padded bucket count (bucket = dst>>8; N<=131072)
#define BCAP 5632      // pass-B stage capacity
#define SCAP 1024      // per-block CSR stage capacity (gathers)
#define BS_BLKS 8

typedef __attribute__((ext_vector_type(2))) float f2;
typedef __attribute__((ext_vector_type(8))) short bf16x8;
typedef __attribute__((ext_vector_type(4))) float f32x4;
__device__ __forceinline__ f2 mkf2(float x, float y) { f2 r; r.x = x; r.y = y; return r; }

__device__ __forceinline__ unsigned short f2bf(float f) {
    unsigned u = __float_as_uint(f);
    u += 0x7fffu + ((u >> 16) & 1u);      // round-nearest-even
    return (unsigned short)(u >> 16);
}
__device__ __forceinline__ float bflo(unsigned u) { return __uint_as_float(u << 16); }
__device__ __forceinline__ float bfhi(unsigned u) { return __uint_as_float(u & 0xffff0000u); }

// ================= pass A: bin edges by dst>>8, coalesced writes =================
__global__ __launch_bounds__(TA) void k_binA(const int* __restrict__ src,
        const int* __restrict__ dst, int E,
        int* __restrict__ outbuf, int* __restrict__ cntmat, int* __restrict__ offmat) {
    __shared__ int cnt[NBP];
    __shared__ int off[NBP];
    __shared__ int stage[CH];
    int t = threadIdx.x;
    long base = (long)blockIdx.x * CH;
    int nE = (int)(E - base); if (nE > CH) nE = CH;
    cnt[t] = 0;
    __syncthreads();
    int bk[16], pk[16], rk[16];
#pragma unroll
    for (int j = 0; j < 16; ++j) {
        int idx = t + j * TA;
        if (idx < nE) {
            long e = base + idx;
            int d = __builtin_nontemporal_load(&dst[e]);
            int s = __builtin_nontemporal_load(&src[e]);
            int b = d >> 8;
            bk[j] = b;
            pk[j] = s | ((d & 255) << 17);
            rk[j] = atomicAdd(&cnt[b], 1);
        } else bk[j] = -1;
    }
    __syncthreads();
    int c = cnt[t];
    off[t] = c;
    __syncthreads();
    int inc = c;
    for (int s = 1; s < NBP; s <<= 1) {
        int add = (t >= s) ? off[t - s] : 0;
        __syncthreads();
        inc += add; off[t] = inc;
        __syncthreads();
    }
    int excl = inc - c;
    __syncthreads();
    off[t] = excl;
    __syncthreads();
#pragma unroll
    for (int j = 0; j < 16; ++j)
        if (bk[j] >= 0) stage[off[bk[j]] + rk[j]] = pk[j];
    __syncthreads();
    for (int i = t; i < nE; i += TA) outbuf[base + i] = stage[i];
    cntmat[blockIdx.x * NBP + t] = c;
    offmat[blockIdx.x * NBP + t] = excl;
}

// ============ bucket totals (parallel partial) + pool zero-init ============
__global__ __launch_bounds__(NBP) void k_bsum1(const int* __restrict__ cntmat,
        int nblkA, int* __restrict__ part, float* __restrict__ pool, int poolN) {
    int t = threadIdx.x, b = blockIdx.x;
    int per = (nblkA + BS_BLKS - 1) / BS_BLKS;
    int i0 = b * per, i1 = min(i0 + per, nblkA);
    int s = 0;
    for (int i = i0; i < i1; ++i) s += cntmat[i * NBP + t];
    part[b * NBP + t] = s;
    // zero the pool+cntg region (replaces pathological hipMemsetAsync fill)
    for (int i = b * NBP + t; i < poolN; i += BS_BLKS * NBP) pool[i] = 0.f;
}

__global__ __launch_bounds__(NBP) void k_bsum2(const int* __restrict__ part,
        int* __restrict__ bbase, const float* __restrict__ W2,
        uint4* __restrict__ w2frag) {
    __shared__ int sh[NBP];
    int t = threadIdx.x;
    int s = 0;
#pragma unroll
    for (int i = 0; i < BS_BLKS; ++i) s += part[i * NBP + t];
    sh[t] = s;
    __syncthreads();
    int inc = s;
    for (int st = 1; st < NBP; st <<= 1) {
        int add = (t >= st) ? sh[t - st] : 0;
        __syncthreads();
        inc += add; sh[t] = inc;
        __syncthreads();
    }
    bbase[t] = inc - s;
    // pack W2 into MFMA B-fragment layout: frag f = kt*2+nt; lane l holds
    // B[k = kt*32 + (l>>4)*8 + j][c = nt*16 + (l&15)], j=0..7
    if (t < 256) {
        int f = t >> 6, l = t & 63;
        int kt = f >> 1, nt = f & 1;
        int kbase = kt * 32 + (l >> 4) * 8;
        int c = nt * 16 + (l & 15);
        unsigned short v[8];
#pragma unroll
        for (int j = 0; j < 8; ++j) v[j] = f2bf(W2[(kbase + j) * OUTC + c]);
        uint4 o;
        o.x = (unsigned)v[0] | ((unsigned)v[1] << 16);
        o.y = (unsigned)v[2] | ((unsigned)v[3] << 16);
        o.z = (unsigned)v[4] | ((unsigned)v[5] << 16);
        o.w = (unsigned)v[6] | ((unsigned)v[7] << 16);
        w2frag[f * 64 + l] = o;
    }
}

// === pass B: per bucket, gather runs, emit CSR + meta(start,deg) + bf16 xs (fused prep) ===
__global__ __launch_bounds__(TA) void k_binB(const int* __restrict__ outbuf,
        const int* __restrict__ cntmat, const int* __restrict__ offmat,
        const int* __restrict__ bbase, int nblkA, int N,
        int* __restrict__ csr, int2* __restrict__ meta,
        const float* __restrict__ x, unsigned* __restrict__ xs16h,
        unsigned short* __restrict__ xs17h) {
    __shared__ int segc[256], sego[256], segs[256];
    __shared__ int ndeg[256], noff[256];
    __shared__ int stage[BCAP];
    int t = threadIdx.x, b = blockIdx.x;
    if (t < 256) {
        int cc = 0, ss = 0;
        if (t < nblkA) { cc = cntmat[t * NBP + b]; ss = offmat[t * NBP + b]; }
        segc[t] = cc; segs[t] = ss; sego[t] = cc;
        ndeg[t] = 0;
    }
    __syncthreads();
    {
        int c = (t < 256) ? sego[t] : 0;
        int inc = c;
        for (int s = 1; s < 256; s <<= 1) {
            int add = (t < 256 && t >= s) ? sego[t - s] : 0;
            __syncthreads();
            if (t < 256) { inc += add; sego[t] = inc; }
            __syncthreads();
        }
        if (t < 256) sego[t] = inc - c;
    }
    __syncthreads();
    int wave = t >> 6, lane = t & 63;
    for (int i = wave; i < nblkA; i += TA / 64) {
        int c = segc[i], so = sego[i];
        long gs = (long)i * CH + segs[i];
        for (int l = lane; l < c; l += 64) {
            int p = so + l;
            if (p < BCAP) stage[p] = __builtin_nontemporal_load(&outbuf[gs + l]);
        }
    }
    __syncthreads();
    int T = sego[255] + segc[255];
    if (T > BCAP) T = BCAP;
    int mypk[11], myrk[11], ne = 0;
    for (int k = t; k < T; k += TA) {
        int p = stage[k];
        int l = (p >> 17) & 255;
        myrk[ne] = atomicAdd(&ndeg[l], 1);
        mypk[ne] = p;
        ne++;
    }
    __syncthreads();
    {
        int c = (t < 256) ? ndeg[t] : 0;
        if (t < 256) noff[t] = c;
        __syncthreads();
        int inc = c;
        for (int s = 1; s < 256; s <<= 1) {
            int add = (t < 256 && t >= s) ? noff[t - s] : 0;
            __syncthreads();
            if (t < 256) { inc += add; noff[t] = inc; }
            __syncthreads();
        }
        if (t < 256) noff[t] = inc - c;
    }
    __syncthreads();
    int gb = bbase[b];
    int n0 = b << 8;
    if (t < 256 && n0 + t < N) {
        int n = n0 + t;
        meta[n] = make_int2(gb + noff[t], ndeg[t]);
        float dinv = rsqrtf((float)(ndeg[t] + 1));
        const float* xr = x + (size_t)n * IN_C;
        unsigned* xo = xs16h + (size_t)n * 8;
#pragma unroll
        for (int w2 = 0; w2 < 8; ++w2) {
            unsigned lo = f2bf(xr[2 * w2] * dinv);
            unsigned hi = f2bf(xr[2 * w2 + 1] * dinv);
            xo[w2] = lo | (hi << 16);
        }
        xs17h[n] = f2bf(xr[16] * dinv);
    }
    for (int j = 0; j < ne; ++j) {
        int p = mypk[j];
        int l = (p >> 17) & 255;
        csr[gb + noff[l] + myrk[j]] = p & 0x1FFFF;
    }
}

// ---------- layer 1: gather -> fold -> matvec1 -> in-block MFMA mm2 -> fp8 hs2 ----------
__global__ __launch_bounds__(256) void k_gather1(
        const uint4* __restrict__ xs16v, const unsigned short* __restrict__ xs17h,
        const int* __restrict__ csr, const int2* __restrict__ meta,
        const float* __restrict__ W1, const float* __restrict__ b1,
        const uint4* __restrict__ w2frag, unsigned char* __restrict__ hs2b, int N) {
    __shared__ __align__(16) float aggx[16][20];
    __shared__ float dinv_sh[16];
    __shared__ __align__(16) float h1sh[16][68];   // holds dinv*relu(h1), f32
    __shared__ int csr_sh[SCAP];

    int tid = threadIdx.x;
    int n0 = blockIdx.x * 16;
    int nlast = min(n0 + 15, N - 1);
    int2 m0 = meta[n0];
    int2 mlv = meta[nlast];
    int s_lo = m0.x;
    int seglen = mlv.x + mlv.y - s_lo;
    int sg = min(seglen, SCAP);
    for (int i = tid; i < sg; i += 256)
        csr_sh[i] = __builtin_nontemporal_load(&csr[s_lo + i]);
    int ch = tid & 63;
    float w1r[IN_C];
#pragma unroll
    for (int k = 0; k < IN_C; ++k) w1r[k] = W1[k * HID + ch];
    float b1v = b1[ch];
    __syncthreads();

    int ln = tid >> 4, sl = tid & 15;
    int n = n0 + ln;
    f2 acc[8];
#pragma unroll
    for (int j = 0; j < 8; ++j) acc[j] = mkf2(0.f, 0.f);
    float a17 = 0.f;
    if (n < N) {
        int2 m = meta[n];
        int start = m.x, cnt = m.y, end = start + cnt;
        auto body = [&](int s) {
            uint4 v0 = xs16v[(size_t)s * 2];
            uint4 v1 = xs16v[(size_t)s * 2 + 1];
            acc[0] += mkf2(bflo(v0.x), bfhi(v0.x));
            acc[1] += mkf2(bflo(v0.y), bfhi(v0.y));
            acc[2] += mkf2(bflo(v0.z), bfhi(v0.z));
            acc[3] += mkf2(bflo(v0.w), bfhi(v0.w));
            acc[4] += mkf2(bflo(v1.x), bfhi(v1.x));
            acc[5] += mkf2(bflo(v1.y), bfhi(v1.y));
            acc[6] += mkf2(bflo(v1.z), bfhi(v1.z));
            acc[7] += mkf2(bflo(v1.w), bfhi(v1.w));
            a17 += bflo((unsigned)xs17h[s]);
        };
        if (seglen <= SCAP) {
            for (int k = start + sl; k < end; k += 16) body(csr_sh[k - s_lo]);
        } else {
            for (int k = start + sl; k < end; k += 16)
                body(__builtin_nontemporal_load(&csr[k]));
        }
        if (sl == 0) {                                   // self loop
            body(n);
            dinv_sh[ln] = rsqrtf((float)(cnt + 1));
        }
    }
    float a[16];
#pragma unroll
    for (int j = 0; j < 8; ++j) { a[2 * j] = acc[j].x; a[2 * j + 1] = acc[j].y; }
#pragma unroll
    for (int j = 0; j < 8; ++j) {
        float tt = (sl & 8) ? a[j + 8] : a[j];
        float uu = (sl & 8) ? a[j] : a[j + 8];
        a[j] = tt + __shfl_xor(uu, 8);
    }
#pragma unroll
    for (int j = 0; j < 4; ++j) {
        float tt = (sl & 4) ? a[j + 4] : a[j];
        float uu = (sl & 4) ? a[j] : a[j + 4];
        a[j] = tt + __shfl_xor(uu, 4);
    }
#pragma unroll
    for (int j = 0; j < 2; ++j) {
        float tt = (sl & 2) ? a[j + 2] : a[j];
        float uu = (sl & 2) ? a[j] : a[j + 2];
        a[j] = tt + __shfl_xor(uu, 2);
    }
    {
        float tt = (sl & 1) ? a[1] : a[0];
        float uu = (sl & 1) ? a[0] : a[1];
        a[0] = tt + __shfl_xor(uu, 1);
    }
    a17 += __shfl_xor(a17, 1);
    a17 += __shfl_xor(a17, 2);
    a17 += __shfl_xor(a17, 4);
    a17 += __shfl_xor(a17, 8);
    aggx[ln][sl] = a[0];
    if (sl == 0) aggx[ln][16] = a17;
    __syncthreads();
    // matvec1 + bias + relu; h1sh = dinv * relu(...)  (f32)
    int s0 = tid >> 6;
#pragma unroll
    for (int rep = 0; rep < 4; ++rep) {
        int slot = s0 + rep * 4;
        int nn = n0 + slot;
        if (nn < N) {
            const float4* ap = (const float4*)aggx[slot];
            float4 A0 = ap[0], A1 = ap[1], A2 = ap[2], A3 = ap[3];
            float a16 = aggx[slot][16];
            float dot = A0.x * w1r[0]  + A0.y * w1r[1]  + A0.z * w1r[2]  + A0.w * w1r[3]
                      + A1.x * w1r[4]  + A1.y * w1r[5]  + A1.z * w1r[6]  + A1.w * w1r[7]
                      + A2.x * w1r[8]  + A2.y * w1r[9]  + A2.z * w1r[10] + A2.w * w1r[11]
                      + A3.x * w1r[12] + A3.y * w1r[13] + A3.z * w1r[14] + A3.w * w1r[15]
                      + a16  * w1r[16];
            float dv = dinv_sh[slot];
            h1sh[slot][ch] = dv * fmaxf(dv * dot + b1v, 0.f);
        }
    }
    __syncthreads();
    // mm2 via MFMA on this block's 16 nodes: wave wv computes N-tile wv (cols wv*16..+15)
    int wv = tid >> 6, l = tid & 63;
    if (wv < 2) {
        int row = l & 15, kq = l >> 4;
        const float4* hp = (const float4*)&h1sh[row][kq * 8];
        float4 f0v = hp[0], f1v = hp[1];
        const float4* hq = (const float4*)&h1sh[row][32 + kq * 8];
        float4 g0v = hq[0], g1v = hq[1];
        bf16x8 a0, a1;
        a0[0] = (short)f2bf(f0v.x); a0[1] = (short)f2bf(f0v.y);
        a0[2] = (short)f2bf(f0v.z); a0[3] = (short)f2bf(f0v.w);
        a0[4] = (short)f2bf(f1v.x); a0[5] = (short)f2bf(f1v.y);
        a0[6] = (short)f2bf(f1v.z); a0[7] = (short)f2bf(f1v.w);
        a1[0] = (short)f2bf(g0v.x); a1[1] = (short)f2bf(g0v.y);
        a1[2] = (short)f2bf(g0v.z); a1[3] = (short)f2bf(g0v.w);
        a1[4] = (short)f2bf(g1v.x); a1[5] = (short)f2bf(g1v.y);
        a1[6] = (short)f2bf(g1v.z); a1[7] = (short)f2bf(g1v.w);
        bf16x8 bA = *(const bf16x8*)&w2frag[(0 + wv) * 64 + l];   // kt0, nt=wv
        bf16x8 bB = *(const bf16x8*)&w2frag[(2 + wv) * 64 + l];   // kt1, nt=wv
        f32x4 d = {0.f, 0.f, 0.f, 0.f};
        d = __builtin_amdgcn_mfma_f32_16x16x32_bf16(a0, bA, d, 0, 0, 0);
        d = __builtin_amdgcn_mfma_f32_16x16x32_bf16(a1, bB, d, 0, 0, 0);
        int rbase = (l >> 4) * 4;
#pragma unroll
        for (int r = 0; r < 4; ++r) {
            int node = n0 + rbase + r;
            if (node < N) {
                unsigned pk = (unsigned)__builtin_amdgcn_cvt_pk_fp8_f32(d[r], 0.f, 0, false);
                hs2b[(size_t)node * 32 + wv * 16 + (l & 15)] = (unsigned char)(pk & 0xFFu);
            }
        }
    }
}

// ---------- layer 2 gather: csr LDS-staged, 1 lane/edge, fp8 rows (HW cvt) + pool ----------
__global__ __launch_bounds__(256) void k_gather2(
        const uint4* __restrict__ hs2v, const int* __restrict__ csr,
        const int2* __restrict__ meta, const float* __restrict__ b2,
        const int* __restrict__ batch, float* pool, float* cntg, int N) {
    __shared__ __align__(16) float cont[16][OUTC];
    __shared__ int bsh[16];
    __shared__ int csr_sh[SCAP];
    int tid = threadIdx.x;
    int n0 = blockIdx.x * 16;
    int nlast = min(n0 + 15, N - 1);
    int2 m0 = meta[n0];
    int2 mlv = meta[nlast];
    int s_lo = m0.x;
    int seglen = mlv.x + mlv.y - s_lo;
    int sg = min(seglen, SCAP);
    for (int i = tid; i < sg; i += 256)
        csr_sh[i] = __builtin_nontemporal_load(&csr[s_lo + i]);
    __syncthreads();

    int ln = tid >> 4, sl = tid & 15;
    int n = n0 + ln;
    f2 acc[16];
#pragma unroll
    for (int j = 0; j < 16; ++j) acc[j] = mkf2(0.f, 0.f);
    float dinv = 0.f;
    if (n < N) {
        int2 m = meta[n];
        int start = m.x, cnt = m.y, end = start + cnt;
        dinv = rsqrtf((float)(cnt + 1));
        auto body = [&](int s) {
            const uint4* rp = hs2v + (size_t)s * 2;
            uint4 v0 = rp[0], v1 = rp[1];
            f2 t;
            t = __builtin_amdgcn_cvt_pk_f32_fp8((int)v0.x, false); acc[0]  += t;
            t = __builtin_amdgcn_cvt_pk_f32_fp8((int)v0.x, true);  acc[1]  += t;
            t = __builtin_amdgcn_cvt_pk_f32_fp8((int)v0.y, false); acc[2]  += t;
            t = __builtin_amdgcn_cvt_pk_f32_fp8((int)v0.y, true);  acc[3]  += t;
            t = __builtin_amdgcn_cvt_pk_f32_fp8((int)v0.z, false); acc[4]  += t;
            t = __builtin_amdgcn_cvt_pk_f32_fp8((int)v0.z, true);  acc[5]  += t;
            t = __builtin_amdgcn_cvt_pk_f32_fp8((int)v0.w, false); acc[6]  += t;
            t = __builtin_amdgcn_cvt_pk_f32_fp8((int)v0.w, true);  acc[7]  += t;
            t = __builtin_amdgcn_cvt_pk_f32_fp8((int)v1.x, false); acc[8]  += t;
            t = __builtin_amdgcn_cvt_pk_f32_fp8((int)v1.x, true);  acc[9]  += t;
            t = __builtin_amdgcn_cvt_pk_f32_fp8((int)v1.y, false); acc[10] += t;
            t = __builtin_amdgcn_cvt_pk_f32_fp8((int)v1.y, true);  acc[11] += t;
            t = __builtin_amdgcn_cvt_pk_f32_fp8((int)v1.z, false); acc[12] += t;
            t = __builtin_amdgcn_cvt_pk_f32_fp8((int)v1.z, true);  acc[13] += t;
            t = __builtin_amdgcn_cvt_pk_f32_fp8((int)v1.w, false); acc[14] += t;
            t = __builtin_amdgcn_cvt_pk_f32_fp8((int)v1.w, true);  acc[15] += t;
        };
        if (seglen <= SCAP) {
            for (int k = start + sl; k < end; k += 16) body(csr_sh[k - s_lo]);
        } else {
            for (int k = start + sl; k < end; k += 16)
                body(__builtin_nontemporal_load(&csr[k]));
        }
        if (sl == 0) body(n);                            // self loop
    }
    float a[32];
#pragma unroll
    for (int j = 0; j < 16; ++j) { a[2 * j] = acc[j].x; a[2 * j + 1] = acc[j].y; }
    // halving fold: lane sl ends with channels (2sl, 2sl+1) in a[0], a[1]
#pragma unroll
    for (int j = 0; j < 16; ++j) {
        float tt = (sl & 8) ? a[j + 16] : a[j];
        float uu = (sl & 8) ? a[j] : a[j + 16];
        a[j] = tt + __shfl_xor(uu, 8);
    }
#pragma unroll
    for (int j = 0; j < 8; ++j) {
        float tt = (sl & 4) ? a[j + 8] : a[j];
        float uu = (sl & 4) ? a[j] : a[j + 8];
        a[j] = tt + __shfl_xor(uu, 4);
    }
#pragma unroll
    for (int j = 0; j < 4; ++j) {
        float tt = (sl & 2) ? a[j + 4] : a[j];
        float uu = (sl & 2) ? a[j] : a[j + 4];
        a[j] = tt + __shfl_xor(uu, 2);
    }
#pragma unroll
    for (int j = 0; j < 2; ++j) {
        float tt = (sl & 1) ? a[j + 2] : a[j];
        float uu = (sl & 1) ? a[j] : a[j + 2];
        a[j] = tt + __shfl_xor(uu, 1);
    }
    if (n < N) {
        float c0 = dinv * a[0] + b2[2 * sl];
        float c1 = dinv * a[1] + b2[2 * sl + 1];
        *(float2*)&cont[ln][2 * sl] = make_float2(c0, c1);
        if (sl == 0) bsh[ln] = batch[n];
    } else {
        *(float2*)&cont[ln][2 * sl] = make_float2(0.f, 0.f);
        if (sl == 0) bsh[ln] = -1;
    }
    __syncthreads();
    if (tid < OUTC) {
        int c = tid;
        float run = 0.f; int cur = -1;
        for (int j = 0; j < 16; ++j) {
            int bj = bsh[j];
            if (bj < 0) continue;
            if (bj == cur) run += cont[j][c];
            else {
                if (cur >= 0) atomicAdd(&pool[(size_t)cur * OUTC + c], run);
                cur = bj; run = cont[j][c];
            }
        }
        if (cur >= 0) atomicAdd(&pool[(size_t)cur * OUTC + c], run);
        if (c == 0) {
            float crun = 0.f; cur = -1;
            for (int j = 0; j < 16; ++j) {
                int bj = bsh[j];
                if (bj < 0) continue;
                if (bj == cur) crun += 1.f;
                else {
                    if (cur >= 0) atomicAdd(&cntg[cur], crun);
                    cur = bj; crun = 1.f;
                }
            }
            if (cur >= 0) atomicAdd(&cntg[cur], crun);
        }
    }
}

// ---------- final: pooled mean -> fc1(relu) -> fc2 ----------
__global__ void k_final(const float* __restrict__ pool, const float* __restrict__ cntg,
                        const float* __restrict__ Wf1, const float* __restrict__ bf1,
                        const float* __restrict__ Wf2, const float* __restrict__ bf2,
                        float* out, int G) {
    __shared__ float p[OUTC], t[OUTC];
    int g = blockIdx.x;
    int c = threadIdx.x;
    float csafe = fmaxf(cntg[g], 1.0f);
    p[c] = pool[g * OUTC + c] / csafe;
    __syncthreads();
    float acc = bf1[c];
#pragma unroll
    for (int k = 0; k < OUTC; ++k) acc += p[k] * Wf1[k * OUTC + c];
    t[c] = fmaxf(acc, 0.f);
    __syncthreads();
    float acc2 = bf2[c];
#pragma unroll
    for (int k = 0; k < OUTC; ++k) acc2 += t[k] * Wf2[k * OUTC + c];
    out[g * OUTC + c] = acc2;
}

extern "C" void kernel_launch(void* const* d_in, const int* in_sizes, int n_in,
                              void* d_out, int out_size, void* d_ws, size_t ws_size,
                              hipStream_t stream) {
    const float* x    = (const float*)d_in[0];
    const int*   ei   = (const int*)  d_in[1];
    const int*   batch= (const int*)  d_in[2];
    const float* W1   = (const float*)d_in[3];
    const float* b1   = (const float*)d_in[4];
    const float* W2   = (const float*)d_in[5];
    const float* b2   = (const float*)d_in[6];
    const float* Wf1  = (const float*)d_in[7];
    const float* bf1  = (const float*)d_in[8];
    const float* Wf2  = (const float*)d_in[9];
    const float* bf2  = (const float*)d_in[10];

    const int N = in_sizes[0] / IN_C;
    const int E = in_sizes[1] / 2;
    const int G = out_size / OUTC;
    const int* src = ei;
    const int* dst = ei + E;

    const int nblkA = (E + CH - 1) / CH;
    const int NB    = (N + 255) >> 8;

    // ---- workspace layout ----
    char* w = (char*)d_ws;
    int*   csr      = (int*)w;   w += (size_t)E * sizeof(int);
    int2*  meta     = (int2*)w;  w += (size_t)N * sizeof(int2);
    unsigned* xs16h = (unsigned*)w; w += (size_t)N * 8 * sizeof(unsigned);
    unsigned char* hs2 = (unsigned char*)w; w += (size_t)N * 32;   // fp8 rows, 32B
    unsigned short* xs17h = (unsigned short*)w; w += (size_t)N * sizeof(unsigned short);
    w = (char*)(((size_t)w + 15) & ~(size_t)15);
    float* pool     = (float*)w; w += (size_t)G * OUTC * sizeof(float);
    float* cntg     = (float*)w; w += (size_t)G * sizeof(float);
    w = (char*)(((size_t)w + 15) & ~(size_t)15);
    int*   outbuf   = (int*)w;   w += (size_t)E * sizeof(int);
    int*   cntmat   = (int*)w;   w += (size_t)nblkA * NBP * sizeof(int);
    int*   offmat   = (int*)w;   w += (size_t)nblkA * NBP * sizeof(int);
    int*   bbase    = (int*)w;   w += NBP * sizeof(int);
    int*   part     = (int*)w;   w += BS_BLKS * NBP * sizeof(int);
    w = (char*)(((size_t)w + 15) & ~(size_t)15);
    uint4* w2frag   = (uint4*)w; w += 4 * 64 * sizeof(uint4);

    const int poolN = G * OUTC + G;   // pool + cntg are contiguous floats

    // CSR build (counting sort) + fused x prep + W2 fragment pack + pool zero
    k_binA<<<nblkA, TA, 0, stream>>>(src, dst, E, outbuf, cntmat, offmat);
    k_bsum1<<<BS_BLKS, NBP, 0, stream>>>(cntmat, nblkA, part, pool, poolN);
    k_bsum2<<<1, NBP, 0, stream>>>(part, bbase, W2, w2frag);
    k_binB<<<NB, TA, 0, stream>>>(outbuf, cntmat, offmat, bbase, nblkA, N,
                                  csr, meta, x, xs16h, xs17h);

    // layer 1: gather + matvec1 + in-block MFMA mm2 -> fp8 hs2 (natural ch order)
    dim3 blk(256);
    k_gather1<<<(N + 15) / 16, blk, 0, stream>>>((const uint4*)xs16h, xs17h, csr, meta,
                                                 W1, b1, w2frag, hs2, N);

    // layer 2 gather + pool (fp8 rows, fully L2-resident)
    k_gather2<<<(N + 15) / 16, blk, 0, stream>>>((const uint4*)hs2, csr, meta,
                                                 b2, batch, pool, cntg, N);

    // readout
    k_final<<<G, OUTC, 0, stream>>>(pool, cntg, Wf1, bf1, Wf2, bf2, (float*)d_out, G);
}

// Round 16
// 121.066 us; speedup vs baseline: 2.1970x; 1.0086x over previous
//
#include <hip/hip_runtime.h>

#define IN_C 17
#define HID  64
#define OUTC 32

#define CH   8192      // edges per pass-A block
#define TA   512       // pass-A threads
#define NBP  512       // padded bucket count (bucket = dst>>8; N<=131072)
#define BCAP 5632      // pass-B stage capacity
#define BS_BLKS 8

typedef __attribute__((ext_vector_type(2))) float f2;
typedef __attribute__((ext_vector_type(8))) short bf16x8;
typedef __attribute__((ext_vector_type(4))) float f32x4;
__device__ __forceinline__ f2 mkf2(float x, float y) { f2 r; r.x = x; r.y = y; return r; }

__device__ __forceinline__ unsigned short f2bf(float f) {
    unsigned u = __float_as_uint(f);
    u += 0x7fffu + ((u >> 16) & 1u);      // round-nearest-even
    return (unsigned short)(u >> 16);
}
__device__ __forceinline__ float bflo(unsigned u) { return __uint_as_float(u << 16); }
__device__ __forceinline__ float bfhi(unsigned u) { return __uint_as_float(u & 0xffff0000u); }

// ================= pass A: bin edges by dst>>8, coalesced writes =================
__global__ __launch_bounds__(TA) void k_binA(const int* __restrict__ src,
        const int* __restrict__ dst, int E,
        int* __restrict__ outbuf, int* __restrict__ cntmat, int* __restrict__ offmat) {
    __shared__ int cnt[NBP];
    __shared__ int off[NBP];
    __shared__ int stage[CH];
    int t = threadIdx.x;
    long base = (long)blockIdx.x * CH;
    int nE = (int)(E - base); if (nE > CH) nE = CH;
    cnt[t] = 0;
    __syncthreads();
    int bk[16], pk[16], rk[16];
#pragma unroll
    for (int j = 0; j < 16; ++j) {
        int idx = t + j * TA;
        if (idx < nE) {
            long e = base + idx;
            int d = __builtin_nontemporal_load(&dst[e]);
            int s = __builtin_nontemporal_load(&src[e]);
            int b = d >> 8;
            bk[j] = b;
            pk[j] = s | ((d & 255) << 17);
            rk[j] = atomicAdd(&cnt[b], 1);
        } else bk[j] = -1;
    }
    __syncthreads();
    int c = cnt[t];
    off[t] = c;
    __syncthreads();
    int inc = c;
    for (int s = 1; s < NBP; s <<= 1) {
        int add = (t >= s) ? off[t - s] : 0;
        __syncthreads();
        inc += add; off[t] = inc;
        __syncthreads();
    }
    int excl = inc - c;
    __syncthreads();
    off[t] = excl;
    __syncthreads();
#pragma unroll
    for (int j = 0; j < 16; ++j)
        if (bk[j] >= 0) stage[off[bk[j]] + rk[j]] = pk[j];
    __syncthreads();
    for (int i = t; i < nE; i += TA) outbuf[base + i] = stage[i];
    cntmat[blockIdx.x * NBP + t] = c;
    offmat[blockIdx.x * NBP + t] = excl;
}

// ============ bucket totals (parallel partial) + pool zero-init ============
__global__ __launch_bounds__(NBP) void k_bsum1(const int* __restrict__ cntmat,
        int nblkA, int* __restrict__ part, float* __restrict__ pool, int poolN) {
    int t = threadIdx.x, b = blockIdx.x;
    int per = (nblkA + BS_BLKS - 1) / BS_BLKS;
    int i0 = b * per, i1 = min(i0 + per, nblkA);
    int s = 0;
    for (int i = i0; i < i1; ++i) s += cntmat[i * NBP + t];
    part[b * NBP + t] = s;
    // zero the pool+cntg region (replaces pathological hipMemsetAsync fill)
    for (int i = b * NBP + t; i < poolN; i += BS_BLKS * NBP) pool[i] = 0.f;
}

__global__ __launch_bounds__(NBP) void k_bsum2(const int* __restrict__ part,
        int* __restrict__ bbase, const float* __restrict__ W2,
        uint4* __restrict__ w2frag) {
    __shared__ int sh[NBP];
    int t = threadIdx.x;
    int s = 0;
#pragma unroll
    for (int i = 0; i < BS_BLKS; ++i) s += part[i * NBP + t];
    sh[t] = s;
    __syncthreads();
    int inc = s;
    for (int st = 1; st < NBP; st <<= 1) {
        int add = (t >= st) ? sh[t - st] : 0;
        __syncthreads();
        inc += add; sh[t] = inc;
        __syncthreads();
    }
    bbase[t] = inc - s;
    // pack W2 into MFMA B-fragment layout: frag f = kt*2+nt; lane l holds
    // B[k = kt*32 + (l>>4)*8 + j][c = nt*16 + (l&15)], j=0..7
    if (t < 256) {
        int f = t >> 6, l = t & 63;
        int kt = f >> 1, nt = f & 1;
        int kbase = kt * 32 + (l >> 4) * 8;
        int c = nt * 16 + (l & 15);
        unsigned short v[8];
#pragma unroll
        for (int j = 0; j < 8; ++j) v[j] = f2bf(W2[(kbase + j) * OUTC + c]);
        uint4 o;
        o.x = (unsigned)v[0] | ((unsigned)v[1] << 16);
        o.y = (unsigned)v[2] | ((unsigned)v[3] << 16);
        o.z = (unsigned)v[4] | ((unsigned)v[5] << 16);
        o.w = (unsigned)v[6] | ((unsigned)v[7] << 16);
        w2frag[f * 64 + l] = o;
    }
}

// === pass B: per bucket, gather runs, emit CSR + meta(start,deg) + bf16 xs (fused prep) ===
__global__ __launch_bounds__(TA) void k_binB(const int* __restrict__ outbuf,
        const int* __restrict__ cntmat, const int* __restrict__ offmat,
        const int* __restrict__ bbase, int nblkA, int N,
        int* __restrict__ csr, int2* __restrict__ meta,
        const float* __restrict__ x, unsigned* __restrict__ xs16h,
        unsigned short* __restrict__ xs17h) {
    __shared__ int segc[256], sego[256], segs[256];
    __shared__ int ndeg[256], noff[256];
    __shared__ int stage[BCAP];
    int t = threadIdx.x, b = blockIdx.x;
    if (t < 256) {
        int cc = 0, ss = 0;
        if (t < nblkA) { cc = cntmat[t * NBP + b]; ss = offmat[t * NBP + b]; }
        segc[t] = cc; segs[t] = ss; sego[t] = cc;
        ndeg[t] = 0;
    }
    __syncthreads();
    {
        int c = (t < 256) ? sego[t] : 0;
        int inc = c;
        for (int s = 1; s < 256; s <<= 1) {
            int add = (t < 256 && t >= s) ? sego[t - s] : 0;
            __syncthreads();
            if (t < 256) { inc += add; sego[t] = inc; }
            __syncthreads();
        }
        if (t < 256) sego[t] = inc - c;
    }
    __syncthreads();
    int wave = t >> 6, lane = t & 63;
    for (int i = wave; i < nblkA; i += TA / 64) {
        int c = segc[i], so = sego[i];
        long gs = (long)i * CH + segs[i];
        for (int l = lane; l < c; l += 64) {
            int p = so + l;
            if (p < BCAP) stage[p] = __builtin_nontemporal_load(&outbuf[gs + l]);
        }
    }
    __syncthreads();
    int T = sego[255] + segc[255];
    if (T > BCAP) T = BCAP;
    int mypk[11], myrk[11], ne = 0;
    for (int k = t; k < T; k += TA) {
        int p = stage[k];
        int l = (p >> 17) & 255;
        myrk[ne] = atomicAdd(&ndeg[l], 1);
        mypk[ne] = p;
        ne++;
    }
    __syncthreads();
    {
        int c = (t < 256) ? ndeg[t] : 0;
        if (t < 256) noff[t] = c;
        __syncthreads();
        int inc = c;
        for (int s = 1; s < 256; s <<= 1) {
            int add = (t < 256 && t >= s) ? noff[t - s] : 0;
            __syncthreads();
            if (t < 256) { inc += add; noff[t] = inc; }
            __syncthreads();
        }
        if (t < 256) noff[t] = inc - c;
    }
    __syncthreads();
    int gb = bbase[b];
    int n0 = b << 8;
    if (t < 256 && n0 + t < N) {
        int n = n0 + t;
        meta[n] = make_int2(gb + noff[t], ndeg[t]);
        float dinv = rsqrtf((float)(ndeg[t] + 1));
        const float* xr = x + (size_t)n * IN_C;
        unsigned* xo = xs16h + (size_t)n * 8;
#pragma unroll
        for (int w2 = 0; w2 < 8; ++w2) {
            unsigned lo = f2bf(xr[2 * w2] * dinv);
            unsigned hi = f2bf(xr[2 * w2 + 1] * dinv);
            xo[w2] = lo | (hi << 16);
        }
        xs17h[n] = f2bf(xr[16] * dinv);
    }
    for (int j = 0; j < ne; ++j) {
        int p = mypk[j];
        int l = (p >> 17) & 255;
        csr[gb + noff[l] + myrk[j]] = p & 0x1FFFF;
    }
}

// ---------- layer 1: direct-csr gather -> fold -> matvec1 -> in-block MFMA mm2 -> fp8 hs2 ----------
__global__ __launch_bounds__(256) void k_gather1(
        const uint4* __restrict__ xs16v, const unsigned short* __restrict__ xs17h,
        const int* __restrict__ csr, const int2* __restrict__ meta,
        const float* __restrict__ W1, const float* __restrict__ b1,
        const uint4* __restrict__ w2frag, unsigned char* __restrict__ hs2b, int N) {
    __shared__ __align__(16) float aggx[16][20];
    __shared__ float dinv_sh[16];
    __shared__ __align__(16) float h1sh[16][68];   // holds dinv*relu(h1), f32

    int tid = threadIdx.x;
    int n0 = blockIdx.x * 16;
    int ch = tid & 63;
    float w1r[IN_C];
#pragma unroll
    for (int k = 0; k < IN_C; ++k) w1r[k] = W1[k * HID + ch];
    float b1v = b1[ch];

    int ln = tid >> 4, sl = tid & 15;
    int n = n0 + ln;
    f2 acc[8];
#pragma unroll
    for (int j = 0; j < 8; ++j) acc[j] = mkf2(0.f, 0.f);
    float a17 = 0.f;
    if (n < N) {
        int2 m = meta[n];
        int start = m.x, cnt = m.y, end = start + cnt;
        auto body = [&](int s) {
            uint4 v0 = xs16v[(size_t)s * 2];
            uint4 v1 = xs16v[(size_t)s * 2 + 1];
            acc[0] += mkf2(bflo(v0.x), bfhi(v0.x));
            acc[1] += mkf2(bflo(v0.y), bfhi(v0.y));
            acc[2] += mkf2(bflo(v0.z), bfhi(v0.z));
            acc[3] += mkf2(bflo(v0.w), bfhi(v0.w));
            acc[4] += mkf2(bflo(v1.x), bfhi(v1.x));
            acc[5] += mkf2(bflo(v1.y), bfhi(v1.y));
            acc[6] += mkf2(bflo(v1.z), bfhi(v1.z));
            acc[7] += mkf2(bflo(v1.w), bfhi(v1.w));
            a17 += bflo((unsigned)xs17h[s]);
        };
        for (int k = start + sl; k < end; k += 16)
            body(__builtin_nontemporal_load(&csr[k]));
        if (sl == 0) {                                   // self loop
            body(n);
            dinv_sh[ln] = rsqrtf((float)(cnt + 1));
        }
    }
    float a[16];
#pragma unroll
    for (int j = 0; j < 8; ++j) { a[2 * j] = acc[j].x; a[2 * j + 1] = acc[j].y; }
#pragma unroll
    for (int j = 0; j < 8; ++j) {
        float tt = (sl & 8) ? a[j + 8] : a[j];
        float uu = (sl & 8) ? a[j] : a[j + 8];
        a[j] = tt + __shfl_xor(uu, 8);
    }
#pragma unroll
    for (int j = 0; j < 4; ++j) {
        float tt = (sl & 4) ? a[j + 4] : a[j];
        float uu = (sl & 4) ? a[j] : a[j + 4];
        a[j] = tt + __shfl_xor(uu, 4);
    }
#pragma unroll
    for (int j = 0; j < 2; ++j) {
        float tt = (sl & 2) ? a[j + 2] : a[j];
        float uu = (sl & 2) ? a[j] : a[j + 2];
        a[j] = tt + __shfl_xor(uu, 2);
    }
    {
        float tt = (sl & 1) ? a[1] : a[0];
        float uu = (sl & 1) ? a[0] : a[1];
        a[0] = tt + __shfl_xor(uu, 1);
    }
    a17 += __shfl_xor(a17, 1);
    a17 += __shfl_xor(a17, 2);
    a17 += __shfl_xor(a17, 4);
    a17 += __shfl_xor(a17, 8);
    aggx[ln][sl] = a[0];
    if (sl == 0) aggx[ln][16] = a17;
    __syncthreads();
    // matvec1 + bias + relu; h1sh = dinv * relu(...)  (f32)
    int s0 = tid >> 6;
#pragma unroll
    for (int rep = 0; rep < 4; ++rep) {
        int slot = s0 + rep * 4;
        int nn = n0 + slot;
        if (nn < N) {
            const float4* ap = (const float4*)aggx[slot];
            float4 A0 = ap[0], A1 = ap[1], A2 = ap[2], A3 = ap[3];
            float a16 = aggx[slot][16];
            float dot = A0.x * w1r[0]  + A0.y * w1r[1]  + A0.z * w1r[2]  + A0.w * w1r[3]
                      + A1.x * w1r[4]  + A1.y * w1r[5]  + A1.z * w1r[6]  + A1.w * w1r[7]
                      + A2.x * w1r[8]  + A2.y * w1r[9]  + A2.z * w1r[10] + A2.w * w1r[11]
                      + A3.x * w1r[12] + A3.y * w1r[13] + A3.z * w1r[14] + A3.w * w1r[15]
                      + a16  * w1r[16];
            float dv = dinv_sh[slot];
            h1sh[slot][ch] = dv * fmaxf(dv * dot + b1v, 0.f);
        }
    }
    __syncthreads();
    // mm2 via MFMA on this block's 16 nodes: wave wv computes N-tile wv (cols wv*16..+15)
    int wv = tid >> 6, l = tid & 63;
    if (wv < 2) {
        int row = l & 15, kq = l >> 4;
        const float4* hp = (const float4*)&h1sh[row][kq * 8];
        float4 f0v = hp[0], f1v = hp[1];
        const float4* hq = (const float4*)&h1sh[row][32 + kq * 8];
        float4 g0v = hq[0], g1v = hq[1];
        bf16x8 a0, a1;
        a0[0] = (short)f2bf(f0v.x); a0[1] = (short)f2bf(f0v.y);
        a0[2] = (short)f2bf(f0v.z); a0[3] = (short)f2bf(f0v.w);
        a0[4] = (short)f2bf(f1v.x); a0[5] = (short)f2bf(f1v.y);
        a0[6] = (short)f2bf(f1v.z); a0[7] = (short)f2bf(f1v.w);
        a1[0] = (short)f2bf(g0v.x); a1[1] = (short)f2bf(g0v.y);
        a1[2] = (short)f2bf(g0v.z); a1[3] = (short)f2bf(g0v.w);
        a1[4] = (short)f2bf(g1v.x); a1[5] = (short)f2bf(g1v.y);
        a1[6] = (short)f2bf(g1v.z); a1[7] = (short)f2bf(g1v.w);
        bf16x8 bA = *(const bf16x8*)&w2frag[(0 + wv) * 64 + l];   // kt0, nt=wv
        bf16x8 bB = *(const bf16x8*)&w2frag[(2 + wv) * 64 + l];   // kt1, nt=wv
        f32x4 d = {0.f, 0.f, 0.f, 0.f};
        d = __builtin_amdgcn_mfma_f32_16x16x32_bf16(a0, bA, d, 0, 0, 0);
        d = __builtin_amdgcn_mfma_f32_16x16x32_bf16(a1, bB, d, 0, 0, 0);
        int rbase = (l >> 4) * 4;
#pragma unroll
        for (int r = 0; r < 4; ++r) {
            int node = n0 + rbase + r;
            if (node < N) {
                unsigned pk = (unsigned)__builtin_amdgcn_cvt_pk_fp8_f32(d[r], 0.f, 0, false);
                hs2b[(size_t)node * 32 + wv * 16 + (l & 15)] = (unsigned char)(pk & 0xFFu);
            }
        }
    }
}

// ---------- layer 2 gather: direct-csr, 1 lane/edge, fp8 rows (HW cvt) + pool ----------
__global__ __launch_bounds__(256) void k_gather2(
        const uint4* __restrict__ hs2v, const int* __restrict__ csr,
        const int2* __restrict__ meta, const float* __restrict__ b2,
        const int* __restrict__ batch, float* pool, float* cntg, int N) {
    __shared__ __align__(16) float cont[16][OUTC];
    __shared__ int bsh[16];
    int tid = threadIdx.x;
    int n0 = blockIdx.x * 16;

    int ln = tid >> 4, sl = tid & 15;
    int n = n0 + ln;
    f2 acc[16];
#pragma unroll
    for (int j = 0; j < 16; ++j) acc[j] = mkf2(0.f, 0.f);
    float dinv = 0.f;
    if (n < N) {
        int2 m = meta[n];
        int start = m.x, cnt = m.y, end = start + cnt;
        dinv = rsqrtf((float)(cnt + 1));
        auto body = [&](int s) {
            const uint4* rp = hs2v + (size_t)s * 2;
            uint4 v0 = rp[0], v1 = rp[1];
            f2 t;
            t = __builtin_amdgcn_cvt_pk_f32_fp8((int)v0.x, false); acc[0]  += t;
            t = __builtin_amdgcn_cvt_pk_f32_fp8((int)v0.x, true);  acc[1]  += t;
            t = __builtin_amdgcn_cvt_pk_f32_fp8((int)v0.y, false); acc[2]  += t;
            t = __builtin_amdgcn_cvt_pk_f32_fp8((int)v0.y, true);  acc[3]  += t;
            t = __builtin_amdgcn_cvt_pk_f32_fp8((int)v0.z, false); acc[4]  += t;
            t = __builtin_amdgcn_cvt_pk_f32_fp8((int)v0.z, true);  acc[5]  += t;
            t = __builtin_amdgcn_cvt_pk_f32_fp8((int)v0.w, false); acc[6]  += t;
            t = __builtin_amdgcn_cvt_pk_f32_fp8((int)v0.w, true);  acc[7]  += t;
            t = __builtin_amdgcn_cvt_pk_f32_fp8((int)v1.x, false); acc[8]  += t;
            t = __builtin_amdgcn_cvt_pk_f32_fp8((int)v1.x, true);  acc[9]  += t;
            t = __builtin_amdgcn_cvt_pk_f32_fp8((int)v1.y, false); acc[10] += t;
            t = __builtin_amdgcn_cvt_pk_f32_fp8((int)v1.y, true);  acc[11] += t;
            t = __builtin_amdgcn_cvt_pk_f32_fp8((int)v1.z, false); acc[12] += t;
            t = __builtin_amdgcn_cvt_pk_f32_fp8((int)v1.z, true);  acc[13] += t;
            t = __builtin_amdgcn_cvt_pk_f32_fp8((int)v1.w, false); acc[14] += t;
            t = __builtin_amdgcn_cvt_pk_f32_fp8((int)v1.w, true);  acc[15] += t;
        };
        for (int k = start + sl; k < end; k += 16)
            body(__builtin_nontemporal_load(&csr[k]));
        if (sl == 0) body(n);                            // self loop
    }
    float a[32];
#pragma unroll
    for (int j = 0; j < 16; ++j) { a[2 * j] = acc[j].x; a[2 * j + 1] = acc[j].y; }
    // halving fold: lane sl ends with channels (2sl, 2sl+1) in a[0], a[1]
#pragma unroll
    for (int j = 0; j < 16; ++j) {
        float tt = (sl & 8) ? a[j + 16] : a[j];
        float uu = (sl & 8) ? a[j] : a[j + 16];
        a[j] = tt + __shfl_xor(uu, 8);
    }
#pragma unroll
    for (int j = 0; j < 8; ++j) {
        float tt = (sl & 4) ? a[j + 8] : a[j];
        float uu = (sl & 4) ? a[j] : a[j + 8];
        a[j] = tt + __shfl_xor(uu, 4);
    }
#pragma unroll
    for (int j = 0; j < 4; ++j) {
        float tt = (sl & 2) ? a[j + 4] : a[j];
        float uu = (sl & 2) ? a[j] : a[j + 4];
        a[j] = tt + __shfl_xor(uu, 2);
    }
#pragma unroll
    for (int j = 0; j < 2; ++j) {
        float tt = (sl & 1) ? a[j + 2] : a[j];
        float uu = (sl & 1) ? a[j] : a[j + 2];
        a[j] = tt + __shfl_xor(uu, 1);
    }
    if (n < N) {
        float c0 = dinv * a[0] + b2[2 * sl];
        float c1 = dinv * a[1] + b2[2 * sl + 1];
        *(float2*)&cont[ln][2 * sl] = make_float2(c0, c1);
        if (sl == 0) bsh[ln] = batch[n];
    } else {
        *(float2*)&cont[ln][2 * sl] = make_float2(0.f, 0.f);
        if (sl == 0) bsh[ln] = -1;
    }
    __syncthreads();
    if (tid < OUTC) {
        int c = tid;
        float run = 0.f; int cur = -1;
        for (int j = 0; j < 16; ++j) {
            int bj = bsh[j];
            if (bj < 0) continue;
            if (bj == cur) run += cont[j][c];
            else {
                if (cur >= 0) atomicAdd(&pool[(size_t)cur * OUTC + c], run);
                cur = bj; run = cont[j][c];
            }
        }
        if (cur >= 0) atomicAdd(&pool[(size_t)cur * OUTC + c], run);
        if (c == 0) {
            float crun = 0.f; cur = -1;
            for (int j = 0; j < 16; ++j) {
                int bj = bsh[j];
                if (bj < 0) continue;
                if (bj == cur) crun += 1.f;
                else {
                    if (cur >= 0) atomicAdd(&cntg[cur], crun);
                    cur = bj; crun = 1.f;
                }
            }
            if (cur >= 0) atomicAdd(&cntg[cur], crun);
        }
    }
}

// ---------- final: pooled mean -> fc1(relu) -> fc2 ----------
__global__ void k_final(const float* __restrict__ pool, const float* __restrict__ cntg,
                        const float* __restrict__ Wf1, const float* __restrict__ bf1,
                        const float* __restrict__ Wf2, const float* __restrict__ bf2,
                        float* out, int G) {
    __shared__ float p[OUTC], t[OUTC];
    int g = blockIdx.x;
    int c = threadIdx.x;
    float csafe = fmaxf(cntg[g], 1.0f);
    p[c] = pool[g * OUTC + c] / csafe;
    __syncthreads();
    float acc = bf1[c];
#pragma unroll
    for (int k = 0; k < OUTC; ++k) acc += p[k] * Wf1[k * OUTC + c];
    t[c] = fmaxf(acc, 0.f);
    __syncthreads();
    float acc2 = bf2[c];
#pragma unroll
    for (int k = 0; k < OUTC; ++k) acc2 += t[k] * Wf2[k * OUTC + c];
    out[g * OUTC + c] = acc2;
}

extern "C" void kernel_launch(void* const* d_in, const int* in_sizes, int n_in,
                              void* d_out, int out_size, void* d_ws, size_t ws_size,
                              hipStream_t stream) {
    const float* x    = (const float*)d_in[0];
    const int*   ei   = (const int*)  d_in[1];
    const int*   batch= (const int*)  d_in[2];
    const float* W1   = (const float*)d_in[3];
    const float* b1   = (const float*)d_in[4];
    const float* W2   = (const float*)d_in[5];
    const float* b2   = (const float*)d_in[6];
    const float* Wf1  = (const float*)d_in[7];
    const float* bf1  = (const float*)d_in[8];
    const float* Wf2  = (const float*)d_in[9];
    const float* bf2  = (const float*)d_in[10];

    const int N = in_sizes[0] / IN_C;
    const int E = in_sizes[1] / 2;
    const int G = out_size / OUTC;
    const int* src = ei;
    const int* dst = ei + E;

    const int nblkA = (E + CH - 1) / CH;
    const int NB    = (N + 255) >> 8;

    // ---- workspace layout ----
    char* w = (char*)d_ws;
    int*   csr      = (int*)w;   w += (size_t)E * sizeof(int);
    int2*  meta     = (int2*)w;  w += (size_t)N * sizeof(int2);
    unsigned* xs16h = (unsigned*)w; w += (size_t)N * 8 * sizeof(unsigned);
    unsigned char* hs2 = (unsigned char*)w; w += (size_t)N * 32;   // fp8 rows, 32B
    unsigned short* xs17h = (unsigned short*)w; w += (size_t)N * sizeof(unsigned short);
    w = (char*)(((size_t)w + 15) & ~(size_t)15);
    float* pool     = (float*)w; w += (size_t)G * OUTC * sizeof(float);
    float* cntg     = (float*)w; w += (size_t)G * sizeof(float);
    w = (char*)(((size_t)w + 15) & ~(size_t)15);
    int*   outbuf   = (int*)w;   w += (size_t)E * sizeof(int);
    int*   cntmat   = (int*)w;   w += (size_t)nblkA * NBP * sizeof(int);
    int*   offmat   = (int*)w;   w += (size_t)nblkA * NBP * sizeof(int);
    int*   bbase    = (int*)w;   w += NBP * sizeof(int);
    int*   part     = (int*)w;   w += BS_BLKS * NBP * sizeof(int);
    w = (char*)(((size_t)w + 15) & ~(size_t)15);
    uint4* w2frag   = (uint4*)w; w += 4 * 64 * sizeof(uint4);

    const int poolN = G * OUTC + G;   // pool + cntg are contiguous floats

    // CSR build (counting sort) + fused x prep + W2 fragment pack + pool zero
    k_binA<<<nblkA, TA, 0, stream>>>(src, dst, E, outbuf, cntmat, offmat);
    k_bsum1<<<BS_BLKS, NBP, 0, stream>>>(cntmat, nblkA, part, pool, poolN);
    k_bsum2<<<1, NBP, 0, stream>>>(part, bbase, W2, w2frag);
    k_binB<<<NB, TA, 0, stream>>>(outbuf, cntmat, offmat, bbase, nblkA, N,
                                  csr, meta, x, xs16h, xs17h);

    // layer 1: gather + matvec1 + in-block MFMA mm2 -> fp8 hs2 (natural ch order)
    dim3 blk(256);
    k_gather1<<<(N + 15) / 16, blk, 0, stream>>>((const uint4*)xs16h, xs17h, csr, meta,
                                                 W1, b1, w2frag, hs2, N);

    // layer 2 gather + pool (fp8 rows, fully L2-resident)
    k_gather2<<<(N + 15) / 16, blk, 0, stream>>>((const uint4*)hs2, csr, meta,
                                                 b2, batch, pool, cntg, N);

    // readout
    k_final<<<G, OUTC, 0, stream>>>(pool, cntg, Wf1, bf1, Wf2, bf2, (float*)d_out, G);
}